// Round 11
// baseline (510.380 us; speedup 1.0000x reference)
//
#include <hip/hip_runtime.h>

#define N_NODES 50000
#define N_EDGES 800000
#define N_GRAPHS 512
#define F_IN 128
#define HDIM 96
#define NCLS 10
#define BN_EPS 1e-5f

// partitioned CSR fill geometry
#define NPB 128
#define NBUCK2 ((N_NODES + NPB - 1) / NPB) // 391 buckets
#define NEB 128
#define EPB ((N_EDGES + NEB - 1) / NEB)    // 6250 edges per block

typedef unsigned int u32;
typedef unsigned short u16;
typedef __attribute__((ext_vector_type(8))) short bf16x8;
typedef __attribute__((ext_vector_type(4))) float f32x4;

__device__ __forceinline__ u16 f2bf(float f) {
    u32 u = __float_as_uint(f);
    u32 r = (u + 0x7fffu + ((u >> 16) & 1u)) >> 16;   // RNE
    return (u16)r;
}
__device__ __forceinline__ float bflo(u32 w) { return __uint_as_float(w << 16); }
__device__ __forceinline__ float bfhi(u32 w) { return __uint_as_float(w & 0xffff0000u); }
__device__ __forceinline__ float bf2f(u16 v) { return __uint_as_float((u32)v << 16); }

// ---------------- column stats (slot partials, no atomics) ----------------
template<int NC>
__global__ __launch_bounds__(256) void colstats4_kernel(const float* __restrict__ in,
                                                        float* __restrict__ partials,
                                                        int nrows) {
    constexpr int CG  = NC / 4;
    constexpr int RPB = 256 / CG;
    const int cg = threadIdx.x % CG;
    const int rg = threadIdx.x / CG;
    float4 s = make_float4(0.f, 0.f, 0.f, 0.f);
    float4 q = make_float4(0.f, 0.f, 0.f, 0.f);
    for (int r = blockIdx.x * RPB + rg; r < nrows; r += gridDim.x * RPB) {
        float4 v = *(const float4*)&in[(size_t)r * NC + cg * 4];
        s.x += v.x; s.y += v.y; s.z += v.z; s.w += v.w;
        q.x += v.x * v.x; q.y += v.y * v.y; q.z += v.z * v.z; q.w += v.w * v.w;
    }
    __shared__ float ss[RPB][NC], sq[RPB][NC];
    *(float4*)&ss[rg][cg * 4] = s;
    *(float4*)&sq[rg][cg * 4] = q;
    __syncthreads();
    if (threadIdx.x < NC) {
        float a = 0.f, b = 0.f;
        #pragma unroll
        for (int r = 0; r < RPB; r++) { a += ss[r][threadIdx.x]; b += sq[r][threadIdx.x]; }
        partials[(size_t)blockIdx.x * 2 * NC + threadIdx.x]      = a;
        partials[(size_t)blockIdx.x * 2 * NC + NC + threadIdx.x] = b;
    }
}

template<int NC>
__global__ __launch_bounds__(2*NC) void colstats_kernel(const float* __restrict__ in,
                                                        float* __restrict__ partials,
                                                        int nrows) {
    const int col  = threadIdx.x % NC;
    const int half = threadIdx.x / NC;
    float s = 0.f, ss = 0.f;
    for (int r = blockIdx.x * 2 + half; r < nrows; r += gridDim.x * 2) {
        float v = in[(size_t)r * NC + col];
        s += v; ss += v * v;
    }
    __shared__ float shs[2][NC], shq[2][NC];
    shs[half][col] = s; shq[half][col] = ss;
    __syncthreads();
    if (half == 0) {
        partials[(size_t)blockIdx.x * 2 * NC + col]      = s  + shs[1][col];
        partials[(size_t)blockIdx.x * 2 * NC + NC + col] = ss + shq[1][col];
    }
}

// fixed-order slot reduction + BN finalize (deterministic)
__global__ void reduce_finalize_kernel(const float* __restrict__ partials, int nslots,
                                       const float* __restrict__ w,
                                       const float* __restrict__ b,
                                       float* __restrict__ ac, int ncols, float inv_n) {
    const int k = threadIdx.x;
    if (k >= ncols) return;
    const int stride = 2 * ncols;
    float s0=0,s1=0,s2=0,s3=0, q0=0,q1=0,q2=0,q3=0;
    int i = 0;
    for (; i + 4 <= nslots; i += 4) {
        s0 += partials[(size_t)(i    ) * stride + k];
        s1 += partials[(size_t)(i + 1) * stride + k];
        s2 += partials[(size_t)(i + 2) * stride + k];
        s3 += partials[(size_t)(i + 3) * stride + k];
        q0 += partials[(size_t)(i    ) * stride + ncols + k];
        q1 += partials[(size_t)(i + 1) * stride + ncols + k];
        q2 += partials[(size_t)(i + 2) * stride + ncols + k];
        q3 += partials[(size_t)(i + 3) * stride + ncols + k];
    }
    for (; i < nslots; i++) {
        s0 += partials[(size_t)i * stride + k];
        q0 += partials[(size_t)i * stride + ncols + k];
    }
    float s = (s0 + s1) + (s2 + s3);
    float q = (q0 + q1) + (q2 + q3);
    float mu  = s * inv_n;
    float var = q * inv_n - mu * mu;
    float a   = w[k] * rsqrtf(var + BN_EPS);
    ac[k]         = a;
    ac[ncols + k] = b[k] - mu * a;
}

// ---------------- fused weight prep: all 7 weights in one launch ----------------
#define WPF_BLOCKS 48   // ceil(128*96/256)
#define WPH_BLOCKS 36   // 96*96/256
__global__ __launch_bounds__(256) void wprep_all_kernel(
        const float* __restrict__ Wf, const float* __restrict__ bf, const float* __restrict__ acX,
        const float* __restrict__ W0a, const float* __restrict__ b0a,
        const float* __restrict__ W0b, const float* __restrict__ b0b,
        const float* __restrict__ W1a, const float* __restrict__ b1a,
        const float* __restrict__ W1b, const float* __restrict__ b1b,
        const float* __restrict__ W2a, const float* __restrict__ b2a,
        const float* __restrict__ W2b, const float* __restrict__ b2b,
        u16* __restrict__ wtF, float* __restrict__ bFm,
        u16* __restrict__ wtbase, float* __restrict__ bmbase) {
    const int tid = threadIdx.x;
    int blk = blockIdx.x;
    if (blk < WPF_BLOCKS) {
        int i = blk * 256 + tid;
        if (i < F_IN * 96) {
            int k = i / 96, n = i % 96;
            wtF[n * F_IN + k] = f2bf(Wf[i] * acX[k]);
        }
        if (blk == 0 && tid < 96) {
            float b = bf[tid];
            for (int k = 0; k < F_IN; k++) b += acX[F_IN + k] * Wf[k * 96 + tid];
            bFm[tid] = b;
        }
        return;
    }
    blk -= WPF_BLOCKS;
    const int s  = blk / WPH_BLOCKS;
    const int b2 = blk % WPH_BLOCKS;
    const float* W; const float* bias;
    switch (s) {
        case 0: W = W0a; bias = b0a; break;
        case 1: W = W0b; bias = b0b; break;
        case 2: W = W1a; bias = b1a; break;
        case 3: W = W1b; bias = b1b; break;
        case 4: W = W2a; bias = b2a; break;
        default: W = W2b; bias = b2b; break;
    }
    u16*   wtb  = wtbase + (size_t)s * 96 * HDIM;
    float* bmod = bmbase + (size_t)s * 96;
    int i = b2 * 256 + tid;
    if (i < HDIM * 96) {
        int k = i / 96, n = i % 96;
        wtb[n * HDIM + k] = f2bf(W[i]);
    }
    if (b2 == 0 && tid < 96) bmod[tid] = bias[tid];
}

// ---------------- CSR build ----------------
__global__ __launch_bounds__(1024) void scan1_kernel(const int* __restrict__ in,
                                                     int* __restrict__ tmp,
                                                     int* __restrict__ partial, int n) {
    __shared__ int sh[1024];
    const int i = blockIdx.x * 1024 + threadIdx.x;
    const int d = (i < n) ? in[i] : 0;
    sh[threadIdx.x] = d;
    __syncthreads();
    for (int off = 1; off < 1024; off <<= 1) {
        int v = 0;
        if (threadIdx.x >= off) v = sh[threadIdx.x - off];
        __syncthreads();
        sh[threadIdx.x] += v;
        __syncthreads();
    }
    if (i < n) tmp[i] = sh[threadIdx.x] - d;
    if (threadIdx.x == 1023) partial[blockIdx.x] = sh[1023];
}

__global__ __launch_bounds__(1024) void scan3_rowptr_kernel(const int* __restrict__ tmp,
                                                            const int* __restrict__ partial,
                                                            const int* __restrict__ deg,
                                                            int* __restrict__ row_ptr,
                                                            int n, int nparts) {
    __shared__ int offs;
    if (threadIdx.x < 64) {
        int v = (threadIdx.x < blockIdx.x && threadIdx.x < nparts) ? partial[threadIdx.x] : 0;
        for (int o = 32; o > 0; o >>= 1) v += __shfl_down(v, o, 64);
        if (threadIdx.x == 0) offs = v;
    }
    __syncthreads();
    const int i = blockIdx.x * 1024 + threadIdx.x;
    if (i < n) {
        int v = tmp[i] + offs;
        row_ptr[i] = v;
        if (i == n - 1) row_ptr[n] = v + deg[i];
    }
}

__global__ __launch_bounds__(1024) void scan3_kernel(const int* __restrict__ tmp,
                                                     const int* __restrict__ partial,
                                                     int* __restrict__ out,
                                                     int n, int nparts) {
    __shared__ int offs;
    if (threadIdx.x < 64) {
        int v = (threadIdx.x < blockIdx.x && threadIdx.x < nparts) ? partial[threadIdx.x] : 0;
        for (int o = 32; o > 0; o >>= 1) v += __shfl_down(v, o, 64);
        if (threadIdx.x == 0) offs = v;
    }
    __syncthreads();
    const int i = blockIdx.x * 1024 + threadIdx.x;
    if (i < n) out[i] = tmp[i] + offs;
}

__global__ __launch_bounds__(256) void count_kernel(const int* __restrict__ dst,
                                                    int* __restrict__ deg,
                                                    int* __restrict__ cnt) {
    __shared__ int lc[NBUCK2];
    for (int i = threadIdx.x; i < NBUCK2; i += 256) lc[i] = 0;
    __syncthreads();
    const int lo = blockIdx.x * EPB;
    const int hi = min(lo + EPB, N_EDGES);
    for (int e = lo + threadIdx.x; e < hi; e += 256) {
        int d = dst[e];
        atomicAdd(&lc[d / NPB], 1);
        atomicAdd(&deg[d], 1);
    }
    __syncthreads();
    for (int i = threadIdx.x; i < NBUCK2; i += 256)
        cnt[i * NEB + blockIdx.x] = lc[i];
}

__global__ __launch_bounds__(256) void distribute_kernel(const int* __restrict__ src,
                                                         const int* __restrict__ dst,
                                                         const int* __restrict__ ofs,
                                                         u32* __restrict__ ebuf) {
    __shared__ int lofs[NBUCK2];
    for (int i = threadIdx.x; i < NBUCK2; i += 256) lofs[i] = ofs[i * NEB + blockIdx.x];
    __syncthreads();
    const int lo = blockIdx.x * EPB;
    const int hi = min(lo + EPB, N_EDGES);
    for (int e = lo + threadIdx.x; e < hi; e += 256) {
        int d = dst[e];
        int q = atomicAdd(&lofs[d / NPB], 1);
        ebuf[q] = ((u32)src[e] << 7) | (u32)(d & (NPB - 1));
    }
}

__global__ __launch_bounds__(256) void bucket_fill_kernel(const u32* __restrict__ ebuf,
                                                          const int* __restrict__ ofs,
                                                          const int* __restrict__ row_ptr,
                                                          int* __restrict__ csr) {
    __shared__ int cur[NPB];
    const int p    = blockIdx.x;
    const int base = p * NPB;
    const int nn   = min(NPB, N_NODES - base);
    for (int i = threadIdx.x; i < nn; i += 256) cur[i] = row_ptr[base + i];
    __syncthreads();
    const int e0 = ofs[p * NEB];
    const int e1 = (p + 1 < NBUCK2) ? ofs[(p + 1) * NEB] : N_EDGES;
    for (int e = e0 + threadIdx.x; e < e1; e += 256) {
        u32 v = ebuf[e];
        int pos = atomicAdd(&cur[v & (NPB - 1)], 1);
        csr[pos] = (int)(v >> 7);
    }
}

// ---------------- GIN aggregation (bf16 gathers, f64 accumulation) ----------------
// f64 accumulation makes the per-node sum insensitive to csr neighbor PERMUTATION
// (order jitter ~2^-45 relative << bf16 rounding grid) -> deterministic output.
__device__ __forceinline__ void acc8lo(double& a, u32 w0,u32 w1,u32 w2,u32 w3,u32 w4,u32 w5,u32 w6,u32 w7){
    a += bflo(w0); a += bflo(w1); a += bflo(w2); a += bflo(w3);
    a += bflo(w4); a += bflo(w5); a += bflo(w6); a += bflo(w7);
}
__device__ __forceinline__ void acc8hi(double& a, u32 w0,u32 w1,u32 w2,u32 w3,u32 w4,u32 w5,u32 w6,u32 w7){
    a += bfhi(w0); a += bfhi(w1); a += bfhi(w2); a += bfhi(w3);
    a += bfhi(w4); a += bfhi(w5); a += bfhi(w6); a += bfhi(w7);
}
__global__ __launch_bounds__(192) void agg_kernel(const u16* __restrict__ hb,
                                                  const int* __restrict__ row_ptr,
                                                  const int* __restrict__ csr,
                                                  u16* __restrict__ mb, int n) {
    const int jj   = threadIdx.x % 12;
    const int node = blockIdx.x * 16 + threadIdx.x / 12;
    if (node >= n) return;
    const int p0 = row_ptr[node], p1 = row_ptr[node + 1];
    uint4 sv = *(const uint4*)&hb[(size_t)node * 96 + jj * 8];
    double a0 = bflo(sv.x), a1 = bfhi(sv.x), a2 = bflo(sv.y), a3 = bfhi(sv.y);
    double a4 = bflo(sv.z), a5 = bfhi(sv.z), a6 = bflo(sv.w), a7 = bfhi(sv.w);
    int p = p0;
    for (; p + 8 <= p1; p += 8) {
        int s0 = csr[p],     s1 = csr[p + 1], s2 = csr[p + 2], s3 = csr[p + 3];
        int s4 = csr[p + 4], s5 = csr[p + 5], s6 = csr[p + 6], s7 = csr[p + 7];
        uint4 v0 = *(const uint4*)&hb[(size_t)s0 * 96 + jj * 8];
        uint4 v1 = *(const uint4*)&hb[(size_t)s1 * 96 + jj * 8];
        uint4 v2 = *(const uint4*)&hb[(size_t)s2 * 96 + jj * 8];
        uint4 v3 = *(const uint4*)&hb[(size_t)s3 * 96 + jj * 8];
        uint4 v4 = *(const uint4*)&hb[(size_t)s4 * 96 + jj * 8];
        uint4 v5 = *(const uint4*)&hb[(size_t)s5 * 96 + jj * 8];
        uint4 v6 = *(const uint4*)&hb[(size_t)s6 * 96 + jj * 8];
        uint4 v7 = *(const uint4*)&hb[(size_t)s7 * 96 + jj * 8];
        acc8lo(a0, v0.x,v1.x,v2.x,v3.x,v4.x,v5.x,v6.x,v7.x);
        acc8hi(a1, v0.x,v1.x,v2.x,v3.x,v4.x,v5.x,v6.x,v7.x);
        acc8lo(a2, v0.y,v1.y,v2.y,v3.y,v4.y,v5.y,v6.y,v7.y);
        acc8hi(a3, v0.y,v1.y,v2.y,v3.y,v4.y,v5.y,v6.y,v7.y);
        acc8lo(a4, v0.z,v1.z,v2.z,v3.z,v4.z,v5.z,v6.z,v7.z);
        acc8hi(a5, v0.z,v1.z,v2.z,v3.z,v4.z,v5.z,v6.z,v7.z);
        acc8lo(a6, v0.w,v1.w,v2.w,v3.w,v4.w,v5.w,v6.w,v7.w);
        acc8hi(a7, v0.w,v1.w,v2.w,v3.w,v4.w,v5.w,v6.w,v7.w);
    }
    for (; p < p1; p++) {
        int s = csr[p];
        uint4 v = *(const uint4*)&hb[(size_t)s * 96 + jj * 8];
        a0 += bflo(v.x); a1 += bfhi(v.x); a2 += bflo(v.y); a3 += bfhi(v.y);
        a4 += bflo(v.z); a5 += bfhi(v.z); a6 += bflo(v.w); a7 += bfhi(v.w);
    }
    uint4 o;
    o.x = (u32)f2bf((float)a0) | ((u32)f2bf((float)a1) << 16);
    o.y = (u32)f2bf((float)a2) | ((u32)f2bf((float)a3) << 16);
    o.z = (u32)f2bf((float)a4) | ((u32)f2bf((float)a5) << 16);
    o.w = (u32)f2bf((float)a6) | ((u32)f2bf((float)a7) << 16);
    *(uint4*)&mb[(size_t)node * 96 + jj * 8] = o;
}

// ---------------- MFMA matmul (STATS -> slot partials, deterministic) ----------------
template<int KDIM, bool IN_F32, bool IN_AFF_RELU, bool OUT_RELU, bool STATS, bool OUT_BF16>
__global__ __launch_bounds__(256) void mmx_kernel(const void* __restrict__ in_,
                                                  const u16* __restrict__ wt,
                                                  const float* __restrict__ bias,
                                                  const float* __restrict__ ac,
                                                  void* __restrict__ out_,
                                                  float* __restrict__ partials,
                                                  int nrows) {
    constexpr int KP = KDIM + 8;
    constexpr int KB = KDIM / 32;
    __shared__ u16 wlds[96 * KP];
    __shared__ u16 alds[64 * KP];
    __shared__ float sred[2][4][96];
    const int tid = threadIdx.x;

    for (int i = tid; i < 96 * (KDIM / 8); i += 256) {
        int nn = i / (KDIM / 8), c8 = i % (KDIM / 8);
        *(uint4*)&wlds[nn * KP + c8 * 8] = *(const uint4*)&wt[nn * KDIM + c8 * 8];
    }

    const int w    = tid >> 6;
    const int lane = tid & 63;
    const int r16  = lane & 15;
    const int kg   = lane >> 4;
    const int m0   = w * 16;
    float bn[6];
    #pragma unroll
    for (int nt = 0; nt < 6; nt++) bn[nt] = bias[nt * 16 + r16];
    float scol[6] = {0,0,0,0,0,0}, qcol[6] = {0,0,0,0,0,0};

    const int nchunks = (nrows + 63) / 64;
    for (int chunk = blockIdx.x; chunk < nchunks; chunk += gridDim.x) {
        const int row0 = chunk * 64;
        __syncthreads();
        if constexpr (IN_F32) {
            const float* inf = (const float*)in_;
            for (int i = tid; i < 64 * (KDIM / 4); i += 256) {
                int r = i / (KDIM / 4), c4 = i % (KDIM / 4);
                int gr = row0 + r;
                float4 v = (gr < nrows) ? *(const float4*)&inf[(size_t)gr * KDIM + c4 * 4]
                                        : make_float4(0.f, 0.f, 0.f, 0.f);
                if constexpr (IN_AFF_RELU) {
                    float4 a = *(const float4*)&ac[c4 * 4];
                    float4 c = *(const float4*)&ac[KDIM + c4 * 4];
                    v.x = fmaxf(v.x * a.x + c.x, 0.f);
                    v.y = fmaxf(v.y * a.y + c.y, 0.f);
                    v.z = fmaxf(v.z * a.z + c.z, 0.f);
                    v.w = fmaxf(v.w * a.w + c.w, 0.f);
                }
                ushort4 o; o.x = f2bf(v.x); o.y = f2bf(v.y); o.z = f2bf(v.z); o.w = f2bf(v.w);
                *(ushort4*)&alds[r * KP + c4 * 4] = o;
            }
        } else {
            const u16* inb = (const u16*)in_;
            for (int i = tid; i < 64 * (KDIM / 8); i += 256) {
                int r = i / (KDIM / 8), c8 = i % (KDIM / 8);
                int gr = row0 + r;
                uint4 v = (gr < nrows) ? *(const uint4*)&inb[(size_t)gr * KDIM + c8 * 8]
                                       : make_uint4(0u, 0u, 0u, 0u);
                *(uint4*)&alds[r * KP + c8 * 8] = v;
            }
        }
        __syncthreads();

        bf16x8 af[KB];
        #pragma unroll
        for (int kb = 0; kb < KB; kb++)
            af[kb] = *(const bf16x8*)&alds[(m0 + r16) * KP + kb * 32 + kg * 8];

        f32x4 acc[6];
        #pragma unroll
        for (int nt = 0; nt < 6; nt++) acc[nt] = (f32x4){bn[nt], bn[nt], bn[nt], bn[nt]};
        #pragma unroll
        for (int kb = 0; kb < KB; kb++) {
            #pragma unroll
            for (int nt = 0; nt < 6; nt++) {
                bf16x8 bfr = *(const bf16x8*)&wlds[(nt * 16 + r16) * KP + kb * 32 + kg * 8];
                acc[nt] = __builtin_amdgcn_mfma_f32_16x16x32_bf16(af[kb], bfr, acc[nt], 0, 0, 0);
            }
        }

        const int gr0  = row0 + m0 + kg * 4;
        const bool full = (gr0 + 3 < nrows);
        #pragma unroll
        for (int nt = 0; nt < 6; nt++) {
            float v[4] = {acc[nt][0], acc[nt][1], acc[nt][2], acc[nt][3]};
            if constexpr (OUT_RELU) {
                #pragma unroll
                for (int rr = 0; rr < 4; rr++) v[rr] = fmaxf(v[rr], 0.f);
            }
            const int n = nt * 16 + r16;
            #pragma unroll
            for (int rr = 0; rr < 4; rr++) {
                const int gr = gr0 + rr;
                if (full || gr < nrows) {
                    if constexpr (OUT_BF16) ((u16*)out_)[(size_t)gr * 96 + n] = f2bf(v[rr]);
                    else                    ((float*)out_)[(size_t)gr * 96 + n] = v[rr];
                    if constexpr (STATS) { scol[nt] += v[rr]; qcol[nt] += v[rr] * v[rr]; }
                }
            }
        }
    }

    if constexpr (STATS) {
        #pragma unroll
        for (int nt = 0; nt < 6; nt++) {
            scol[nt] += __shfl_xor(scol[nt], 16);
            scol[nt] += __shfl_xor(scol[nt], 32);
            qcol[nt] += __shfl_xor(qcol[nt], 16);
            qcol[nt] += __shfl_xor(qcol[nt], 32);
        }
        __syncthreads();
        if (kg == 0) {
            #pragma unroll
            for (int nt = 0; nt < 6; nt++) {
                sred[0][w][nt * 16 + r16] = scol[nt];
                sred[1][w][nt * 16 + r16] = qcol[nt];
            }
        }
        __syncthreads();
        if (tid < 96) {
            float a = (sred[0][0][tid] + sred[0][1][tid]) + (sred[0][2][tid] + sred[0][3][tid]);
            float b = (sred[1][0][tid] + sred[1][1][tid]) + (sred[1][2][tid] + sred[1][3][tid]);
            partials[(size_t)blockIdx.x * 192 + tid]      = a;
            partials[(size_t)blockIdx.x * 192 + 96 + tid] = b;
        }
    }
}

// ---------------- deterministic per-graph pool (batch sorted) ----------------
__device__ __forceinline__ int lower_bound_dev(const int* __restrict__ a, int n, int v) {
    int lo = 0, hi = n;
    while (lo < hi) { int m = (lo + hi) >> 1; if (a[m] < v) lo = m + 1; else hi = m; }
    return lo;
}
__global__ __launch_bounds__(96) void pool_det_kernel(const u16* __restrict__ hb,
                                                      const int* __restrict__ batch,
                                                      float* __restrict__ g) {
    const int gi = blockIdx.x;
    __shared__ int sh_lo, sh_hi;
    if (threadIdx.x == 0) sh_lo = lower_bound_dev(batch, N_NODES, gi);
    if (threadIdx.x == 1) sh_hi = lower_bound_dev(batch, N_NODES, gi + 1);
    __syncthreads();
    const int lo = sh_lo, hi = sh_hi;
    const int j = threadIdx.x;
    float s0 = 0.f, s1 = 0.f, s2 = 0.f, s3 = 0.f;
    int r = lo;
    for (; r + 4 <= hi; r += 4) {
        s0 += bf2f(hb[(size_t)r       * 96 + j]);
        s1 += bf2f(hb[(size_t)(r + 1) * 96 + j]);
        s2 += bf2f(hb[(size_t)(r + 2) * 96 + j]);
        s3 += bf2f(hb[(size_t)(r + 3) * 96 + j]);
    }
    for (; r < hi; r++) s0 += bf2f(hb[(size_t)r * 96 + j]);
    g[(size_t)gi * 96 + j] = (s0 + s1) + (s2 + s3);
}

// ---------------- f32 small matmul (G-sized tail; STATS -> slots) ----------------
template<int KDIM, bool IN_AFF, bool IN_RELU, bool OUT_RELU, bool STATS>
__global__ __launch_bounds__(192) void mm_kernel(const float* __restrict__ in,
                                                 const float* __restrict__ W,
                                                 const float* __restrict__ bias,
                                                 const float* __restrict__ ac,
                                                 float* __restrict__ out,
                                                 float* __restrict__ partials, int nrows) {
    constexpr int KG = KDIM / 4;
    __shared__ float ws[KDIM][96];
    __shared__ float xs[32][KDIM];
    const int tid = threadIdx.x;
    const int cg  = tid % 24;
    const int rg  = tid / 24;
    for (int i = tid; i < KDIM * 24; i += 192) {
        int k = i / 24, c4 = i % 24;
        *(float4*)&ws[k][c4 * 4] = *(const float4*)&W[(size_t)k * 96 + c4 * 4];
    }
    const float4 bj = *(const float4*)&bias[cg * 4];
    float s0=0,s1=0,s2=0,s3=0, q0=0,q1=0,q2=0,q3=0;
    const int nchunks = (nrows + 31) / 32;
    for (int chunk = blockIdx.x; chunk < nchunks; chunk += gridDim.x) {
        const int row0 = chunk * 32;
        __syncthreads();
        for (int i = tid; i < 32 * KG; i += 192) {
            int r = i / KG, g = i % KG;
            int gr = row0 + r;
            float4 v = make_float4(0.f, 0.f, 0.f, 0.f);
            if (gr < nrows) v = *(const float4*)&in[(size_t)gr * KDIM + g * 4];
            if constexpr (IN_AFF) {
                float4 a = *(const float4*)&ac[g * 4];
                float4 c = *(const float4*)&ac[KDIM + g * 4];
                v.x = v.x * a.x + c.x; v.y = v.y * a.y + c.y;
                v.z = v.z * a.z + c.z; v.w = v.w * a.w + c.w;
            }
            if constexpr (IN_RELU) {
                v.x = fmaxf(v.x, 0.f); v.y = fmaxf(v.y, 0.f);
                v.z = fmaxf(v.z, 0.f); v.w = fmaxf(v.w, 0.f);
            }
            *(float4*)&xs[r][4 * (g ^ (r & 7))] = v;
        }
        __syncthreads();
        float acc[4][4];
        #pragma unroll
        for (int m = 0; m < 4; m++) {
            acc[m][0] = bj.x; acc[m][1] = bj.y; acc[m][2] = bj.z; acc[m][3] = bj.w;
        }
        #pragma unroll 4
        for (int g = 0; g < KG; g++) {
            const int xi = 4 * (g ^ rg);
            float4 xv0 = *(const float4*)&xs[rg     ][xi];
            float4 xv1 = *(const float4*)&xs[rg +  8][xi];
            float4 xv2 = *(const float4*)&xs[rg + 16][xi];
            float4 xv3 = *(const float4*)&xs[rg + 24][xi];
            #pragma unroll
            for (int i = 0; i < 4; i++) {
                float4 wv = *(const float4*)&ws[g * 4 + i][cg * 4];
                float x0 = (i==0)?xv0.x:(i==1)?xv0.y:(i==2)?xv0.z:xv0.w;
                float x1 = (i==0)?xv1.x:(i==1)?xv1.y:(i==2)?xv1.z:xv1.w;
                float x2 = (i==0)?xv2.x:(i==1)?xv2.y:(i==2)?xv2.z:xv2.w;
                float x3 = (i==0)?xv3.x:(i==1)?xv3.y:(i==2)?xv3.z:xv3.w;
                acc[0][0] = fmaf(x0, wv.x, acc[0][0]); acc[0][1] = fmaf(x0, wv.y, acc[0][1]);
                acc[0][2] = fmaf(x0, wv.z, acc[0][2]); acc[0][3] = fmaf(x0, wv.w, acc[0][3]);
                acc[1][0] = fmaf(x1, wv.x, acc[1][0]); acc[1][1] = fmaf(x1, wv.y, acc[1][1]);
                acc[1][2] = fmaf(x1, wv.z, acc[1][2]); acc[1][3] = fmaf(x1, wv.w, acc[1][3]);
                acc[2][0] = fmaf(x2, wv.x, acc[2][0]); acc[2][1] = fmaf(x2, wv.y, acc[2][1]);
                acc[2][2] = fmaf(x2, wv.z, acc[2][2]); acc[2][3] = fmaf(x2, wv.w, acc[2][3]);
                acc[3][0] = fmaf(x3, wv.x, acc[3][0]); acc[3][1] = fmaf(x3, wv.y, acc[3][1]);
                acc[3][2] = fmaf(x3, wv.z, acc[3][2]); acc[3][3] = fmaf(x3, wv.w, acc[3][3]);
            }
        }
        #pragma unroll
        for (int m = 0; m < 4; m++) {
            const int gr = row0 + rg + 8 * m;
            if (gr < nrows) {
                float4 o = make_float4(acc[m][0], acc[m][1], acc[m][2], acc[m][3]);
                if constexpr (OUT_RELU) {
                    o.x = fmaxf(o.x, 0.f); o.y = fmaxf(o.y, 0.f);
                    o.z = fmaxf(o.z, 0.f); o.w = fmaxf(o.w, 0.f);
                }
                *(float4*)&out[(size_t)gr * 96 + cg * 4] = o;
                if constexpr (STATS) {
                    s0 += o.x; q0 += o.x * o.x; s1 += o.y; q1 += o.y * o.y;
                    s2 += o.z; q2 += o.z * o.z; s3 += o.w; q3 += o.w * o.w;
                }
            }
        }
    }
    if constexpr (STATS) {
        __syncthreads();
        float* rs = &xs[0][0];
        float* rq = rs + 8 * 96;
        rs[rg * 96 + cg * 4 + 0] = s0; rs[rg * 96 + cg * 4 + 1] = s1;
        rs[rg * 96 + cg * 4 + 2] = s2; rs[rg * 96 + cg * 4 + 3] = s3;
        rq[rg * 96 + cg * 4 + 0] = q0; rq[rg * 96 + cg * 4 + 1] = q1;
        rq[rg * 96 + cg * 4 + 2] = q2; rq[rg * 96 + cg * 4 + 3] = q3;
        __syncthreads();
        if (tid < 96) {
            float a = 0.f, b = 0.f;
            #pragma unroll
            for (int r = 0; r < 8; r++) { a += rs[r * 96 + tid]; b += rq[r * 96 + tid]; }
            partials[(size_t)blockIdx.x * 192 + tid]      = a;
            partials[(size_t)blockIdx.x * 192 + 96 + tid] = b;
        }
    }
}

// ---------------- head ----------------
__global__ void head_kernel(const float* __restrict__ g1, const float* __restrict__ ac,
                            const float* __restrict__ Wc, const float* __restrict__ bc,
                            float* __restrict__ out, int ngraphs) {
    int gi = blockIdx.x * blockDim.x + threadIdx.x;
    if (gi >= ngraphs) return;
    float v[NCLS];
    #pragma unroll
    for (int c = 0; c < NCLS; c++) v[c] = bc[c];
    for (int k = 0; k < HDIM; k++) {
        float x = g1[(size_t)gi * HDIM + k] * ac[k] + ac[HDIM + k];
        #pragma unroll
        for (int c = 0; c < NCLS; c++) v[c] = fmaf(x, Wc[k * NCLS + c], v[c]);
    }
    float mx = v[0];
    #pragma unroll
    for (int c = 1; c < NCLS; c++) mx = fmaxf(mx, v[c]);
    float sum = 0.f;
    #pragma unroll
    for (int c = 0; c < NCLS; c++) sum += expf(v[c] - mx);
    float lse = mx + logf(sum);
    #pragma unroll
    for (int c = 0; c < NCLS; c++) out[(size_t)gi * NCLS + c] = v[c] - lse;
}

extern "C" void kernel_launch(void* const* d_in, const int* in_sizes, int n_in,
                              void* d_out, int out_size, void* d_ws, size_t ws_size,
                              hipStream_t stream) {
    const float* x         = (const float*)d_in[0];
    const int*   ei        = (const int*)  d_in[1];
    const int*   batch     = (const int*)  d_in[2];
    const float* bn_feat_w = (const float*)d_in[3];
    const float* bn_feat_b = (const float*)d_in[4];
    const float* Wf        = (const float*)d_in[5];
    const float* bfv       = (const float*)d_in[6];
    const float* bn_fc_w   = (const float*)d_in[7];
    const float* bn_fc_b   = (const float*)d_in[8];
    const float* Wl        = (const float*)d_in[9];
    const float* bl        = (const float*)d_in[10];
    const float* bn_hid_w  = (const float*)d_in[11];
    const float* bn_hid_b  = (const float*)d_in[12];
    const float* Wc        = (const float*)d_in[13];
    const float* bc        = (const float*)d_in[14];
    float* out = (float*)d_out;

    char* p = (char*)d_ws;
    auto alloc = [&](size_t bytes) { char* q = p; p += (bytes + 255) & ~(size_t)255; return q; };

    // zero-region: deg only
    int*   deg    = (int*)  alloc((size_t)N_NODES * 4);

    // slot-partial buffers (fully rewritten each call -> no zeroing)
    float* pstatX = (float*)alloc((size_t)256 * 2 * F_IN * 4);
    float* pstatT = (float*)alloc((size_t)1024 * 192 * 4);
    float* pstatG = (float*)alloc((size_t)64 * 192 * 4);
    float* pstatG1= (float*)alloc((size_t)16 * 192 * 4);

    u16*   hb     = (u16*)  alloc((size_t)N_NODES * HDIM * 2);
    u16*   mb     = (u16*)  alloc((size_t)N_NODES * HDIM * 2);
    float* tf     = (float*)alloc((size_t)N_NODES * HDIM * 4);
    float* g      = (float*)alloc((size_t)N_GRAPHS * HDIM * 4);
    float* g1     = (float*)alloc((size_t)N_GRAPHS * HDIM * 4);
    float* acX    = (float*)alloc(2 * F_IN * 4);
    float* acT    = (float*)alloc(2 * HDIM * 4);
    float* acG    = (float*)alloc(2 * HDIM * 4);
    float* acHid  = (float*)alloc(2 * HDIM * 4);
    u16*   wtF    = (u16*)  alloc(96 * F_IN * 2);
    float* bFmod  = (float*)alloc(96 * 4);
    u16*   wtH    = (u16*)  alloc((size_t)6 * 96 * HDIM * 2);
    float* bmH    = (float*)alloc((size_t)6 * 96 * 4);
    int* row_ptr  = (int*)alloc((size_t)(N_NODES + 1) * 4);
    int* csr      = (int*)alloc((size_t)N_EDGES * 4);
    int* stmp     = (int*)alloc((size_t)N_NODES * 4);
    int* spart    = (int*)alloc(64 * 4);
    int* cnt      = (int*)alloc((size_t)NBUCK2 * NEB * 4);
    int* ofs      = (int*)alloc((size_t)NBUCK2 * NEB * 4);
    int* stmp2    = (int*)alloc((size_t)NBUCK2 * NEB * 4);
    int* spart2   = (int*)alloc(64 * 4);
    u32* ebuf     = (u32*)alloc((size_t)N_EDGES * 4);

    const int* srcp = ei;
    const int* dstp = ei + N_EDGES;

    const int nch64  = (N_NODES + 63) / 64;
    const int gridF  = (nch64 < 768) ? nch64 : 768;
    const int grid96 = (nch64 < 1024) ? nch64 : 1024;   // 782
    const int gridG  = (N_GRAPHS + 31) / 32;            // 16
    const int nscan  = (N_NODES + 1023) / 1024;
    const int ncb    = NBUCK2 * NEB;
    const int nscan2 = (ncb + 1023) / 1024;

    hipMemsetAsync(deg, 0, (size_t)N_NODES * 4, stream);

    // BN(x) stats (slots) -> finalize -> fold into Wf -> h = relu(x @ Wf' + bf')
    colstats4_kernel<F_IN><<<256, 256, 0, stream>>>(x, pstatX, N_NODES);
    reduce_finalize_kernel<<<1, F_IN, 0, stream>>>(pstatX, 256, bn_feat_w, bn_feat_b, acX, F_IN, 1.0f / N_NODES);
    wprep_all_kernel<<<WPF_BLOCKS + 6 * WPH_BLOCKS, 256, 0, stream>>>(
        Wf, bfv, acX,
        (const float*)d_in[15], (const float*)d_in[16],
        (const float*)d_in[19], (const float*)d_in[20],
        (const float*)d_in[21], (const float*)d_in[22],
        (const float*)d_in[25], (const float*)d_in[26],
        (const float*)d_in[27], (const float*)d_in[28],
        (const float*)d_in[31], (const float*)d_in[32],
        wtF, bFmod, wtH, bmH);
    mmx_kernel<F_IN, true, false, true, false, true><<<gridF, 256, 0, stream>>>(x, wtF, bFmod, nullptr, hb, nullptr, N_NODES);

    // CSR build
    count_kernel<<<NEB, 256, 0, stream>>>(dstp, deg, cnt);
    scan1_kernel<<<nscan, 1024, 0, stream>>>(deg, stmp, spart, N_NODES);
    scan3_rowptr_kernel<<<nscan, 1024, 0, stream>>>(stmp, spart, deg, row_ptr, N_NODES, nscan);
    scan1_kernel<<<nscan2, 1024, 0, stream>>>(cnt, stmp2, spart2, ncb);
    scan3_kernel<<<nscan2, 1024, 0, stream>>>(stmp2, spart2, ofs, ncb, nscan2);
    distribute_kernel<<<NEB, 256, 0, stream>>>(srcp, dstp, ofs, ebuf);
    bucket_fill_kernel<<<NBUCK2, 256, 0, stream>>>(ebuf, ofs, row_ptr, csr);

    for (int l = 0; l < 3; l++) {
        const float* bw = (const float*)d_in[17 + 6 * l];
        const float* bb = (const float*)d_in[18 + 6 * l];
        u16*   wt1 = wtH + (size_t)(2 * l)     * 96 * HDIM;
        u16*   wt2 = wtH + (size_t)(2 * l + 1) * 96 * HDIM;
        float* b1m = bmH + (size_t)(2 * l)     * 96;
        float* b2m = bmH + (size_t)(2 * l + 1) * 96;
        // m = h + sum_nbr(h)  (bf16 gathers, f64 accum -> order-insensitive)
        agg_kernel<<<(N_NODES + 15) / 16, 192, 0, stream>>>(hb, row_ptr, csr, mb, N_NODES);
        // t = m @ W1 + b1 -> f32 tf, stats as slot partials
        mmx_kernel<HDIM, false, false, false, true, false><<<grid96, 256, 0, stream>>>(mb, wt1, b1m, nullptr, tf, pstatT, N_NODES);
        reduce_finalize_kernel<<<1, HDIM, 0, stream>>>(pstatT, grid96, bw, bb, acT, HDIM, 1.0f / N_NODES);
        // h = relu( relu(BN(t_f32)) @ W2 + b2 ) -> bf16 hb (all layers)
        mmx_kernel<HDIM, true, true, true, false, true><<<grid96, 256, 0, stream>>>(tf, wt2, b2m, acT, hb, nullptr, N_NODES);
    }

    // deterministic per-graph pool
    pool_det_kernel<<<N_GRAPHS, 96, 0, stream>>>(hb, batch, g);

    // g1 = relu(BN_fc(g) @ Wl + bl), stats via slots
    colstats_kernel<HDIM><<<64, 2 * HDIM, 0, stream>>>(g, pstatG, N_GRAPHS);
    reduce_finalize_kernel<<<1, HDIM, 0, stream>>>(pstatG, 64, bn_fc_w, bn_fc_b, acG, HDIM, 1.0f / N_GRAPHS);
    mm_kernel<HDIM, true, false, true, true><<<gridG, 192, 0, stream>>>(g, Wl, bl, acG, g1, pstatG1, N_GRAPHS);
    reduce_finalize_kernel<<<1, HDIM, 0, stream>>>(pstatG1, gridG, bn_hid_w, bn_hid_b, acHid, HDIM, 1.0f / N_GRAPHS);

    head_kernel<<<2, 256, 0, stream>>>(g1, acHid, Wc, bc, out, N_GRAPHS);
}

// Round 12
// 394.975 us; speedup vs baseline: 1.2922x; 1.2922x over previous
//
#include <hip/hip_runtime.h>

#define N_NODES 50000
#define N_EDGES 800000
#define N_GRAPHS 512
#define F_IN 128
#define HDIM 96
#define NCLS 10
#define BN_EPS 1e-5f

// partitioned CSR fill geometry
#define NPB 128
#define NBUCK2 ((N_NODES + NPB - 1) / NPB) // 391 buckets
#define NEB 128
#define EPB ((N_EDGES + NEB - 1) / NEB)    // 6250 edges per block

typedef unsigned int u32;
typedef unsigned short u16;
typedef __attribute__((ext_vector_type(8))) short bf16x8;
typedef __attribute__((ext_vector_type(4))) float f32x4;

__device__ __forceinline__ u16 f2bf(float f) {
    u32 u = __float_as_uint(f);
    u32 r = (u + 0x7fffu + ((u >> 16) & 1u)) >> 16;   // RNE
    return (u16)r;
}
__device__ __forceinline__ float bflo(u32 w) { return __uint_as_float(w << 16); }
__device__ __forceinline__ float bfhi(u32 w) { return __uint_as_float(w & 0xffff0000u); }
__device__ __forceinline__ float bf2f(u16 v) { return __uint_as_float((u32)v << 16); }

// ---------------- column stats (slot partials, no atomics) ----------------
template<int NC>
__global__ __launch_bounds__(256) void colstats4_kernel(const float* __restrict__ in,
                                                        float* __restrict__ partials,
                                                        int nrows) {
    constexpr int CG  = NC / 4;
    constexpr int RPB = 256 / CG;
    const int cg = threadIdx.x % CG;
    const int rg = threadIdx.x / CG;
    float4 s = make_float4(0.f, 0.f, 0.f, 0.f);
    float4 q = make_float4(0.f, 0.f, 0.f, 0.f);
    for (int r = blockIdx.x * RPB + rg; r < nrows; r += gridDim.x * RPB) {
        float4 v = *(const float4*)&in[(size_t)r * NC + cg * 4];
        s.x += v.x; s.y += v.y; s.z += v.z; s.w += v.w;
        q.x += v.x * v.x; q.y += v.y * v.y; q.z += v.z * v.z; q.w += v.w * v.w;
    }
    __shared__ float ss[RPB][NC], sq[RPB][NC];
    *(float4*)&ss[rg][cg * 4] = s;
    *(float4*)&sq[rg][cg * 4] = q;
    __syncthreads();
    if (threadIdx.x < NC) {
        float a = 0.f, b = 0.f;
        #pragma unroll
        for (int r = 0; r < RPB; r++) { a += ss[r][threadIdx.x]; b += sq[r][threadIdx.x]; }
        partials[(size_t)blockIdx.x * 2 * NC + threadIdx.x]      = a;
        partials[(size_t)blockIdx.x * 2 * NC + NC + threadIdx.x] = b;
    }
}

template<int NC>
__global__ __launch_bounds__(2*NC) void colstats_kernel(const float* __restrict__ in,
                                                        float* __restrict__ partials,
                                                        int nrows) {
    const int col  = threadIdx.x % NC;
    const int half = threadIdx.x / NC;
    float s = 0.f, ss = 0.f;
    for (int r = blockIdx.x * 2 + half; r < nrows; r += gridDim.x * 2) {
        float v = in[(size_t)r * NC + col];
        s += v; ss += v * v;
    }
    __shared__ float shs[2][NC], shq[2][NC];
    shs[half][col] = s; shq[half][col] = ss;
    __syncthreads();
    if (half == 0) {
        partials[(size_t)blockIdx.x * 2 * NC + col]      = s  + shs[1][col];
        partials[(size_t)blockIdx.x * 2 * NC + NC + col] = ss + shq[1][col];
    }
}

// group-parallel fixed-order slot reduction + BN finalize (deterministic).
// NCOLS*8 threads: thread (k,grp) sums slots grp, grp+8, ... sequentially (fixed
// order), then a fixed-order 8-way tree in LDS. Coalesced reads across k.
template<int NCOLS>
__global__ __launch_bounds__(NCOLS * 8) void reduce_finalize_kernel(
        const float* __restrict__ partials, int nslots,
        const float* __restrict__ w,
        const float* __restrict__ b,
        float* __restrict__ ac, float inv_n) {
    const int k   = threadIdx.x % NCOLS;
    const int grp = threadIdx.x / NCOLS;   // 0..7
    const int stride = 2 * NCOLS;
    float s = 0.f, q = 0.f;
    for (int i = grp; i < nslots; i += 8) {
        s += partials[(size_t)i * stride + k];
        q += partials[(size_t)i * stride + NCOLS + k];
    }
    __shared__ float ss[8][NCOLS], sq[8][NCOLS];
    ss[grp][k] = s; sq[grp][k] = q;
    __syncthreads();
    if (grp == 0) {
        float S = ((ss[0][k] + ss[1][k]) + (ss[2][k] + ss[3][k]))
                + ((ss[4][k] + ss[5][k]) + (ss[6][k] + ss[7][k]));
        float Q = ((sq[0][k] + sq[1][k]) + (sq[2][k] + sq[3][k]))
                + ((sq[4][k] + sq[5][k]) + (sq[6][k] + sq[7][k]));
        float mu  = S * inv_n;
        float var = Q * inv_n - mu * mu;
        float a   = w[k] * rsqrtf(var + BN_EPS);
        ac[k]         = a;
        ac[NCOLS + k] = b[k] - mu * a;
    }
}

// ---------------- fused weight prep: all 7 weights in one launch ----------------
#define WPF_BLOCKS 48   // ceil(128*96/256)
#define WPH_BLOCKS 36   // 96*96/256
__global__ __launch_bounds__(256) void wprep_all_kernel(
        const float* __restrict__ Wf, const float* __restrict__ bf, const float* __restrict__ acX,
        const float* __restrict__ W0a, const float* __restrict__ b0a,
        const float* __restrict__ W0b, const float* __restrict__ b0b,
        const float* __restrict__ W1a, const float* __restrict__ b1a,
        const float* __restrict__ W1b, const float* __restrict__ b1b,
        const float* __restrict__ W2a, const float* __restrict__ b2a,
        const float* __restrict__ W2b, const float* __restrict__ b2b,
        u16* __restrict__ wtF, float* __restrict__ bFm,
        u16* __restrict__ wtbase, float* __restrict__ bmbase) {
    const int tid = threadIdx.x;
    int blk = blockIdx.x;
    if (blk < WPF_BLOCKS) {
        int i = blk * 256 + tid;
        if (i < F_IN * 96) {
            int k = i / 96, n = i % 96;
            wtF[n * F_IN + k] = f2bf(Wf[i] * acX[k]);
        }
        if (blk == 0 && tid < 96) {
            float b = bf[tid];
            for (int k = 0; k < F_IN; k++) b += acX[F_IN + k] * Wf[k * 96 + tid];
            bFm[tid] = b;
        }
        return;
    }
    blk -= WPF_BLOCKS;
    const int s  = blk / WPH_BLOCKS;
    const int b2 = blk % WPH_BLOCKS;
    const float* W; const float* bias;
    switch (s) {
        case 0: W = W0a; bias = b0a; break;
        case 1: W = W0b; bias = b0b; break;
        case 2: W = W1a; bias = b1a; break;
        case 3: W = W1b; bias = b1b; break;
        case 4: W = W2a; bias = b2a; break;
        default: W = W2b; bias = b2b; break;
    }
    u16*   wtb  = wtbase + (size_t)s * 96 * HDIM;
    float* bmod = bmbase + (size_t)s * 96;
    int i = b2 * 256 + tid;
    if (i < HDIM * 96) {
        int k = i / 96, n = i % 96;
        wtb[n * HDIM + k] = f2bf(W[i]);
    }
    if (b2 == 0 && tid < 96) bmod[tid] = bias[tid];
}

// ---------------- CSR build ----------------
__global__ __launch_bounds__(1024) void scan1_kernel(const int* __restrict__ in,
                                                     int* __restrict__ tmp,
                                                     int* __restrict__ partial, int n) {
    __shared__ int sh[1024];
    const int i = blockIdx.x * 1024 + threadIdx.x;
    const int d = (i < n) ? in[i] : 0;
    sh[threadIdx.x] = d;
    __syncthreads();
    for (int off = 1; off < 1024; off <<= 1) {
        int v = 0;
        if (threadIdx.x >= off) v = sh[threadIdx.x - off];
        __syncthreads();
        sh[threadIdx.x] += v;
        __syncthreads();
    }
    if (i < n) tmp[i] = sh[threadIdx.x] - d;
    if (threadIdx.x == 1023) partial[blockIdx.x] = sh[1023];
}

__global__ __launch_bounds__(1024) void scan3_rowptr_kernel(const int* __restrict__ tmp,
                                                            const int* __restrict__ partial,
                                                            const int* __restrict__ deg,
                                                            int* __restrict__ row_ptr,
                                                            int n, int nparts) {
    __shared__ int offs;
    if (threadIdx.x < 64) {
        int v = (threadIdx.x < blockIdx.x && threadIdx.x < nparts) ? partial[threadIdx.x] : 0;
        for (int o = 32; o > 0; o >>= 1) v += __shfl_down(v, o, 64);
        if (threadIdx.x == 0) offs = v;
    }
    __syncthreads();
    const int i = blockIdx.x * 1024 + threadIdx.x;
    if (i < n) {
        int v = tmp[i] + offs;
        row_ptr[i] = v;
        if (i == n - 1) row_ptr[n] = v + deg[i];
    }
}

__global__ __launch_bounds__(1024) void scan3_kernel(const int* __restrict__ tmp,
                                                     const int* __restrict__ partial,
                                                     int* __restrict__ out,
                                                     int n, int nparts) {
    __shared__ int offs;
    if (threadIdx.x < 64) {
        int v = (threadIdx.x < blockIdx.x && threadIdx.x < nparts) ? partial[threadIdx.x] : 0;
        for (int o = 32; o > 0; o >>= 1) v += __shfl_down(v, o, 64);
        if (threadIdx.x == 0) offs = v;
    }
    __syncthreads();
    const int i = blockIdx.x * 1024 + threadIdx.x;
    if (i < n) out[i] = tmp[i] + offs;
}

__global__ __launch_bounds__(256) void count_kernel(const int* __restrict__ dst,
                                                    int* __restrict__ deg,
                                                    int* __restrict__ cnt) {
    __shared__ int lc[NBUCK2];
    for (int i = threadIdx.x; i < NBUCK2; i += 256) lc[i] = 0;
    __syncthreads();
    const int lo = blockIdx.x * EPB;
    const int hi = min(lo + EPB, N_EDGES);
    for (int e = lo + threadIdx.x; e < hi; e += 256) {
        int d = dst[e];
        atomicAdd(&lc[d / NPB], 1);
        atomicAdd(&deg[d], 1);
    }
    __syncthreads();
    for (int i = threadIdx.x; i < NBUCK2; i += 256)
        cnt[i * NEB + blockIdx.x] = lc[i];
}

__global__ __launch_bounds__(256) void distribute_kernel(const int* __restrict__ src,
                                                         const int* __restrict__ dst,
                                                         const int* __restrict__ ofs,
                                                         u32* __restrict__ ebuf) {
    __shared__ int lofs[NBUCK2];
    for (int i = threadIdx.x; i < NBUCK2; i += 256) lofs[i] = ofs[i * NEB + blockIdx.x];
    __syncthreads();
    const int lo = blockIdx.x * EPB;
    const int hi = min(lo + EPB, N_EDGES);
    for (int e = lo + threadIdx.x; e < hi; e += 256) {
        int d = dst[e];
        int q = atomicAdd(&lofs[d / NPB], 1);
        ebuf[q] = ((u32)src[e] << 7) | (u32)(d & (NPB - 1));
    }
}

__global__ __launch_bounds__(256) void bucket_fill_kernel(const u32* __restrict__ ebuf,
                                                          const int* __restrict__ ofs,
                                                          const int* __restrict__ row_ptr,
                                                          int* __restrict__ csr) {
    __shared__ int cur[NPB];
    const int p    = blockIdx.x;
    const int base = p * NPB;
    const int nn   = min(NPB, N_NODES - base);
    for (int i = threadIdx.x; i < nn; i += 256) cur[i] = row_ptr[base + i];
    __syncthreads();
    const int e0 = ofs[p * NEB];
    const int e1 = (p + 1 < NBUCK2) ? ofs[(p + 1) * NEB] : N_EDGES;
    for (int e = e0 + threadIdx.x; e < e1; e += 256) {
        u32 v = ebuf[e];
        int pos = atomicAdd(&cur[v & (NPB - 1)], 1);
        csr[pos] = (int)(v >> 7);
    }
}

// ---------------- GIN aggregation (bf16 gathers, f64 accumulation) ----------------
__device__ __forceinline__ void acc8lo(double& a, u32 w0,u32 w1,u32 w2,u32 w3,u32 w4,u32 w5,u32 w6,u32 w7){
    a += bflo(w0); a += bflo(w1); a += bflo(w2); a += bflo(w3);
    a += bflo(w4); a += bflo(w5); a += bflo(w6); a += bflo(w7);
}
__device__ __forceinline__ void acc8hi(double& a, u32 w0,u32 w1,u32 w2,u32 w3,u32 w4,u32 w5,u32 w6,u32 w7){
    a += bfhi(w0); a += bfhi(w1); a += bfhi(w2); a += bfhi(w3);
    a += bfhi(w4); a += bfhi(w5); a += bfhi(w6); a += bfhi(w7);
}
__global__ __launch_bounds__(192) void agg_kernel(const u16* __restrict__ hb,
                                                  const int* __restrict__ row_ptr,
                                                  const int* __restrict__ csr,
                                                  u16* __restrict__ mb, int n) {
    const int jj   = threadIdx.x % 12;
    const int node = blockIdx.x * 16 + threadIdx.x / 12;
    if (node >= n) return;
    const int p0 = row_ptr[node], p1 = row_ptr[node + 1];
    uint4 sv = *(const uint4*)&hb[(size_t)node * 96 + jj * 8];
    double a0 = bflo(sv.x), a1 = bfhi(sv.x), a2 = bflo(sv.y), a3 = bfhi(sv.y);
    double a4 = bflo(sv.z), a5 = bfhi(sv.z), a6 = bflo(sv.w), a7 = bfhi(sv.w);
    int p = p0;
    for (; p + 8 <= p1; p += 8) {
        int s0 = csr[p],     s1 = csr[p + 1], s2 = csr[p + 2], s3 = csr[p + 3];
        int s4 = csr[p + 4], s5 = csr[p + 5], s6 = csr[p + 6], s7 = csr[p + 7];
        uint4 v0 = *(const uint4*)&hb[(size_t)s0 * 96 + jj * 8];
        uint4 v1 = *(const uint4*)&hb[(size_t)s1 * 96 + jj * 8];
        uint4 v2 = *(const uint4*)&hb[(size_t)s2 * 96 + jj * 8];
        uint4 v3 = *(const uint4*)&hb[(size_t)s3 * 96 + jj * 8];
        uint4 v4 = *(const uint4*)&hb[(size_t)s4 * 96 + jj * 8];
        uint4 v5 = *(const uint4*)&hb[(size_t)s5 * 96 + jj * 8];
        uint4 v6 = *(const uint4*)&hb[(size_t)s6 * 96 + jj * 8];
        uint4 v7 = *(const uint4*)&hb[(size_t)s7 * 96 + jj * 8];
        acc8lo(a0, v0.x,v1.x,v2.x,v3.x,v4.x,v5.x,v6.x,v7.x);
        acc8hi(a1, v0.x,v1.x,v2.x,v3.x,v4.x,v5.x,v6.x,v7.x);
        acc8lo(a2, v0.y,v1.y,v2.y,v3.y,v4.y,v5.y,v6.y,v7.y);
        acc8hi(a3, v0.y,v1.y,v2.y,v3.y,v4.y,v5.y,v6.y,v7.y);
        acc8lo(a4, v0.z,v1.z,v2.z,v3.z,v4.z,v5.z,v6.z,v7.z);
        acc8hi(a5, v0.z,v1.z,v2.z,v3.z,v4.z,v5.z,v6.z,v7.z);
        acc8lo(a6, v0.w,v1.w,v2.w,v3.w,v4.w,v5.w,v6.w,v7.w);
        acc8hi(a7, v0.w,v1.w,v2.w,v3.w,v4.w,v5.w,v6.w,v7.w);
    }
    for (; p < p1; p++) {
        int s = csr[p];
        uint4 v = *(const uint4*)&hb[(size_t)s * 96 + jj * 8];
        a0 += bflo(v.x); a1 += bfhi(v.x); a2 += bflo(v.y); a3 += bfhi(v.y);
        a4 += bflo(v.z); a5 += bfhi(v.z); a6 += bflo(v.w); a7 += bfhi(v.w);
    }
    uint4 o;
    o.x = (u32)f2bf((float)a0) | ((u32)f2bf((float)a1) << 16);
    o.y = (u32)f2bf((float)a2) | ((u32)f2bf((float)a3) << 16);
    o.z = (u32)f2bf((float)a4) | ((u32)f2bf((float)a5) << 16);
    o.w = (u32)f2bf((float)a6) | ((u32)f2bf((float)a7) << 16);
    *(uint4*)&mb[(size_t)node * 96 + jj * 8] = o;
}

// ---------------- MFMA matmul (STATS -> slot partials, deterministic) ----------------
template<int KDIM, bool IN_F32, bool IN_AFF_RELU, bool OUT_RELU, bool STATS, bool OUT_BF16>
__global__ __launch_bounds__(256) void mmx_kernel(const void* __restrict__ in_,
                                                  const u16* __restrict__ wt,
                                                  const float* __restrict__ bias,
                                                  const float* __restrict__ ac,
                                                  void* __restrict__ out_,
                                                  float* __restrict__ partials,
                                                  int nrows) {
    constexpr int KP = KDIM + 8;
    constexpr int KB = KDIM / 32;
    __shared__ u16 wlds[96 * KP];
    __shared__ u16 alds[64 * KP];
    __shared__ float sred[2][4][96];
    const int tid = threadIdx.x;

    for (int i = tid; i < 96 * (KDIM / 8); i += 256) {
        int nn = i / (KDIM / 8), c8 = i % (KDIM / 8);
        *(uint4*)&wlds[nn * KP + c8 * 8] = *(const uint4*)&wt[nn * KDIM + c8 * 8];
    }

    const int w    = tid >> 6;
    const int lane = tid & 63;
    const int r16  = lane & 15;
    const int kg   = lane >> 4;
    const int m0   = w * 16;
    float bn[6];
    #pragma unroll
    for (int nt = 0; nt < 6; nt++) bn[nt] = bias[nt * 16 + r16];
    float scol[6] = {0,0,0,0,0,0}, qcol[6] = {0,0,0,0,0,0};

    const int nchunks = (nrows + 63) / 64;
    for (int chunk = blockIdx.x; chunk < nchunks; chunk += gridDim.x) {
        const int row0 = chunk * 64;
        __syncthreads();
        if constexpr (IN_F32) {
            const float* inf = (const float*)in_;
            for (int i = tid; i < 64 * (KDIM / 4); i += 256) {
                int r = i / (KDIM / 4), c4 = i % (KDIM / 4);
                int gr = row0 + r;
                float4 v = (gr < nrows) ? *(const float4*)&inf[(size_t)gr * KDIM + c4 * 4]
                                        : make_float4(0.f, 0.f, 0.f, 0.f);
                if constexpr (IN_AFF_RELU) {
                    float4 a = *(const float4*)&ac[c4 * 4];
                    float4 c = *(const float4*)&ac[KDIM + c4 * 4];
                    v.x = fmaxf(v.x * a.x + c.x, 0.f);
                    v.y = fmaxf(v.y * a.y + c.y, 0.f);
                    v.z = fmaxf(v.z * a.z + c.z, 0.f);
                    v.w = fmaxf(v.w * a.w + c.w, 0.f);
                }
                ushort4 o; o.x = f2bf(v.x); o.y = f2bf(v.y); o.z = f2bf(v.z); o.w = f2bf(v.w);
                *(ushort4*)&alds[r * KP + c4 * 4] = o;
            }
        } else {
            const u16* inb = (const u16*)in_;
            for (int i = tid; i < 64 * (KDIM / 8); i += 256) {
                int r = i / (KDIM / 8), c8 = i % (KDIM / 8);
                int gr = row0 + r;
                uint4 v = (gr < nrows) ? *(const uint4*)&inb[(size_t)gr * KDIM + c8 * 8]
                                       : make_uint4(0u, 0u, 0u, 0u);
                *(uint4*)&alds[r * KP + c8 * 8] = v;
            }
        }
        __syncthreads();

        bf16x8 af[KB];
        #pragma unroll
        for (int kb = 0; kb < KB; kb++)
            af[kb] = *(const bf16x8*)&alds[(m0 + r16) * KP + kb * 32 + kg * 8];

        f32x4 acc[6];
        #pragma unroll
        for (int nt = 0; nt < 6; nt++) acc[nt] = (f32x4){bn[nt], bn[nt], bn[nt], bn[nt]};
        #pragma unroll
        for (int kb = 0; kb < KB; kb++) {
            #pragma unroll
            for (int nt = 0; nt < 6; nt++) {
                bf16x8 bfr = *(const bf16x8*)&wlds[(nt * 16 + r16) * KP + kb * 32 + kg * 8];
                acc[nt] = __builtin_amdgcn_mfma_f32_16x16x32_bf16(af[kb], bfr, acc[nt], 0, 0, 0);
            }
        }

        const int gr0  = row0 + m0 + kg * 4;
        const bool full = (gr0 + 3 < nrows);
        #pragma unroll
        for (int nt = 0; nt < 6; nt++) {
            float v[4] = {acc[nt][0], acc[nt][1], acc[nt][2], acc[nt][3]};
            if constexpr (OUT_RELU) {
                #pragma unroll
                for (int rr = 0; rr < 4; rr++) v[rr] = fmaxf(v[rr], 0.f);
            }
            const int n = nt * 16 + r16;
            #pragma unroll
            for (int rr = 0; rr < 4; rr++) {
                const int gr = gr0 + rr;
                if (full || gr < nrows) {
                    if constexpr (OUT_BF16) ((u16*)out_)[(size_t)gr * 96 + n] = f2bf(v[rr]);
                    else                    ((float*)out_)[(size_t)gr * 96 + n] = v[rr];
                    if constexpr (STATS) { scol[nt] += v[rr]; qcol[nt] += v[rr] * v[rr]; }
                }
            }
        }
    }

    if constexpr (STATS) {
        #pragma unroll
        for (int nt = 0; nt < 6; nt++) {
            scol[nt] += __shfl_xor(scol[nt], 16);
            scol[nt] += __shfl_xor(scol[nt], 32);
            qcol[nt] += __shfl_xor(qcol[nt], 16);
            qcol[nt] += __shfl_xor(qcol[nt], 32);
        }
        __syncthreads();
        if (kg == 0) {
            #pragma unroll
            for (int nt = 0; nt < 6; nt++) {
                sred[0][w][nt * 16 + r16] = scol[nt];
                sred[1][w][nt * 16 + r16] = qcol[nt];
            }
        }
        __syncthreads();
        if (tid < 96) {
            float a = (sred[0][0][tid] + sred[0][1][tid]) + (sred[0][2][tid] + sred[0][3][tid]);
            float b = (sred[1][0][tid] + sred[1][1][tid]) + (sred[1][2][tid] + sred[1][3][tid]);
            partials[(size_t)blockIdx.x * 192 + tid]      = a;
            partials[(size_t)blockIdx.x * 192 + 96 + tid] = b;
        }
    }
}

// ---------------- deterministic per-graph pool (batch sorted) ----------------
__device__ __forceinline__ int lower_bound_dev(const int* __restrict__ a, int n, int v) {
    int lo = 0, hi = n;
    while (lo < hi) { int m = (lo + hi) >> 1; if (a[m] < v) lo = m + 1; else hi = m; }
    return lo;
}
__global__ __launch_bounds__(96) void pool_det_kernel(const u16* __restrict__ hb,
                                                      const int* __restrict__ batch,
                                                      float* __restrict__ g) {
    const int gi = blockIdx.x;
    __shared__ int sh_lo, sh_hi;
    if (threadIdx.x == 0) sh_lo = lower_bound_dev(batch, N_NODES, gi);
    if (threadIdx.x == 1) sh_hi = lower_bound_dev(batch, N_NODES, gi + 1);
    __syncthreads();
    const int lo = sh_lo, hi = sh_hi;
    const int j = threadIdx.x;
    float s0 = 0.f, s1 = 0.f, s2 = 0.f, s3 = 0.f;
    int r = lo;
    for (; r + 4 <= hi; r += 4) {
        s0 += bf2f(hb[(size_t)r       * 96 + j]);
        s1 += bf2f(hb[(size_t)(r + 1) * 96 + j]);
        s2 += bf2f(hb[(size_t)(r + 2) * 96 + j]);
        s3 += bf2f(hb[(size_t)(r + 3) * 96 + j]);
    }
    for (; r < hi; r++) s0 += bf2f(hb[(size_t)r * 96 + j]);
    g[(size_t)gi * 96 + j] = (s0 + s1) + (s2 + s3);
}

// ---------------- f32 small matmul (G-sized tail; STATS -> slots) ----------------
template<int KDIM, bool IN_AFF, bool IN_RELU, bool OUT_RELU, bool STATS>
__global__ __launch_bounds__(192) void mm_kernel(const float* __restrict__ in,
                                                 const float* __restrict__ W,
                                                 const float* __restrict__ bias,
                                                 const float* __restrict__ ac,
                                                 float* __restrict__ out,
                                                 float* __restrict__ partials, int nrows) {
    constexpr int KG = KDIM / 4;
    __shared__ float ws[KDIM][96];
    __shared__ float xs[32][KDIM];
    const int tid = threadIdx.x;
    const int cg  = tid % 24;
    const int rg  = tid / 24;
    for (int i = tid; i < KDIM * 24; i += 192) {
        int k = i / 24, c4 = i % 24;
        *(float4*)&ws[k][c4 * 4] = *(const float4*)&W[(size_t)k * 96 + c4 * 4];
    }
    const float4 bj = *(const float4*)&bias[cg * 4];
    float s0=0,s1=0,s2=0,s3=0, q0=0,q1=0,q2=0,q3=0;
    const int nchunks = (nrows + 31) / 32;
    for (int chunk = blockIdx.x; chunk < nchunks; chunk += gridDim.x) {
        const int row0 = chunk * 32;
        __syncthreads();
        for (int i = tid; i < 32 * KG; i += 192) {
            int r = i / KG, g = i % KG;
            int gr = row0 + r;
            float4 v = make_float4(0.f, 0.f, 0.f, 0.f);
            if (gr < nrows) v = *(const float4*)&in[(size_t)gr * KDIM + g * 4];
            if constexpr (IN_AFF) {
                float4 a = *(const float4*)&ac[g * 4];
                float4 c = *(const float4*)&ac[KDIM + g * 4];
                v.x = v.x * a.x + c.x; v.y = v.y * a.y + c.y;
                v.z = v.z * a.z + c.z; v.w = v.w * a.w + c.w;
            }
            if constexpr (IN_RELU) {
                v.x = fmaxf(v.x, 0.f); v.y = fmaxf(v.y, 0.f);
                v.z = fmaxf(v.z, 0.f); v.w = fmaxf(v.w, 0.f);
            }
            *(float4*)&xs[r][4 * (g ^ (r & 7))] = v;
        }
        __syncthreads();
        float acc[4][4];
        #pragma unroll
        for (int m = 0; m < 4; m++) {
            acc[m][0] = bj.x; acc[m][1] = bj.y; acc[m][2] = bj.z; acc[m][3] = bj.w;
        }
        #pragma unroll 4
        for (int g = 0; g < KG; g++) {
            const int xi = 4 * (g ^ rg);
            float4 xv0 = *(const float4*)&xs[rg     ][xi];
            float4 xv1 = *(const float4*)&xs[rg +  8][xi];
            float4 xv2 = *(const float4*)&xs[rg + 16][xi];
            float4 xv3 = *(const float4*)&xs[rg + 24][xi];
            #pragma unroll
            for (int i = 0; i < 4; i++) {
                float4 wv = *(const float4*)&ws[g * 4 + i][cg * 4];
                float x0 = (i==0)?xv0.x:(i==1)?xv0.y:(i==2)?xv0.z:xv0.w;
                float x1 = (i==0)?xv1.x:(i==1)?xv1.y:(i==2)?xv1.z:xv1.w;
                float x2 = (i==0)?xv2.x:(i==1)?xv2.y:(i==2)?xv2.z:xv2.w;
                float x3 = (i==0)?xv3.x:(i==1)?xv3.y:(i==2)?xv3.z:xv3.w;
                acc[0][0] = fmaf(x0, wv.x, acc[0][0]); acc[0][1] = fmaf(x0, wv.y, acc[0][1]);
                acc[0][2] = fmaf(x0, wv.z, acc[0][2]); acc[0][3] = fmaf(x0, wv.w, acc[0][3]);
                acc[1][0] = fmaf(x1, wv.x, acc[1][0]); acc[1][1] = fmaf(x1, wv.y, acc[1][1]);
                acc[1][2] = fmaf(x1, wv.z, acc[1][2]); acc[1][3] = fmaf(x1, wv.w, acc[1][3]);
                acc[2][0] = fmaf(x2, wv.x, acc[2][0]); acc[2][1] = fmaf(x2, wv.y, acc[2][1]);
                acc[2][2] = fmaf(x2, wv.z, acc[2][2]); acc[2][3] = fmaf(x2, wv.w, acc[2][3]);
                acc[3][0] = fmaf(x3, wv.x, acc[3][0]); acc[3][1] = fmaf(x3, wv.y, acc[3][1]);
                acc[3][2] = fmaf(x3, wv.z, acc[3][2]); acc[3][3] = fmaf(x3, wv.w, acc[3][3]);
            }
        }
        #pragma unroll
        for (int m = 0; m < 4; m++) {
            const int gr = row0 + rg + 8 * m;
            if (gr < nrows) {
                float4 o = make_float4(acc[m][0], acc[m][1], acc[m][2], acc[m][3]);
                if constexpr (OUT_RELU) {
                    o.x = fmaxf(o.x, 0.f); o.y = fmaxf(o.y, 0.f);
                    o.z = fmaxf(o.z, 0.f); o.w = fmaxf(o.w, 0.f);
                }
                *(float4*)&out[(size_t)gr * 96 + cg * 4] = o;
                if constexpr (STATS) {
                    s0 += o.x; q0 += o.x * o.x; s1 += o.y; q1 += o.y * o.y;
                    s2 += o.z; q2 += o.z * o.z; s3 += o.w; q3 += o.w * o.w;
                }
            }
        }
    }
    if constexpr (STATS) {
        __syncthreads();
        float* rs = &xs[0][0];
        float* rq = rs + 8 * 96;
        rs[rg * 96 + cg * 4 + 0] = s0; rs[rg * 96 + cg * 4 + 1] = s1;
        rs[rg * 96 + cg * 4 + 2] = s2; rs[rg * 96 + cg * 4 + 3] = s3;
        rq[rg * 96 + cg * 4 + 0] = q0; rq[rg * 96 + cg * 4 + 1] = q1;
        rq[rg * 96 + cg * 4 + 2] = q2; rq[rg * 96 + cg * 4 + 3] = q3;
        __syncthreads();
        if (tid < 96) {
            float a = 0.f, b = 0.f;
            #pragma unroll
            for (int r = 0; r < 8; r++) { a += rs[r * 96 + tid]; b += rq[r * 96 + tid]; }
            partials[(size_t)blockIdx.x * 192 + tid]      = a;
            partials[(size_t)blockIdx.x * 192 + 96 + tid] = b;
        }
    }
}

// ---------------- head ----------------
__global__ void head_kernel(const float* __restrict__ g1, const float* __restrict__ ac,
                            const float* __restrict__ Wc, const float* __restrict__ bc,
                            float* __restrict__ out, int ngraphs) {
    int gi = blockIdx.x * blockDim.x + threadIdx.x;
    if (gi >= ngraphs) return;
    float v[NCLS];
    #pragma unroll
    for (int c = 0; c < NCLS; c++) v[c] = bc[c];
    for (int k = 0; k < HDIM; k++) {
        float x = g1[(size_t)gi * HDIM + k] * ac[k] + ac[HDIM + k];
        #pragma unroll
        for (int c = 0; c < NCLS; c++) v[c] = fmaf(x, Wc[k * NCLS + c], v[c]);
    }
    float mx = v[0];
    #pragma unroll
    for (int c = 1; c < NCLS; c++) mx = fmaxf(mx, v[c]);
    float sum = 0.f;
    #pragma unroll
    for (int c = 0; c < NCLS; c++) sum += expf(v[c] - mx);
    float lse = mx + logf(sum);
    #pragma unroll
    for (int c = 0; c < NCLS; c++) out[(size_t)gi * NCLS + c] = v[c] - lse;
}

extern "C" void kernel_launch(void* const* d_in, const int* in_sizes, int n_in,
                              void* d_out, int out_size, void* d_ws, size_t ws_size,
                              hipStream_t stream) {
    const float* x         = (const float*)d_in[0];
    const int*   ei        = (const int*)  d_in[1];
    const int*   batch     = (const int*)  d_in[2];
    const float* bn_feat_w = (const float*)d_in[3];
    const float* bn_feat_b = (const float*)d_in[4];
    const float* Wf        = (const float*)d_in[5];
    const float* bfv       = (const float*)d_in[6];
    const float* bn_fc_w   = (const float*)d_in[7];
    const float* bn_fc_b   = (const float*)d_in[8];
    const float* Wl        = (const float*)d_in[9];
    const float* bl        = (const float*)d_in[10];
    const float* bn_hid_w  = (const float*)d_in[11];
    const float* bn_hid_b  = (const float*)d_in[12];
    const float* Wc        = (const float*)d_in[13];
    const float* bc        = (const float*)d_in[14];
    float* out = (float*)d_out;

    char* p = (char*)d_ws;
    auto alloc = [&](size_t bytes) { char* q = p; p += (bytes + 255) & ~(size_t)255; return q; };

    // zero-region: deg only
    int*   deg    = (int*)  alloc((size_t)N_NODES * 4);

    // slot-partial buffers (fully rewritten each call -> no zeroing)
    float* pstatX = (float*)alloc((size_t)256 * 2 * F_IN * 4);
    float* pstatT = (float*)alloc((size_t)1024 * 192 * 4);
    float* pstatG = (float*)alloc((size_t)64 * 192 * 4);
    float* pstatG1= (float*)alloc((size_t)16 * 192 * 4);

    u16*   hb     = (u16*)  alloc((size_t)N_NODES * HDIM * 2);
    u16*   mb     = (u16*)  alloc((size_t)N_NODES * HDIM * 2);
    float* tf     = (float*)alloc((size_t)N_NODES * HDIM * 4);
    float* g      = (float*)alloc((size_t)N_GRAPHS * HDIM * 4);
    float* g1     = (float*)alloc((size_t)N_GRAPHS * HDIM * 4);
    float* acX    = (float*)alloc(2 * F_IN * 4);
    float* acT    = (float*)alloc(2 * HDIM * 4);
    float* acG    = (float*)alloc(2 * HDIM * 4);
    float* acHid  = (float*)alloc(2 * HDIM * 4);
    u16*   wtF    = (u16*)  alloc(96 * F_IN * 2);
    float* bFmod  = (float*)alloc(96 * 4);
    u16*   wtH    = (u16*)  alloc((size_t)6 * 96 * HDIM * 2);
    float* bmH    = (float*)alloc((size_t)6 * 96 * 4);
    int* row_ptr  = (int*)alloc((size_t)(N_NODES + 1) * 4);
    int* csr      = (int*)alloc((size_t)N_EDGES * 4);
    int* stmp     = (int*)alloc((size_t)N_NODES * 4);
    int* spart    = (int*)alloc(64 * 4);
    int* cnt      = (int*)alloc((size_t)NBUCK2 * NEB * 4);
    int* ofs      = (int*)alloc((size_t)NBUCK2 * NEB * 4);
    int* stmp2    = (int*)alloc((size_t)NBUCK2 * NEB * 4);
    int* spart2   = (int*)alloc(64 * 4);
    u32* ebuf     = (u32*)alloc((size_t)N_EDGES * 4);

    const int* srcp = ei;
    const int* dstp = ei + N_EDGES;

    const int nch64  = (N_NODES + 63) / 64;
    const int gridF  = (nch64 < 768) ? nch64 : 768;
    const int grid96 = (nch64 < 1024) ? nch64 : 1024;   // 782
    const int gridG  = (N_GRAPHS + 31) / 32;            // 16
    const int nscan  = (N_NODES + 1023) / 1024;
    const int ncb    = NBUCK2 * NEB;
    const int nscan2 = (ncb + 1023) / 1024;

    hipMemsetAsync(deg, 0, (size_t)N_NODES * 4, stream);

    // BN(x) stats (slots) -> finalize -> fold into Wf -> h = relu(x @ Wf' + bf')
    colstats4_kernel<F_IN><<<256, 256, 0, stream>>>(x, pstatX, N_NODES);
    reduce_finalize_kernel<F_IN><<<1, F_IN * 8, 0, stream>>>(pstatX, 256, bn_feat_w, bn_feat_b, acX, 1.0f / N_NODES);
    wprep_all_kernel<<<WPF_BLOCKS + 6 * WPH_BLOCKS, 256, 0, stream>>>(
        Wf, bfv, acX,
        (const float*)d_in[15], (const float*)d_in[16],
        (const float*)d_in[19], (const float*)d_in[20],
        (const float*)d_in[21], (const float*)d_in[22],
        (const float*)d_in[25], (const float*)d_in[26],
        (const float*)d_in[27], (const float*)d_in[28],
        (const float*)d_in[31], (const float*)d_in[32],
        wtF, bFmod, wtH, bmH);
    mmx_kernel<F_IN, true, false, true, false, true><<<gridF, 256, 0, stream>>>(x, wtF, bFmod, nullptr, hb, nullptr, N_NODES);

    // CSR build
    count_kernel<<<NEB, 256, 0, stream>>>(dstp, deg, cnt);
    scan1_kernel<<<nscan, 1024, 0, stream>>>(deg, stmp, spart, N_NODES);
    scan3_rowptr_kernel<<<nscan, 1024, 0, stream>>>(stmp, spart, deg, row_ptr, N_NODES, nscan);
    scan1_kernel<<<nscan2, 1024, 0, stream>>>(cnt, stmp2, spart2, ncb);
    scan3_kernel<<<nscan2, 1024, 0, stream>>>(stmp2, spart2, ofs, ncb, nscan2);
    distribute_kernel<<<NEB, 256, 0, stream>>>(srcp, dstp, ofs, ebuf);
    bucket_fill_kernel<<<NBUCK2, 256, 0, stream>>>(ebuf, ofs, row_ptr, csr);

    for (int l = 0; l < 3; l++) {
        const float* bw = (const float*)d_in[17 + 6 * l];
        const float* bb = (const float*)d_in[18 + 6 * l];
        u16*   wt1 = wtH + (size_t)(2 * l)     * 96 * HDIM;
        u16*   wt2 = wtH + (size_t)(2 * l + 1) * 96 * HDIM;
        float* b1m = bmH + (size_t)(2 * l)     * 96;
        float* b2m = bmH + (size_t)(2 * l + 1) * 96;
        // m = h + sum_nbr(h)  (bf16 gathers, f64 accum -> order-insensitive)
        agg_kernel<<<(N_NODES + 15) / 16, 192, 0, stream>>>(hb, row_ptr, csr, mb, N_NODES);
        // t = m @ W1 + b1 -> f32 tf, stats as slot partials
        mmx_kernel<HDIM, false, false, false, true, false><<<grid96, 256, 0, stream>>>(mb, wt1, b1m, nullptr, tf, pstatT, N_NODES);
        reduce_finalize_kernel<HDIM><<<1, HDIM * 8, 0, stream>>>(pstatT, grid96, bw, bb, acT, 1.0f / N_NODES);
        // h = relu( relu(BN(t_f32)) @ W2 + b2 ) -> bf16 hb (all layers)
        mmx_kernel<HDIM, true, true, true, false, true><<<grid96, 256, 0, stream>>>(tf, wt2, b2m, acT, hb, nullptr, N_NODES);
    }

    // deterministic per-graph pool
    pool_det_kernel<<<N_GRAPHS, 96, 0, stream>>>(hb, batch, g);

    // g1 = relu(BN_fc(g) @ Wl + bl), stats via slots
    colstats_kernel<HDIM><<<64, 2 * HDIM, 0, stream>>>(g, pstatG, N_GRAPHS);
    reduce_finalize_kernel<HDIM><<<1, HDIM * 8, 0, stream>>>(pstatG, 64, bn_fc_w, bn_fc_b, acG, 1.0f / N_GRAPHS);
    mm_kernel<HDIM, true, false, true, true><<<gridG, 192, 0, stream>>>(g, Wl, bl, acG, g1, pstatG1, N_GRAPHS);
    reduce_finalize_kernel<HDIM><<<1, HDIM * 8, 0, stream>>>(pstatG1, gridG, bn_hid_w, bn_hid_b, acHid, 1.0f / N_GRAPHS);

    head_kernel<<<2, 256, 0, stream>>>(g1, acHid, Wc, bc, out, N_GRAPHS);
}

// Round 13
// 392.285 us; speedup vs baseline: 1.3010x; 1.0069x over previous
//
#include <hip/hip_runtime.h>

#define N_NODES 50000
#define N_EDGES 800000
#define N_GRAPHS 512
#define F_IN 128
#define HDIM 96
#define NCLS 10
#define BN_EPS 1e-5f

// partitioned CSR fill geometry
#define NPB 128
#define NBUCK2 ((N_NODES + NPB - 1) / NPB) // 391 buckets
#define NEB 128
#define EPB ((N_EDGES + NEB - 1) / NEB)    // 6250 edges per block

typedef unsigned int u32;
typedef unsigned short u16;
typedef __attribute__((ext_vector_type(8))) short bf16x8;
typedef __attribute__((ext_vector_type(4))) float f32x4;

__device__ __forceinline__ u16 f2bf(float f) {
    u32 u = __float_as_uint(f);
    u32 r = (u + 0x7fffu + ((u >> 16) & 1u)) >> 16;   // RNE
    return (u16)r;
}
__device__ __forceinline__ float bflo(u32 w) { return __uint_as_float(w << 16); }
__device__ __forceinline__ float bfhi(u32 w) { return __uint_as_float(w & 0xffff0000u); }
__device__ __forceinline__ float bf2f(u16 v) { return __uint_as_float((u32)v << 16); }

// ---------------- column stats for x (slot partials, no atomics) ----------------
template<int NC>
__global__ __launch_bounds__(256) void colstats4_kernel(const float* __restrict__ in,
                                                        float* __restrict__ partials,
                                                        int nrows) {
    constexpr int CG  = NC / 4;
    constexpr int RPB = 256 / CG;
    const int cg = threadIdx.x % CG;
    const int rg = threadIdx.x / CG;
    float4 s = make_float4(0.f, 0.f, 0.f, 0.f);
    float4 q = make_float4(0.f, 0.f, 0.f, 0.f);
    for (int r = blockIdx.x * RPB + rg; r < nrows; r += gridDim.x * RPB) {
        float4 v = *(const float4*)&in[(size_t)r * NC + cg * 4];
        s.x += v.x; s.y += v.y; s.z += v.z; s.w += v.w;
        q.x += v.x * v.x; q.y += v.y * v.y; q.z += v.z * v.z; q.w += v.w * v.w;
    }
    __shared__ float ss[RPB][NC], sq[RPB][NC];
    *(float4*)&ss[rg][cg * 4] = s;
    *(float4*)&sq[rg][cg * 4] = q;
    __syncthreads();
    if (threadIdx.x < NC) {
        float a = 0.f, b = 0.f;
        #pragma unroll
        for (int r = 0; r < RPB; r++) { a += ss[r][threadIdx.x]; b += sq[r][threadIdx.x]; }
        partials[(size_t)blockIdx.x * 2 * NC + threadIdx.x]      = a;
        partials[(size_t)blockIdx.x * 2 * NC + NC + threadIdx.x] = b;
    }
}

// group-parallel fixed-order slot reduction + BN finalize (deterministic)
template<int NCOLS>
__global__ __launch_bounds__(NCOLS * 8) void reduce_finalize_kernel(
        const float* __restrict__ partials, int nslots,
        const float* __restrict__ w,
        const float* __restrict__ b,
        float* __restrict__ ac, float inv_n) {
    const int k   = threadIdx.x % NCOLS;
    const int grp = threadIdx.x / NCOLS;   // 0..7
    const int stride = 2 * NCOLS;
    float s = 0.f, q = 0.f;
    for (int i = grp; i < nslots; i += 8) {
        s += partials[(size_t)i * stride + k];
        q += partials[(size_t)i * stride + NCOLS + k];
    }
    __shared__ float ss[8][NCOLS], sq[8][NCOLS];
    ss[grp][k] = s; sq[grp][k] = q;
    __syncthreads();
    if (grp == 0) {
        float S = ((ss[0][k] + ss[1][k]) + (ss[2][k] + ss[3][k]))
                + ((ss[4][k] + ss[5][k]) + (ss[6][k] + ss[7][k]));
        float Q = ((sq[0][k] + sq[1][k]) + (sq[2][k] + sq[3][k]))
                + ((sq[4][k] + sq[5][k]) + (sq[6][k] + sq[7][k]));
        float mu  = S * inv_n;
        float var = Q * inv_n - mu * mu;
        float a   = w[k] * rsqrtf(var + BN_EPS);
        ac[k]         = a;
        ac[NCOLS + k] = b[k] - mu * a;
    }
}

// ---------------- fused weight prep: all 7 weights in one launch ----------------
#define WPF_BLOCKS 48   // ceil(128*96/256)
#define WPH_BLOCKS 36   // 96*96/256
__global__ __launch_bounds__(256) void wprep_all_kernel(
        const float* __restrict__ Wf, const float* __restrict__ bf, const float* __restrict__ acX,
        const float* __restrict__ W0a, const float* __restrict__ b0a,
        const float* __restrict__ W0b, const float* __restrict__ b0b,
        const float* __restrict__ W1a, const float* __restrict__ b1a,
        const float* __restrict__ W1b, const float* __restrict__ b1b,
        const float* __restrict__ W2a, const float* __restrict__ b2a,
        const float* __restrict__ W2b, const float* __restrict__ b2b,
        u16* __restrict__ wtF, float* __restrict__ bFm,
        u16* __restrict__ wtbase, float* __restrict__ bmbase) {
    const int tid = threadIdx.x;
    int blk = blockIdx.x;
    if (blk < WPF_BLOCKS) {
        int i = blk * 256 + tid;
        if (i < F_IN * 96) {
            int k = i / 96, n = i % 96;
            wtF[n * F_IN + k] = f2bf(Wf[i] * acX[k]);
        }
        if (blk == 0 && tid < 96) {
            float b = bf[tid];
            for (int k = 0; k < F_IN; k++) b += acX[F_IN + k] * Wf[k * 96 + tid];
            bFm[tid] = b;
        }
        return;
    }
    blk -= WPF_BLOCKS;
    const int s  = blk / WPH_BLOCKS;
    const int b2 = blk % WPH_BLOCKS;
    const float* W; const float* bias;
    switch (s) {
        case 0: W = W0a; bias = b0a; break;
        case 1: W = W0b; bias = b0b; break;
        case 2: W = W1a; bias = b1a; break;
        case 3: W = W1b; bias = b1b; break;
        case 4: W = W2a; bias = b2a; break;
        default: W = W2b; bias = b2b; break;
    }
    u16*   wtb  = wtbase + (size_t)s * 96 * HDIM;
    float* bmod = bmbase + (size_t)s * 96;
    int i = b2 * 256 + tid;
    if (i < HDIM * 96) {
        int k = i / 96, n = i % 96;
        wtb[n * HDIM + k] = f2bf(W[i]);
    }
    if (b2 == 0 && tid < 96) bmod[tid] = bias[tid];
}

// ---------------- CSR build (fused two-segment scans) ----------------
__global__ __launch_bounds__(1024) void scan1_fused_kernel(
        const int* __restrict__ inA, int nA, int* __restrict__ tmpA, int* __restrict__ partA,
        const int* __restrict__ inB, int nB, int* __restrict__ tmpB, int* __restrict__ partB,
        int nblkA) {
    const int* in; int n; int* tmp; int* partial; int base;
    if ((int)blockIdx.x < nblkA) { in = inA; n = nA; tmp = tmpA; partial = partA; base = blockIdx.x; }
    else                         { in = inB; n = nB; tmp = tmpB; partial = partB; base = blockIdx.x - nblkA; }
    __shared__ int sh[1024];
    const int i = base * 1024 + threadIdx.x;
    const int d = (i < n) ? in[i] : 0;
    sh[threadIdx.x] = d;
    __syncthreads();
    for (int off = 1; off < 1024; off <<= 1) {
        int v = 0;
        if (threadIdx.x >= off) v = sh[threadIdx.x - off];
        __syncthreads();
        sh[threadIdx.x] += v;
        __syncthreads();
    }
    if (i < n) tmp[i] = sh[threadIdx.x] - d;
    if (threadIdx.x == 1023) partial[base] = sh[1023];
}

__global__ __launch_bounds__(1024) void scan3_fused_kernel(
        const int* __restrict__ tmpA, const int* __restrict__ partA,
        const int* __restrict__ degA, int* __restrict__ row_ptr, int nA, int npA,
        const int* __restrict__ tmpB, const int* __restrict__ partB,
        int* __restrict__ ofs, int nB, int npB, int nblkA) {
    const int* tmp; const int* partial; int n, nparts, base; bool isA;
    if ((int)blockIdx.x < nblkA) { tmp = tmpA; partial = partA; n = nA; nparts = npA; base = blockIdx.x; isA = true; }
    else                         { tmp = tmpB; partial = partB; n = nB; nparts = npB; base = blockIdx.x - nblkA; isA = false; }
    __shared__ int offs;
    if (threadIdx.x < 64) {
        int v = (threadIdx.x < base && (int)threadIdx.x < nparts) ? partial[threadIdx.x] : 0;
        for (int o = 32; o > 0; o >>= 1) v += __shfl_down(v, o, 64);
        if (threadIdx.x == 0) offs = v;
    }
    __syncthreads();
    const int i = base * 1024 + threadIdx.x;
    if (i < n) {
        int v = tmp[i] + offs;
        if (isA) {
            row_ptr[i] = v;
            if (i == n - 1) row_ptr[n] = v + degA[i];
        } else {
            ofs[i] = v;
        }
    }
}

__global__ __launch_bounds__(256) void count_kernel(const int* __restrict__ dst,
                                                    int* __restrict__ deg,
                                                    int* __restrict__ cnt) {
    __shared__ int lc[NBUCK2];
    for (int i = threadIdx.x; i < NBUCK2; i += 256) lc[i] = 0;
    __syncthreads();
    const int lo = blockIdx.x * EPB;
    const int hi = min(lo + EPB, N_EDGES);
    for (int e = lo + threadIdx.x; e < hi; e += 256) {
        int d = dst[e];
        atomicAdd(&lc[d / NPB], 1);
        atomicAdd(&deg[d], 1);
    }
    __syncthreads();
    for (int i = threadIdx.x; i < NBUCK2; i += 256)
        cnt[i * NEB + blockIdx.x] = lc[i];
}

__global__ __launch_bounds__(256) void distribute_kernel(const int* __restrict__ src,
                                                         const int* __restrict__ dst,
                                                         const int* __restrict__ ofs,
                                                         u32* __restrict__ ebuf) {
    __shared__ int lofs[NBUCK2];
    for (int i = threadIdx.x; i < NBUCK2; i += 256) lofs[i] = ofs[i * NEB + blockIdx.x];
    __syncthreads();
    const int lo = blockIdx.x * EPB;
    const int hi = min(lo + EPB, N_EDGES);
    for (int e = lo + threadIdx.x; e < hi; e += 256) {
        int d = dst[e];
        int q = atomicAdd(&lofs[d / NPB], 1);
        ebuf[q] = ((u32)src[e] << 7) | (u32)(d & (NPB - 1));
    }
}

__global__ __launch_bounds__(256) void bucket_fill_kernel(const u32* __restrict__ ebuf,
                                                          const int* __restrict__ ofs,
                                                          const int* __restrict__ row_ptr,
                                                          int* __restrict__ csr) {
    __shared__ int cur[NPB];
    const int p    = blockIdx.x;
    const int base = p * NPB;
    const int nn   = min(NPB, N_NODES - base);
    for (int i = threadIdx.x; i < nn; i += 256) cur[i] = row_ptr[base + i];
    __syncthreads();
    const int e0 = ofs[p * NEB];
    const int e1 = (p + 1 < NBUCK2) ? ofs[(p + 1) * NEB] : N_EDGES;
    for (int e = e0 + threadIdx.x; e < e1; e += 256) {
        u32 v = ebuf[e];
        int pos = atomicAdd(&cur[v & (NPB - 1)], 1);
        csr[pos] = (int)(v >> 7);
    }
}

// ---------------- fused GIN agg + mm1:  tf = (h + sum_nbr h) @ W1 + b1, stats(tf) ----------------
// Staging computes the aggregation directly into alds (f64 accum -> csr-order-insensitive).
__global__ __launch_bounds__(256) void aggmm_kernel(const u16* __restrict__ hb,
                                                    const int* __restrict__ row_ptr,
                                                    const int* __restrict__ csr,
                                                    const u16* __restrict__ wt,   // [96][96] bf16
                                                    const float* __restrict__ bias,
                                                    float* __restrict__ tf,
                                                    float* __restrict__ partials,
                                                    int nrows) {
    constexpr int KP = HDIM + 8;      // 104
    constexpr int KB = HDIM / 32;     // 3
    __shared__ u16 wlds[96 * KP];
    __shared__ u16 alds[64 * KP];
    __shared__ float sred[2][4][96];
    const int tid = threadIdx.x;

    for (int i = tid; i < 96 * (HDIM / 8); i += 256) {
        int nn = i / (HDIM / 8), c8 = i % (HDIM / 8);
        *(uint4*)&wlds[nn * KP + c8 * 8] = *(const uint4*)&wt[nn * HDIM + c8 * 8];
    }

    const int w    = tid >> 6;
    const int lane = tid & 63;
    const int r16  = lane & 15;
    const int kg   = lane >> 4;
    const int m0   = w * 16;
    float bn[6];
    #pragma unroll
    for (int nt = 0; nt < 6; nt++) bn[nt] = bias[nt * 16 + r16];
    float scol[6] = {0,0,0,0,0,0}, qcol[6] = {0,0,0,0,0,0};

    const int nchunks = (nrows + 63) / 64;
    for (int chunk = blockIdx.x; chunk < nchunks; chunk += gridDim.x) {
        const int row0 = chunk * 64;
        __syncthreads();
        // staging: each task = (row r in chunk, 8-col slice sl); 768 tasks / 256 thr
        for (int t = tid; t < 64 * 12; t += 256) {
            const int r  = t / 12, sl = t % 12;
            const int node = row0 + r;
            uint4 ov = make_uint4(0u, 0u, 0u, 0u);
            if (node < nrows) {
                const int p0 = row_ptr[node], p1 = row_ptr[node + 1];
                uint4 sv = *(const uint4*)&hb[(size_t)node * 96 + sl * 8];
                double a0 = bflo(sv.x), a1 = bfhi(sv.x), a2 = bflo(sv.y), a3 = bfhi(sv.y);
                double a4 = bflo(sv.z), a5 = bfhi(sv.z), a6 = bflo(sv.w), a7 = bfhi(sv.w);
                int p = p0;
                for (; p + 4 <= p1; p += 4) {
                    int s0 = csr[p], s1 = csr[p + 1], s2 = csr[p + 2], s3 = csr[p + 3];
                    uint4 v0 = *(const uint4*)&hb[(size_t)s0 * 96 + sl * 8];
                    uint4 v1 = *(const uint4*)&hb[(size_t)s1 * 96 + sl * 8];
                    uint4 v2 = *(const uint4*)&hb[(size_t)s2 * 96 + sl * 8];
                    uint4 v3 = *(const uint4*)&hb[(size_t)s3 * 96 + sl * 8];
                    a0 += bflo(v0.x); a0 += bflo(v1.x); a0 += bflo(v2.x); a0 += bflo(v3.x);
                    a1 += bfhi(v0.x); a1 += bfhi(v1.x); a1 += bfhi(v2.x); a1 += bfhi(v3.x);
                    a2 += bflo(v0.y); a2 += bflo(v1.y); a2 += bflo(v2.y); a2 += bflo(v3.y);
                    a3 += bfhi(v0.y); a3 += bfhi(v1.y); a3 += bfhi(v2.y); a3 += bfhi(v3.y);
                    a4 += bflo(v0.z); a4 += bflo(v1.z); a4 += bflo(v2.z); a4 += bflo(v3.z);
                    a5 += bfhi(v0.z); a5 += bfhi(v1.z); a5 += bfhi(v2.z); a5 += bfhi(v3.z);
                    a6 += bflo(v0.w); a6 += bflo(v1.w); a6 += bflo(v2.w); a6 += bflo(v3.w);
                    a7 += bfhi(v0.w); a7 += bfhi(v1.w); a7 += bfhi(v2.w); a7 += bfhi(v3.w);
                }
                for (; p < p1; p++) {
                    int s = csr[p];
                    uint4 v = *(const uint4*)&hb[(size_t)s * 96 + sl * 8];
                    a0 += bflo(v.x); a1 += bfhi(v.x); a2 += bflo(v.y); a3 += bfhi(v.y);
                    a4 += bflo(v.z); a5 += bfhi(v.z); a6 += bflo(v.w); a7 += bfhi(v.w);
                }
                ov.x = (u32)f2bf((float)a0) | ((u32)f2bf((float)a1) << 16);
                ov.y = (u32)f2bf((float)a2) | ((u32)f2bf((float)a3) << 16);
                ov.z = (u32)f2bf((float)a4) | ((u32)f2bf((float)a5) << 16);
                ov.w = (u32)f2bf((float)a6) | ((u32)f2bf((float)a7) << 16);
            }
            *(uint4*)&alds[r * KP + sl * 8] = ov;
        }
        __syncthreads();

        bf16x8 af[KB];
        #pragma unroll
        for (int kb = 0; kb < KB; kb++)
            af[kb] = *(const bf16x8*)&alds[(m0 + r16) * KP + kb * 32 + kg * 8];

        f32x4 acc[6];
        #pragma unroll
        for (int nt = 0; nt < 6; nt++) acc[nt] = (f32x4){bn[nt], bn[nt], bn[nt], bn[nt]};
        #pragma unroll
        for (int kb = 0; kb < KB; kb++) {
            #pragma unroll
            for (int nt = 0; nt < 6; nt++) {
                bf16x8 bfr = *(const bf16x8*)&wlds[(nt * 16 + r16) * KP + kb * 32 + kg * 8];
                acc[nt] = __builtin_amdgcn_mfma_f32_16x16x32_bf16(af[kb], bfr, acc[nt], 0, 0, 0);
            }
        }

        const int gr0  = row0 + m0 + kg * 4;
        const bool full = (gr0 + 3 < nrows);
        #pragma unroll
        for (int nt = 0; nt < 6; nt++) {
            const int n = nt * 16 + r16;
            #pragma unroll
            for (int rr = 0; rr < 4; rr++) {
                const int gr = gr0 + rr;
                if (full || gr < nrows) {
                    float v = acc[nt][rr];
                    tf[(size_t)gr * 96 + n] = v;
                    scol[nt] += v; qcol[nt] += v * v;
                }
            }
        }
    }

    #pragma unroll
    for (int nt = 0; nt < 6; nt++) {
        scol[nt] += __shfl_xor(scol[nt], 16);
        scol[nt] += __shfl_xor(scol[nt], 32);
        qcol[nt] += __shfl_xor(qcol[nt], 16);
        qcol[nt] += __shfl_xor(qcol[nt], 32);
    }
    __syncthreads();
    if (kg == 0) {
        #pragma unroll
        for (int nt = 0; nt < 6; nt++) {
            sred[0][w][nt * 16 + r16] = scol[nt];
            sred[1][w][nt * 16 + r16] = qcol[nt];
        }
    }
    __syncthreads();
    if (tid < 96) {
        float a = (sred[0][0][tid] + sred[0][1][tid]) + (sred[0][2][tid] + sred[0][3][tid]);
        float b = (sred[1][0][tid] + sred[1][1][tid]) + (sred[1][2][tid] + sred[1][3][tid]);
        partials[(size_t)blockIdx.x * 192 + tid]      = a;
        partials[(size_t)blockIdx.x * 192 + 96 + tid] = b;
    }
}

// ---------------- MFMA matmul (mmF and mm2) ----------------
template<int KDIM, bool IN_F32, bool IN_AFF_RELU, bool OUT_RELU, bool STATS, bool OUT_BF16>
__global__ __launch_bounds__(256) void mmx_kernel(const void* __restrict__ in_,
                                                  const u16* __restrict__ wt,
                                                  const float* __restrict__ bias,
                                                  const float* __restrict__ ac,
                                                  void* __restrict__ out_,
                                                  float* __restrict__ partials,
                                                  int nrows) {
    constexpr int KP = KDIM + 8;
    constexpr int KB = KDIM / 32;
    __shared__ u16 wlds[96 * KP];
    __shared__ u16 alds[64 * KP];
    __shared__ float sred[2][4][96];
    const int tid = threadIdx.x;

    for (int i = tid; i < 96 * (KDIM / 8); i += 256) {
        int nn = i / (KDIM / 8), c8 = i % (KDIM / 8);
        *(uint4*)&wlds[nn * KP + c8 * 8] = *(const uint4*)&wt[nn * KDIM + c8 * 8];
    }

    const int w    = tid >> 6;
    const int lane = tid & 63;
    const int r16  = lane & 15;
    const int kg   = lane >> 4;
    const int m0   = w * 16;
    float bn[6];
    #pragma unroll
    for (int nt = 0; nt < 6; nt++) bn[nt] = bias[nt * 16 + r16];
    float scol[6] = {0,0,0,0,0,0}, qcol[6] = {0,0,0,0,0,0};

    const int nchunks = (nrows + 63) / 64;
    for (int chunk = blockIdx.x; chunk < nchunks; chunk += gridDim.x) {
        const int row0 = chunk * 64;
        __syncthreads();
        if constexpr (IN_F32) {
            const float* inf = (const float*)in_;
            for (int i = tid; i < 64 * (KDIM / 4); i += 256) {
                int r = i / (KDIM / 4), c4 = i % (KDIM / 4);
                int gr = row0 + r;
                float4 v = (gr < nrows) ? *(const float4*)&inf[(size_t)gr * KDIM + c4 * 4]
                                        : make_float4(0.f, 0.f, 0.f, 0.f);
                if constexpr (IN_AFF_RELU) {
                    float4 a = *(const float4*)&ac[c4 * 4];
                    float4 c = *(const float4*)&ac[KDIM + c4 * 4];
                    v.x = fmaxf(v.x * a.x + c.x, 0.f);
                    v.y = fmaxf(v.y * a.y + c.y, 0.f);
                    v.z = fmaxf(v.z * a.z + c.z, 0.f);
                    v.w = fmaxf(v.w * a.w + c.w, 0.f);
                }
                ushort4 o; o.x = f2bf(v.x); o.y = f2bf(v.y); o.z = f2bf(v.z); o.w = f2bf(v.w);
                *(ushort4*)&alds[r * KP + c4 * 4] = o;
            }
        } else {
            const u16* inb = (const u16*)in_;
            for (int i = tid; i < 64 * (KDIM / 8); i += 256) {
                int r = i / (KDIM / 8), c8 = i % (KDIM / 8);
                int gr = row0 + r;
                uint4 v = (gr < nrows) ? *(const uint4*)&inb[(size_t)gr * KDIM + c8 * 8]
                                       : make_uint4(0u, 0u, 0u, 0u);
                *(uint4*)&alds[r * KP + c8 * 8] = v;
            }
        }
        __syncthreads();

        bf16x8 af[KB];
        #pragma unroll
        for (int kb = 0; kb < KB; kb++)
            af[kb] = *(const bf16x8*)&alds[(m0 + r16) * KP + kb * 32 + kg * 8];

        f32x4 acc[6];
        #pragma unroll
        for (int nt = 0; nt < 6; nt++) acc[nt] = (f32x4){bn[nt], bn[nt], bn[nt], bn[nt]};
        #pragma unroll
        for (int kb = 0; kb < KB; kb++) {
            #pragma unroll
            for (int nt = 0; nt < 6; nt++) {
                bf16x8 bfr = *(const bf16x8*)&wlds[(nt * 16 + r16) * KP + kb * 32 + kg * 8];
                acc[nt] = __builtin_amdgcn_mfma_f32_16x16x32_bf16(af[kb], bfr, acc[nt], 0, 0, 0);
            }
        }

        const int gr0  = row0 + m0 + kg * 4;
        const bool full = (gr0 + 3 < nrows);
        #pragma unroll
        for (int nt = 0; nt < 6; nt++) {
            float v[4] = {acc[nt][0], acc[nt][1], acc[nt][2], acc[nt][3]};
            if constexpr (OUT_RELU) {
                #pragma unroll
                for (int rr = 0; rr < 4; rr++) v[rr] = fmaxf(v[rr], 0.f);
            }
            const int n = nt * 16 + r16;
            #pragma unroll
            for (int rr = 0; rr < 4; rr++) {
                const int gr = gr0 + rr;
                if (full || gr < nrows) {
                    if constexpr (OUT_BF16) ((u16*)out_)[(size_t)gr * 96 + n] = f2bf(v[rr]);
                    else                    ((float*)out_)[(size_t)gr * 96 + n] = v[rr];
                    if constexpr (STATS) { scol[nt] += v[rr]; qcol[nt] += v[rr] * v[rr]; }
                }
            }
        }
    }

    if constexpr (STATS) {
        #pragma unroll
        for (int nt = 0; nt < 6; nt++) {
            scol[nt] += __shfl_xor(scol[nt], 16);
            scol[nt] += __shfl_xor(scol[nt], 32);
            qcol[nt] += __shfl_xor(qcol[nt], 16);
            qcol[nt] += __shfl_xor(qcol[nt], 32);
        }
        __syncthreads();
        if (kg == 0) {
            #pragma unroll
            for (int nt = 0; nt < 6; nt++) {
                sred[0][w][nt * 16 + r16] = scol[nt];
                sred[1][w][nt * 16 + r16] = qcol[nt];
            }
        }
        __syncthreads();
        if (tid < 96) {
            float a = (sred[0][0][tid] + sred[0][1][tid]) + (sred[0][2][tid] + sred[0][3][tid]);
            float b = (sred[1][0][tid] + sred[1][1][tid]) + (sred[1][2][tid] + sred[1][3][tid]);
            partials[(size_t)blockIdx.x * 192 + tid]      = a;
            partials[(size_t)blockIdx.x * 192 + 96 + tid] = b;
        }
    }
}

// ---------------- deterministic per-graph pool + fused stats partials ----------------
__device__ __forceinline__ int lower_bound_dev(const int* __restrict__ a, int n, int v) {
    int lo = 0, hi = n;
    while (lo < hi) { int m = (lo + hi) >> 1; if (a[m] < v) lo = m + 1; else hi = m; }
    return lo;
}
__global__ __launch_bounds__(96) void pool_stats_kernel(const u16* __restrict__ hb,
                                                        const int* __restrict__ batch,
                                                        float* __restrict__ g,
                                                        float* __restrict__ partials) {
    const int gi = blockIdx.x;
    __shared__ int sh_lo, sh_hi;
    if (threadIdx.x == 0) sh_lo = lower_bound_dev(batch, N_NODES, gi);
    if (threadIdx.x == 1) sh_hi = lower_bound_dev(batch, N_NODES, gi + 1);
    __syncthreads();
    const int lo = sh_lo, hi = sh_hi;
    const int j = threadIdx.x;
    float s0 = 0.f, s1 = 0.f, s2 = 0.f, s3 = 0.f;
    int r = lo;
    for (; r + 4 <= hi; r += 4) {
        s0 += bf2f(hb[(size_t)r       * 96 + j]);
        s1 += bf2f(hb[(size_t)(r + 1) * 96 + j]);
        s2 += bf2f(hb[(size_t)(r + 2) * 96 + j]);
        s3 += bf2f(hb[(size_t)(r + 3) * 96 + j]);
    }
    for (; r < hi; r++) s0 += bf2f(hb[(size_t)r * 96 + j]);
    float val = (s0 + s1) + (s2 + s3);
    g[(size_t)gi * 96 + j] = val;
    partials[(size_t)gi * 192 + j]      = val;
    partials[(size_t)gi * 192 + 96 + j] = val * val;
}

// ---------------- f32 small matmul (G-sized tail; STATS -> slots) ----------------
template<int KDIM, bool IN_AFF, bool IN_RELU, bool OUT_RELU, bool STATS>
__global__ __launch_bounds__(192) void mm_kernel(const float* __restrict__ in,
                                                 const float* __restrict__ W,
                                                 const float* __restrict__ bias,
                                                 const float* __restrict__ ac,
                                                 float* __restrict__ out,
                                                 float* __restrict__ partials, int nrows) {
    constexpr int KG = KDIM / 4;
    __shared__ float ws[KDIM][96];
    __shared__ float xs[32][KDIM];
    const int tid = threadIdx.x;
    const int cg  = tid % 24;
    const int rg  = tid / 24;
    for (int i = tid; i < KDIM * 24; i += 192) {
        int k = i / 24, c4 = i % 24;
        *(float4*)&ws[k][c4 * 4] = *(const float4*)&W[(size_t)k * 96 + c4 * 4];
    }
    const float4 bj = *(const float4*)&bias[cg * 4];
    float s0=0,s1=0,s2=0,s3=0, q0=0,q1=0,q2=0,q3=0;
    const int nchunks = (nrows + 31) / 32;
    for (int chunk = blockIdx.x; chunk < nchunks; chunk += gridDim.x) {
        const int row0 = chunk * 32;
        __syncthreads();
        for (int i = tid; i < 32 * KG; i += 192) {
            int r = i / KG, g = i % KG;
            int gr = row0 + r;
            float4 v = make_float4(0.f, 0.f, 0.f, 0.f);
            if (gr < nrows) v = *(const float4*)&in[(size_t)gr * KDIM + g * 4];
            if constexpr (IN_AFF) {
                float4 a = *(const float4*)&ac[g * 4];
                float4 c = *(const float4*)&ac[KDIM + g * 4];
                v.x = v.x * a.x + c.x; v.y = v.y * a.y + c.y;
                v.z = v.z * a.z + c.z; v.w = v.w * a.w + c.w;
            }
            if constexpr (IN_RELU) {
                v.x = fmaxf(v.x, 0.f); v.y = fmaxf(v.y, 0.f);
                v.z = fmaxf(v.z, 0.f); v.w = fmaxf(v.w, 0.f);
            }
            *(float4*)&xs[r][4 * (g ^ (r & 7))] = v;
        }
        __syncthreads();
        float acc[4][4];
        #pragma unroll
        for (int m = 0; m < 4; m++) {
            acc[m][0] = bj.x; acc[m][1] = bj.y; acc[m][2] = bj.z; acc[m][3] = bj.w;
        }
        #pragma unroll 4
        for (int g = 0; g < KG; g++) {
            const int xi = 4 * (g ^ rg);
            float4 xv0 = *(const float4*)&xs[rg     ][xi];
            float4 xv1 = *(const float4*)&xs[rg +  8][xi];
            float4 xv2 = *(const float4*)&xs[rg + 16][xi];
            float4 xv3 = *(const float4*)&xs[rg + 24][xi];
            #pragma unroll
            for (int i = 0; i < 4; i++) {
                float4 wv = *(const float4*)&ws[g * 4 + i][cg * 4];
                float x0 = (i==0)?xv0.x:(i==1)?xv0.y:(i==2)?xv0.z:xv0.w;
                float x1 = (i==0)?xv1.x:(i==1)?xv1.y:(i==2)?xv1.z:xv1.w;
                float x2 = (i==0)?xv2.x:(i==1)?xv2.y:(i==2)?xv2.z:xv2.w;
                float x3 = (i==0)?xv3.x:(i==1)?xv3.y:(i==2)?xv3.z:xv3.w;
                acc[0][0] = fmaf(x0, wv.x, acc[0][0]); acc[0][1] = fmaf(x0, wv.y, acc[0][1]);
                acc[0][2] = fmaf(x0, wv.z, acc[0][2]); acc[0][3] = fmaf(x0, wv.w, acc[0][3]);
                acc[1][0] = fmaf(x1, wv.x, acc[1][0]); acc[1][1] = fmaf(x1, wv.y, acc[1][1]);
                acc[1][2] = fmaf(x1, wv.z, acc[1][2]); acc[1][3] = fmaf(x1, wv.w, acc[1][3]);
                acc[2][0] = fmaf(x2, wv.x, acc[2][0]); acc[2][1] = fmaf(x2, wv.y, acc[2][1]);
                acc[2][2] = fmaf(x2, wv.z, acc[2][2]); acc[2][3] = fmaf(x2, wv.w, acc[2][3]);
                acc[3][0] = fmaf(x3, wv.x, acc[3][0]); acc[3][1] = fmaf(x3, wv.y, acc[3][1]);
                acc[3][2] = fmaf(x3, wv.z, acc[3][2]); acc[3][3] = fmaf(x3, wv.w, acc[3][3]);
            }
        }
        #pragma unroll
        for (int m = 0; m < 4; m++) {
            const int gr = row0 + rg + 8 * m;
            if (gr < nrows) {
                float4 o = make_float4(acc[m][0], acc[m][1], acc[m][2], acc[m][3]);
                if constexpr (OUT_RELU) {
                    o.x = fmaxf(o.x, 0.f); o.y = fmaxf(o.y, 0.f);
                    o.z = fmaxf(o.z, 0.f); o.w = fmaxf(o.w, 0.f);
                }
                *(float4*)&out[(size_t)gr * 96 + cg * 4] = o;
                if constexpr (STATS) {
                    s0 += o.x; q0 += o.x * o.x; s1 += o.y; q1 += o.y * o.y;
                    s2 += o.z; q2 += o.z * o.z; s3 += o.w; q3 += o.w * o.w;
                }
            }
        }
    }
    if constexpr (STATS) {
        __syncthreads();
        float* rs = &xs[0][0];
        float* rq = rs + 8 * 96;
        rs[rg * 96 + cg * 4 + 0] = s0; rs[rg * 96 + cg * 4 + 1] = s1;
        rs[rg * 96 + cg * 4 + 2] = s2; rs[rg * 96 + cg * 4 + 3] = s3;
        rq[rg * 96 + cg * 4 + 0] = q0; rq[rg * 96 + cg * 4 + 1] = q1;
        rq[rg * 96 + cg * 4 + 2] = q2; rq[rg * 96 + cg * 4 + 3] = q3;
        __syncthreads();
        if (tid < 96) {
            float a = 0.f, b = 0.f;
            #pragma unroll
            for (int r = 0; r < 8; r++) { a += rs[r * 96 + tid]; b += rq[r * 96 + tid]; }
            partials[(size_t)blockIdx.x * 192 + tid]      = a;
            partials[(size_t)blockIdx.x * 192 + 96 + tid] = b;
        }
    }
}

// ---------------- head ----------------
__global__ void head_kernel(const float* __restrict__ g1, const float* __restrict__ ac,
                            const float* __restrict__ Wc, const float* __restrict__ bc,
                            float* __restrict__ out, int ngraphs) {
    int gi = blockIdx.x * blockDim.x + threadIdx.x;
    if (gi >= ngraphs) return;
    float v[NCLS];
    #pragma unroll
    for (int c = 0; c < NCLS; c++) v[c] = bc[c];
    for (int k = 0; k < HDIM; k++) {
        float x = g1[(size_t)gi * HDIM + k] * ac[k] + ac[HDIM + k];
        #pragma unroll
        for (int c = 0; c < NCLS; c++) v[c] = fmaf(x, Wc[k * NCLS + c], v[c]);
    }
    float mx = v[0];
    #pragma unroll
    for (int c = 1; c < NCLS; c++) mx = fmaxf(mx, v[c]);
    float sum = 0.f;
    #pragma unroll
    for (int c = 0; c < NCLS; c++) sum += expf(v[c] - mx);
    float lse = mx + logf(sum);
    #pragma unroll
    for (int c = 0; c < NCLS; c++) out[(size_t)gi * NCLS + c] = v[c] - lse;
}

extern "C" void kernel_launch(void* const* d_in, const int* in_sizes, int n_in,
                              void* d_out, int out_size, void* d_ws, size_t ws_size,
                              hipStream_t stream) {
    const float* x         = (const float*)d_in[0];
    const int*   ei        = (const int*)  d_in[1];
    const int*   batch     = (const int*)  d_in[2];
    const float* bn_feat_w = (const float*)d_in[3];
    const float* bn_feat_b = (const float*)d_in[4];
    const float* Wf        = (const float*)d_in[5];
    const float* bfv       = (const float*)d_in[6];
    const float* bn_fc_w   = (const float*)d_in[7];
    const float* bn_fc_b   = (const float*)d_in[8];
    const float* Wl        = (const float*)d_in[9];
    const float* bl        = (const float*)d_in[10];
    const float* bn_hid_w  = (const float*)d_in[11];
    const float* bn_hid_b  = (const float*)d_in[12];
    const float* Wc        = (const float*)d_in[13];
    const float* bc        = (const float*)d_in[14];
    float* out = (float*)d_out;

    char* p = (char*)d_ws;
    auto alloc = [&](size_t bytes) { char* q = p; p += (bytes + 255) & ~(size_t)255; return q; };

    // zero-region: deg only
    int*   deg    = (int*)  alloc((size_t)N_NODES * 4);

    // slot-partial buffers (fully rewritten each call -> no zeroing)
    float* pstatX = (float*)alloc((size_t)256 * 2 * F_IN * 4);
    float* pstatT = (float*)alloc((size_t)1024 * 192 * 4);
    float* pstatG = (float*)alloc((size_t)N_GRAPHS * 192 * 4);
    float* pstatG1= (float*)alloc((size_t)16 * 192 * 4);

    u16*   hb     = (u16*)  alloc((size_t)N_NODES * HDIM * 2);
    float* tf     = (float*)alloc((size_t)N_NODES * HDIM * 4);
    float* g      = (float*)alloc((size_t)N_GRAPHS * HDIM * 4);
    float* g1     = (float*)alloc((size_t)N_GRAPHS * HDIM * 4);
    float* acX    = (float*)alloc(2 * F_IN * 4);
    float* acT    = (float*)alloc(2 * HDIM * 4);
    float* acG    = (float*)alloc(2 * HDIM * 4);
    float* acHid  = (float*)alloc(2 * HDIM * 4);
    u16*   wtF    = (u16*)  alloc(96 * F_IN * 2);
    float* bFmod  = (float*)alloc(96 * 4);
    u16*   wtH    = (u16*)  alloc((size_t)6 * 96 * HDIM * 2);
    float* bmH    = (float*)alloc((size_t)6 * 96 * 4);
    int* row_ptr  = (int*)alloc((size_t)(N_NODES + 1) * 4);
    int* csr      = (int*)alloc((size_t)N_EDGES * 4);
    int* stmp     = (int*)alloc((size_t)N_NODES * 4);
    int* spart    = (int*)alloc(64 * 4);
    int* cnt      = (int*)alloc((size_t)NBUCK2 * NEB * 4);
    int* ofs      = (int*)alloc((size_t)NBUCK2 * NEB * 4);
    int* stmp2    = (int*)alloc((size_t)NBUCK2 * NEB * 4);
    int* spart2   = (int*)alloc(64 * 4);
    u32* ebuf     = (u32*)alloc((size_t)N_EDGES * 4);

    const int* srcp = ei;
    const int* dstp = ei + N_EDGES;

    const int nch64  = (N_NODES + 63) / 64;
    const int gridF  = (nch64 < 768) ? nch64 : 768;
    const int grid96 = (nch64 < 1024) ? nch64 : 1024;   // 782
    const int gridG  = (N_GRAPHS + 31) / 32;            // 16
    const int nscan  = (N_NODES + 1023) / 1024;         // 49
    const int ncb    = NBUCK2 * NEB;                    // 50048
    const int nscan2 = (ncb + 1023) / 1024;             // 49

    hipMemsetAsync(deg, 0, (size_t)N_NODES * 4, stream);

    // BN(x) stats (slots) -> finalize -> fold into Wf -> h = relu(x @ Wf' + bf')
    colstats4_kernel<F_IN><<<256, 256, 0, stream>>>(x, pstatX, N_NODES);
    reduce_finalize_kernel<F_IN><<<1, F_IN * 8, 0, stream>>>(pstatX, 256, bn_feat_w, bn_feat_b, acX, 1.0f / N_NODES);
    wprep_all_kernel<<<WPF_BLOCKS + 6 * WPH_BLOCKS, 256, 0, stream>>>(
        Wf, bfv, acX,
        (const float*)d_in[15], (const float*)d_in[16],
        (const float*)d_in[19], (const float*)d_in[20],
        (const float*)d_in[21], (const float*)d_in[22],
        (const float*)d_in[25], (const float*)d_in[26],
        (const float*)d_in[27], (const float*)d_in[28],
        (const float*)d_in[31], (const float*)d_in[32],
        wtF, bFmod, wtH, bmH);
    mmx_kernel<F_IN, true, false, true, false, true><<<gridF, 256, 0, stream>>>(x, wtF, bFmod, nullptr, hb, nullptr, N_NODES);

    // CSR build (fused scans)
    count_kernel<<<NEB, 256, 0, stream>>>(dstp, deg, cnt);
    scan1_fused_kernel<<<nscan + nscan2, 1024, 0, stream>>>(deg, N_NODES, stmp, spart,
                                                            cnt, ncb, stmp2, spart2, nscan);
    scan3_fused_kernel<<<nscan + nscan2, 1024, 0, stream>>>(stmp, spart, deg, row_ptr, N_NODES, nscan,
                                                            stmp2, spart2, ofs, ncb, nscan2, nscan);
    distribute_kernel<<<NEB, 256, 0, stream>>>(srcp, dstp, ofs, ebuf);
    bucket_fill_kernel<<<NBUCK2, 256, 0, stream>>>(ebuf, ofs, row_ptr, csr);

    for (int l = 0; l < 3; l++) {
        const float* bw = (const float*)d_in[17 + 6 * l];
        const float* bb = (const float*)d_in[18 + 6 * l];
        u16*   wt1 = wtH + (size_t)(2 * l)     * 96 * HDIM;
        u16*   wt2 = wtH + (size_t)(2 * l + 1) * 96 * HDIM;
        float* b1m = bmH + (size_t)(2 * l)     * 96;
        float* b2m = bmH + (size_t)(2 * l + 1) * 96;
        // tf = (h + sum_nbr h) @ W1 + b1  (fused agg + mm1; f64 agg accum), stats slots
        aggmm_kernel<<<grid96, 256, 0, stream>>>(hb, row_ptr, csr, wt1, b1m, tf, pstatT, N_NODES);
        reduce_finalize_kernel<HDIM><<<1, HDIM * 8, 0, stream>>>(pstatT, grid96, bw, bb, acT, 1.0f / N_NODES);
        // h = relu( relu(BN(t_f32)) @ W2 + b2 ) -> bf16 hb
        mmx_kernel<HDIM, true, true, true, false, true><<<grid96, 256, 0, stream>>>(tf, wt2, b2m, acT, hb, nullptr, N_NODES);
    }

    // deterministic per-graph pool + fused stats partials
    pool_stats_kernel<<<N_GRAPHS, 96, 0, stream>>>(hb, batch, g, pstatG);
    reduce_finalize_kernel<HDIM><<<1, HDIM * 8, 0, stream>>>(pstatG, N_GRAPHS, bn_fc_w, bn_fc_b, acG, 1.0f / N_GRAPHS);
    mm_kernel<HDIM, true, false, true, true><<<gridG, 192, 0, stream>>>(g, Wl, bl, acG, g1, pstatG1, N_GRAPHS);
    reduce_finalize_kernel<HDIM><<<1, HDIM * 8, 0, stream>>>(pstatG1, gridG, bn_hid_w, bn_hid_b, acHid, 1.0f / N_GRAPHS);

    head_kernel<<<2, 256, 0, stream>>>(g1, acHid, Wc, bc, out, N_GRAPHS);
}

// Round 14
// 359.033 us; speedup vs baseline: 1.4215x; 1.0926x over previous
//
#include <hip/hip_runtime.h>

#define N_NODES 50000
#define N_EDGES 800000
#define N_GRAPHS 512
#define F_IN 128
#define HDIM 96
#define NCLS 10
#define BN_EPS 1e-5f

// partitioned CSR fill geometry
#define NPB 128
#define NBUCK2 ((N_NODES + NPB - 1) / NPB) // 391 buckets
#define NEB 128
#define EPB ((N_EDGES + NEB - 1) / NEB)    // 6250 edges per block

typedef unsigned int u32;
typedef unsigned short u16;
typedef __attribute__((ext_vector_type(8))) short bf16x8;
typedef __attribute__((ext_vector_type(4))) float f32x4;

__device__ __forceinline__ u16 f2bf(float f) {
    u32 u = __float_as_uint(f);
    u32 r = (u + 0x7fffu + ((u >> 16) & 1u)) >> 16;   // RNE
    return (u16)r;
}
__device__ __forceinline__ float bflo(u32 w) { return __uint_as_float(w << 16); }
__device__ __forceinline__ float bfhi(u32 w) { return __uint_as_float(w & 0xffff0000u); }
__device__ __forceinline__ float bf2f(u16 v) { return __uint_as_float((u32)v << 16); }

// ---------------- column stats for x (slot partials, no atomics) ----------------
template<int NC>
__global__ __launch_bounds__(256) void colstats4_kernel(const float* __restrict__ in,
                                                        float* __restrict__ partials,
                                                        int nrows) {
    constexpr int CG  = NC / 4;
    constexpr int RPB = 256 / CG;
    const int cg = threadIdx.x % CG;
    const int rg = threadIdx.x / CG;
    float4 s = make_float4(0.f, 0.f, 0.f, 0.f);
    float4 q = make_float4(0.f, 0.f, 0.f, 0.f);
    for (int r = blockIdx.x * RPB + rg; r < nrows; r += gridDim.x * RPB) {
        float4 v = *(const float4*)&in[(size_t)r * NC + cg * 4];
        s.x += v.x; s.y += v.y; s.z += v.z; s.w += v.w;
        q.x += v.x * v.x; q.y += v.y * v.y; q.z += v.z * v.z; q.w += v.w * v.w;
    }
    __shared__ float ss[RPB][NC], sq[RPB][NC];
    *(float4*)&ss[rg][cg * 4] = s;
    *(float4*)&sq[rg][cg * 4] = q;
    __syncthreads();
    if (threadIdx.x < NC) {
        float a = 0.f, b = 0.f;
        #pragma unroll
        for (int r = 0; r < RPB; r++) { a += ss[r][threadIdx.x]; b += sq[r][threadIdx.x]; }
        partials[(size_t)blockIdx.x * 2 * NC + threadIdx.x]      = a;
        partials[(size_t)blockIdx.x * 2 * NC + NC + threadIdx.x] = b;
    }
}

// group-parallel fixed-order slot reduction + BN finalize (deterministic)
template<int NCOLS>
__global__ __launch_bounds__(NCOLS * 8) void reduce_finalize_kernel(
        const float* __restrict__ partials, int nslots,
        const float* __restrict__ w,
        const float* __restrict__ b,
        float* __restrict__ ac, float inv_n) {
    const int k   = threadIdx.x % NCOLS;
    const int grp = threadIdx.x / NCOLS;   // 0..7
    const int stride = 2 * NCOLS;
    float s = 0.f, q = 0.f;
    for (int i = grp; i < nslots; i += 8) {
        s += partials[(size_t)i * stride + k];
        q += partials[(size_t)i * stride + NCOLS + k];
    }
    __shared__ float ss[8][NCOLS], sq[8][NCOLS];
    ss[grp][k] = s; sq[grp][k] = q;
    __syncthreads();
    if (grp == 0) {
        float S = ((ss[0][k] + ss[1][k]) + (ss[2][k] + ss[3][k]))
                + ((ss[4][k] + ss[5][k]) + (ss[6][k] + ss[7][k]));
        float Q = ((sq[0][k] + sq[1][k]) + (sq[2][k] + sq[3][k]))
                + ((sq[4][k] + sq[5][k]) + (sq[6][k] + sq[7][k]));
        float mu  = S * inv_n;
        float var = Q * inv_n - mu * mu;
        float a   = w[k] * rsqrtf(var + BN_EPS);
        ac[k]         = a;
        ac[NCOLS + k] = b[k] - mu * a;
    }
}

// ---------------- fused weight prep: all 7 weights in one launch ----------------
#define WPF_BLOCKS 48   // ceil(128*96/256)
#define WPH_BLOCKS 36   // 96*96/256
__global__ __launch_bounds__(256) void wprep_all_kernel(
        const float* __restrict__ Wf, const float* __restrict__ bf, const float* __restrict__ acX,
        const float* __restrict__ W0a, const float* __restrict__ b0a,
        const float* __restrict__ W0b, const float* __restrict__ b0b,
        const float* __restrict__ W1a, const float* __restrict__ b1a,
        const float* __restrict__ W1b, const float* __restrict__ b1b,
        const float* __restrict__ W2a, const float* __restrict__ b2a,
        const float* __restrict__ W2b, const float* __restrict__ b2b,
        u16* __restrict__ wtF, float* __restrict__ bFm,
        u16* __restrict__ wtbase, float* __restrict__ bmbase) {
    const int tid = threadIdx.x;
    int blk = blockIdx.x;
    if (blk < WPF_BLOCKS) {
        int i = blk * 256 + tid;
        if (i < F_IN * 96) {
            int k = i / 96, n = i % 96;
            wtF[n * F_IN + k] = f2bf(Wf[i] * acX[k]);
        }
        if (blk == 0 && tid < 96) {
            float b = bf[tid];
            for (int k = 0; k < F_IN; k++) b += acX[F_IN + k] * Wf[k * 96 + tid];
            bFm[tid] = b;
        }
        return;
    }
    blk -= WPF_BLOCKS;
    const int s  = blk / WPH_BLOCKS;
    const int b2 = blk % WPH_BLOCKS;
    const float* W; const float* bias;
    switch (s) {
        case 0: W = W0a; bias = b0a; break;
        case 1: W = W0b; bias = b0b; break;
        case 2: W = W1a; bias = b1a; break;
        case 3: W = W1b; bias = b1b; break;
        case 4: W = W2a; bias = b2a; break;
        default: W = W2b; bias = b2b; break;
    }
    u16*   wtb  = wtbase + (size_t)s * 96 * HDIM;
    float* bmod = bmbase + (size_t)s * 96;
    int i = b2 * 256 + tid;
    if (i < HDIM * 96) {
        int k = i / 96, n = i % 96;
        wtb[n * HDIM + k] = f2bf(W[i]);
    }
    if (b2 == 0 && tid < 96) bmod[tid] = bias[tid];
}

// ---------------- CSR build ----------------
// count: per-(bucket, edge-block) histogram ONLY (LDS atomics; no global per-node atomics)
__global__ __launch_bounds__(256) void count_kernel(const int* __restrict__ dst,
                                                    int* __restrict__ cnt) {
    __shared__ int lc[NBUCK2];
    for (int i = threadIdx.x; i < NBUCK2; i += 256) lc[i] = 0;
    __syncthreads();
    const int lo = blockIdx.x * EPB;
    const int hi = min(lo + EPB, N_EDGES);
    for (int e = lo + threadIdx.x; e < hi; e += 256)
        atomicAdd(&lc[dst[e] / NPB], 1);
    __syncthreads();
    for (int i = threadIdx.x; i < NBUCK2; i += 256)
        cnt[i * NEB + blockIdx.x] = lc[i];
}

__global__ __launch_bounds__(1024) void scan1_kernel(const int* __restrict__ in,
                                                     int* __restrict__ tmp,
                                                     int* __restrict__ partial, int n) {
    __shared__ int sh[1024];
    const int i = blockIdx.x * 1024 + threadIdx.x;
    const int d = (i < n) ? in[i] : 0;
    sh[threadIdx.x] = d;
    __syncthreads();
    for (int off = 1; off < 1024; off <<= 1) {
        int v = 0;
        if (threadIdx.x >= off) v = sh[threadIdx.x - off];
        __syncthreads();
        sh[threadIdx.x] += v;
        __syncthreads();
    }
    if (i < n) tmp[i] = sh[threadIdx.x] - d;
    if (threadIdx.x == 1023) partial[blockIdx.x] = sh[1023];
}

__global__ __launch_bounds__(1024) void scan3_kernel(const int* __restrict__ tmp,
                                                     const int* __restrict__ partial,
                                                     int* __restrict__ out,
                                                     int n, int nparts) {
    __shared__ int offs;
    if (threadIdx.x < 64) {
        int v = (threadIdx.x < blockIdx.x && (int)threadIdx.x < nparts) ? partial[threadIdx.x] : 0;
        for (int o = 32; o > 0; o >>= 1) v += __shfl_down(v, o, 64);
        if (threadIdx.x == 0) offs = v;
    }
    __syncthreads();
    const int i = blockIdx.x * 1024 + threadIdx.x;
    if (i < n) out[i] = tmp[i] + offs;
}

__global__ __launch_bounds__(256) void distribute_kernel(const int* __restrict__ src,
                                                         const int* __restrict__ dst,
                                                         const int* __restrict__ ofs,
                                                         u32* __restrict__ ebuf) {
    __shared__ int lofs[NBUCK2];
    for (int i = threadIdx.x; i < NBUCK2; i += 256) lofs[i] = ofs[i * NEB + blockIdx.x];
    __syncthreads();
    const int lo = blockIdx.x * EPB;
    const int hi = min(lo + EPB, N_EDGES);
    for (int e = lo + threadIdx.x; e < hi; e += 256) {
        int d = dst[e];
        int q = atomicAdd(&lofs[d / NPB], 1);
        ebuf[q] = ((u32)src[e] << 7) | (u32)(d & (NPB - 1));
    }
}

// bucket fill v2: builds row_ptr from LDS-local histogram + scan (no global deg pass),
// then scatters csr. row_ptr values are identical to a global exclusive scan of degrees
// because ofs[p*NEB] is the global edge-prefix at each bucket boundary.
__global__ __launch_bounds__(256) void bucket_fill2_kernel(const u32* __restrict__ ebuf,
                                                           const int* __restrict__ ofs,
                                                           int* __restrict__ row_ptr,
                                                           int* __restrict__ csr) {
    __shared__ int lcnt[NPB], lpos[NPB];
    const int p    = blockIdx.x;
    const int base = p * NPB;
    const int nn   = min(NPB, N_NODES - base);
    const int tid  = threadIdx.x;
    const int e0 = ofs[p * NEB];
    const int e1 = (p + 1 < NBUCK2) ? ofs[(p + 1) * NEB] : N_EDGES;
    for (int i = tid; i < NPB; i += 256) lcnt[i] = 0;
    __syncthreads();
    for (int e = e0 + tid; e < e1; e += 256)
        atomicAdd(&lcnt[ebuf[e] & (NPB - 1)], 1);
    __syncthreads();
    // inclusive Hillis-Steele scan over NPB=128 entries (threads 0..127)
    if (tid < NPB) lpos[tid] = lcnt[tid];
    __syncthreads();
    for (int off = 1; off < NPB; off <<= 1) {
        int v = 0;
        if (tid < NPB && tid >= off) v = lpos[tid - off];
        __syncthreads();
        if (tid < NPB) lpos[tid] += v;
        __syncthreads();
    }
    if (tid < NPB) {
        int excl = lpos[tid] - lcnt[tid];
        lpos[tid] = e0 + excl;                       // cursor
        if (tid < nn) row_ptr[base + tid] = e0 + excl;
    }
    if (p == NBUCK2 - 1 && tid == 0) row_ptr[N_NODES] = N_EDGES;
    __syncthreads();
    for (int e = e0 + tid; e < e1; e += 256) {
        u32 v = ebuf[e];
        int pos = atomicAdd(&lpos[v & (NPB - 1)], 1);
        csr[pos] = (int)(v >> 7);
    }
}

// ---------------- fused GIN agg + mm1:  tf = (h + sum_nbr h) @ W1 + b1, stats(tf) ----------------
__global__ __launch_bounds__(256) void aggmm_kernel(const u16* __restrict__ hb,
                                                    const int* __restrict__ row_ptr,
                                                    const int* __restrict__ csr,
                                                    const u16* __restrict__ wt,   // [96][96] bf16
                                                    const float* __restrict__ bias,
                                                    float* __restrict__ tf,
                                                    float* __restrict__ partials,
                                                    int nrows) {
    constexpr int KP = HDIM + 8;      // 104
    constexpr int KB = HDIM / 32;     // 3
    __shared__ u16 wlds[96 * KP];
    __shared__ u16 alds[64 * KP];
    __shared__ float sred[2][4][96];
    const int tid = threadIdx.x;

    for (int i = tid; i < 96 * (HDIM / 8); i += 256) {
        int nn = i / (HDIM / 8), c8 = i % (HDIM / 8);
        *(uint4*)&wlds[nn * KP + c8 * 8] = *(const uint4*)&wt[nn * HDIM + c8 * 8];
    }

    const int w    = tid >> 6;
    const int lane = tid & 63;
    const int r16  = lane & 15;
    const int kg   = lane >> 4;
    const int m0   = w * 16;
    float bn[6];
    #pragma unroll
    for (int nt = 0; nt < 6; nt++) bn[nt] = bias[nt * 16 + r16];
    float scol[6] = {0,0,0,0,0,0}, qcol[6] = {0,0,0,0,0,0};

    const int nchunks = (nrows + 63) / 64;
    for (int chunk = blockIdx.x; chunk < nchunks; chunk += gridDim.x) {
        const int row0 = chunk * 64;
        __syncthreads();
        for (int t = tid; t < 64 * 12; t += 256) {
            const int r  = t / 12, sl = t % 12;
            const int node = row0 + r;
            uint4 ov = make_uint4(0u, 0u, 0u, 0u);
            if (node < nrows) {
                const int p0 = row_ptr[node], p1 = row_ptr[node + 1];
                uint4 sv = *(const uint4*)&hb[(size_t)node * 96 + sl * 8];
                double a0 = bflo(sv.x), a1 = bfhi(sv.x), a2 = bflo(sv.y), a3 = bfhi(sv.y);
                double a4 = bflo(sv.z), a5 = bfhi(sv.z), a6 = bflo(sv.w), a7 = bfhi(sv.w);
                int p = p0;
                for (; p + 4 <= p1; p += 4) {
                    int s0 = csr[p], s1 = csr[p + 1], s2 = csr[p + 2], s3 = csr[p + 3];
                    uint4 v0 = *(const uint4*)&hb[(size_t)s0 * 96 + sl * 8];
                    uint4 v1 = *(const uint4*)&hb[(size_t)s1 * 96 + sl * 8];
                    uint4 v2 = *(const uint4*)&hb[(size_t)s2 * 96 + sl * 8];
                    uint4 v3 = *(const uint4*)&hb[(size_t)s3 * 96 + sl * 8];
                    a0 += bflo(v0.x); a0 += bflo(v1.x); a0 += bflo(v2.x); a0 += bflo(v3.x);
                    a1 += bfhi(v0.x); a1 += bfhi(v1.x); a1 += bfhi(v2.x); a1 += bfhi(v3.x);
                    a2 += bflo(v0.y); a2 += bflo(v1.y); a2 += bflo(v2.y); a2 += bflo(v3.y);
                    a3 += bfhi(v0.y); a3 += bfhi(v1.y); a3 += bfhi(v2.y); a3 += bfhi(v3.y);
                    a4 += bflo(v0.z); a4 += bflo(v1.z); a4 += bflo(v2.z); a4 += bflo(v3.z);
                    a5 += bfhi(v0.z); a5 += bfhi(v1.z); a5 += bfhi(v2.z); a5 += bfhi(v3.z);
                    a6 += bflo(v0.w); a6 += bflo(v1.w); a6 += bflo(v2.w); a6 += bflo(v3.w);
                    a7 += bfhi(v0.w); a7 += bfhi(v1.w); a7 += bfhi(v2.w); a7 += bfhi(v3.w);
                }
                for (; p < p1; p++) {
                    int s = csr[p];
                    uint4 v = *(const uint4*)&hb[(size_t)s * 96 + sl * 8];
                    a0 += bflo(v.x); a1 += bfhi(v.x); a2 += bflo(v.y); a3 += bfhi(v.y);
                    a4 += bflo(v.z); a5 += bfhi(v.z); a6 += bflo(v.w); a7 += bfhi(v.w);
                }
                ov.x = (u32)f2bf((float)a0) | ((u32)f2bf((float)a1) << 16);
                ov.y = (u32)f2bf((float)a2) | ((u32)f2bf((float)a3) << 16);
                ov.z = (u32)f2bf((float)a4) | ((u32)f2bf((float)a5) << 16);
                ov.w = (u32)f2bf((float)a6) | ((u32)f2bf((float)a7) << 16);
            }
            *(uint4*)&alds[r * KP + sl * 8] = ov;
        }
        __syncthreads();

        bf16x8 af[KB];
        #pragma unroll
        for (int kb = 0; kb < KB; kb++)
            af[kb] = *(const bf16x8*)&alds[(m0 + r16) * KP + kb * 32 + kg * 8];

        f32x4 acc[6];
        #pragma unroll
        for (int nt = 0; nt < 6; nt++) acc[nt] = (f32x4){bn[nt], bn[nt], bn[nt], bn[nt]};
        #pragma unroll
        for (int kb = 0; kb < KB; kb++) {
            #pragma unroll
            for (int nt = 0; nt < 6; nt++) {
                bf16x8 bfr = *(const bf16x8*)&wlds[(nt * 16 + r16) * KP + kb * 32 + kg * 8];
                acc[nt] = __builtin_amdgcn_mfma_f32_16x16x32_bf16(af[kb], bfr, acc[nt], 0, 0, 0);
            }
        }

        const int gr0  = row0 + m0 + kg * 4;
        const bool full = (gr0 + 3 < nrows);
        #pragma unroll
        for (int nt = 0; nt < 6; nt++) {
            const int n = nt * 16 + r16;
            #pragma unroll
            for (int rr = 0; rr < 4; rr++) {
                const int gr = gr0 + rr;
                if (full || gr < nrows) {
                    float v = acc[nt][rr];
                    tf[(size_t)gr * 96 + n] = v;
                    scol[nt] += v; qcol[nt] += v * v;
                }
            }
        }
    }

    #pragma unroll
    for (int nt = 0; nt < 6; nt++) {
        scol[nt] += __shfl_xor(scol[nt], 16);
        scol[nt] += __shfl_xor(scol[nt], 32);
        qcol[nt] += __shfl_xor(qcol[nt], 16);
        qcol[nt] += __shfl_xor(qcol[nt], 32);
    }
    __syncthreads();
    if (kg == 0) {
        #pragma unroll
        for (int nt = 0; nt < 6; nt++) {
            sred[0][w][nt * 16 + r16] = scol[nt];
            sred[1][w][nt * 16 + r16] = qcol[nt];
        }
    }
    __syncthreads();
    if (tid < 96) {
        float a = (sred[0][0][tid] + sred[0][1][tid]) + (sred[0][2][tid] + sred[0][3][tid]);
        float b = (sred[1][0][tid] + sred[1][1][tid]) + (sred[1][2][tid] + sred[1][3][tid]);
        partials[(size_t)blockIdx.x * 192 + tid]      = a;
        partials[(size_t)blockIdx.x * 192 + 96 + tid] = b;
    }
}

// ---------------- MFMA matmul (mmF and mm2) ----------------
template<int KDIM, bool IN_F32, bool IN_AFF_RELU, bool OUT_RELU, bool STATS, bool OUT_BF16>
__global__ __launch_bounds__(256) void mmx_kernel(const void* __restrict__ in_,
                                                  const u16* __restrict__ wt,
                                                  const float* __restrict__ bias,
                                                  const float* __restrict__ ac,
                                                  void* __restrict__ out_,
                                                  float* __restrict__ partials,
                                                  int nrows) {
    constexpr int KP = KDIM + 8;
    constexpr int KB = KDIM / 32;
    __shared__ u16 wlds[96 * KP];
    __shared__ u16 alds[64 * KP];
    __shared__ float sred[2][4][96];
    const int tid = threadIdx.x;

    for (int i = tid; i < 96 * (KDIM / 8); i += 256) {
        int nn = i / (KDIM / 8), c8 = i % (KDIM / 8);
        *(uint4*)&wlds[nn * KP + c8 * 8] = *(const uint4*)&wt[nn * KDIM + c8 * 8];
    }

    const int w    = tid >> 6;
    const int lane = tid & 63;
    const int r16  = lane & 15;
    const int kg   = lane >> 4;
    const int m0   = w * 16;
    float bn[6];
    #pragma unroll
    for (int nt = 0; nt < 6; nt++) bn[nt] = bias[nt * 16 + r16];
    float scol[6] = {0,0,0,0,0,0}, qcol[6] = {0,0,0,0,0,0};

    const int nchunks = (nrows + 63) / 64;
    for (int chunk = blockIdx.x; chunk < nchunks; chunk += gridDim.x) {
        const int row0 = chunk * 64;
        __syncthreads();
        if constexpr (IN_F32) {
            const float* inf = (const float*)in_;
            for (int i = tid; i < 64 * (KDIM / 4); i += 256) {
                int r = i / (KDIM / 4), c4 = i % (KDIM / 4);
                int gr = row0 + r;
                float4 v = (gr < nrows) ? *(const float4*)&inf[(size_t)gr * KDIM + c4 * 4]
                                        : make_float4(0.f, 0.f, 0.f, 0.f);
                if constexpr (IN_AFF_RELU) {
                    float4 a = *(const float4*)&ac[c4 * 4];
                    float4 c = *(const float4*)&ac[KDIM + c4 * 4];
                    v.x = fmaxf(v.x * a.x + c.x, 0.f);
                    v.y = fmaxf(v.y * a.y + c.y, 0.f);
                    v.z = fmaxf(v.z * a.z + c.z, 0.f);
                    v.w = fmaxf(v.w * a.w + c.w, 0.f);
                }
                ushort4 o; o.x = f2bf(v.x); o.y = f2bf(v.y); o.z = f2bf(v.z); o.w = f2bf(v.w);
                *(ushort4*)&alds[r * KP + c4 * 4] = o;
            }
        } else {
            const u16* inb = (const u16*)in_;
            for (int i = tid; i < 64 * (KDIM / 8); i += 256) {
                int r = i / (KDIM / 8), c8 = i % (KDIM / 8);
                int gr = row0 + r;
                uint4 v = (gr < nrows) ? *(const uint4*)&inb[(size_t)gr * KDIM + c8 * 8]
                                       : make_uint4(0u, 0u, 0u, 0u);
                *(uint4*)&alds[r * KP + c8 * 8] = v;
            }
        }
        __syncthreads();

        bf16x8 af[KB];
        #pragma unroll
        for (int kb = 0; kb < KB; kb++)
            af[kb] = *(const bf16x8*)&alds[(m0 + r16) * KP + kb * 32 + kg * 8];

        f32x4 acc[6];
        #pragma unroll
        for (int nt = 0; nt < 6; nt++) acc[nt] = (f32x4){bn[nt], bn[nt], bn[nt], bn[nt]};
        #pragma unroll
        for (int kb = 0; kb < KB; kb++) {
            #pragma unroll
            for (int nt = 0; nt < 6; nt++) {
                bf16x8 bfr = *(const bf16x8*)&wlds[(nt * 16 + r16) * KP + kb * 32 + kg * 8];
                acc[nt] = __builtin_amdgcn_mfma_f32_16x16x32_bf16(af[kb], bfr, acc[nt], 0, 0, 0);
            }
        }

        const int gr0  = row0 + m0 + kg * 4;
        const bool full = (gr0 + 3 < nrows);
        #pragma unroll
        for (int nt = 0; nt < 6; nt++) {
            float v[4] = {acc[nt][0], acc[nt][1], acc[nt][2], acc[nt][3]};
            if constexpr (OUT_RELU) {
                #pragma unroll
                for (int rr = 0; rr < 4; rr++) v[rr] = fmaxf(v[rr], 0.f);
            }
            const int n = nt * 16 + r16;
            #pragma unroll
            for (int rr = 0; rr < 4; rr++) {
                const int gr = gr0 + rr;
                if (full || gr < nrows) {
                    if constexpr (OUT_BF16) ((u16*)out_)[(size_t)gr * 96 + n] = f2bf(v[rr]);
                    else                    ((float*)out_)[(size_t)gr * 96 + n] = v[rr];
                    if constexpr (STATS) { scol[nt] += v[rr]; qcol[nt] += v[rr] * v[rr]; }
                }
            }
        }
    }

    if constexpr (STATS) {
        #pragma unroll
        for (int nt = 0; nt < 6; nt++) {
            scol[nt] += __shfl_xor(scol[nt], 16);
            scol[nt] += __shfl_xor(scol[nt], 32);
            qcol[nt] += __shfl_xor(qcol[nt], 16);
            qcol[nt] += __shfl_xor(qcol[nt], 32);
        }
        __syncthreads();
        if (kg == 0) {
            #pragma unroll
            for (int nt = 0; nt < 6; nt++) {
                sred[0][w][nt * 16 + r16] = scol[nt];
                sred[1][w][nt * 16 + r16] = qcol[nt];
            }
        }
        __syncthreads();
        if (tid < 96) {
            float a = (sred[0][0][tid] + sred[0][1][tid]) + (sred[0][2][tid] + sred[0][3][tid]);
            float b = (sred[1][0][tid] + sred[1][1][tid]) + (sred[1][2][tid] + sred[1][3][tid]);
            partials[(size_t)blockIdx.x * 192 + tid]      = a;
            partials[(size_t)blockIdx.x * 192 + 96 + tid] = b;
        }
    }
}

// ---------------- deterministic per-graph pool + fused stats partials ----------------
__device__ __forceinline__ int lower_bound_dev(const int* __restrict__ a, int n, int v) {
    int lo = 0, hi = n;
    while (lo < hi) { int m = (lo + hi) >> 1; if (a[m] < v) lo = m + 1; else hi = m; }
    return lo;
}
__global__ __launch_bounds__(96) void pool_stats_kernel(const u16* __restrict__ hb,
                                                        const int* __restrict__ batch,
                                                        float* __restrict__ g,
                                                        float* __restrict__ partials) {
    const int gi = blockIdx.x;
    __shared__ int sh_lo, sh_hi;
    if (threadIdx.x == 0) sh_lo = lower_bound_dev(batch, N_NODES, gi);
    if (threadIdx.x == 1) sh_hi = lower_bound_dev(batch, N_NODES, gi + 1);
    __syncthreads();
    const int lo = sh_lo, hi = sh_hi;
    const int j = threadIdx.x;
    float s0 = 0.f, s1 = 0.f, s2 = 0.f, s3 = 0.f;
    int r = lo;
    for (; r + 4 <= hi; r += 4) {
        s0 += bf2f(hb[(size_t)r       * 96 + j]);
        s1 += bf2f(hb[(size_t)(r + 1) * 96 + j]);
        s2 += bf2f(hb[(size_t)(r + 2) * 96 + j]);
        s3 += bf2f(hb[(size_t)(r + 3) * 96 + j]);
    }
    for (; r < hi; r++) s0 += bf2f(hb[(size_t)r * 96 + j]);
    float val = (s0 + s1) + (s2 + s3);
    g[(size_t)gi * 96 + j] = val;
    partials[(size_t)gi * 192 + j]      = val;
    partials[(size_t)gi * 192 + 96 + j] = val * val;
}

// ---------------- f32 small matmul (G-sized tail; STATS -> slots) ----------------
template<int KDIM, bool IN_AFF, bool IN_RELU, bool OUT_RELU, bool STATS>
__global__ __launch_bounds__(192) void mm_kernel(const float* __restrict__ in,
                                                 const float* __restrict__ W,
                                                 const float* __restrict__ bias,
                                                 const float* __restrict__ ac,
                                                 float* __restrict__ out,
                                                 float* __restrict__ partials, int nrows) {
    constexpr int KG = KDIM / 4;
    __shared__ float ws[KDIM][96];
    __shared__ float xs[32][KDIM];
    const int tid = threadIdx.x;
    const int cg  = tid % 24;
    const int rg  = tid / 24;
    for (int i = tid; i < KDIM * 24; i += 192) {
        int k = i / 24, c4 = i % 24;
        *(float4*)&ws[k][c4 * 4] = *(const float4*)&W[(size_t)k * 96 + c4 * 4];
    }
    const float4 bj = *(const float4*)&bias[cg * 4];
    float s0=0,s1=0,s2=0,s3=0, q0=0,q1=0,q2=0,q3=0;
    const int nchunks = (nrows + 31) / 32;
    for (int chunk = blockIdx.x; chunk < nchunks; chunk += gridDim.x) {
        const int row0 = chunk * 32;
        __syncthreads();
        for (int i = tid; i < 32 * KG; i += 192) {
            int r = i / KG, g = i % KG;
            int gr = row0 + r;
            float4 v = make_float4(0.f, 0.f, 0.f, 0.f);
            if (gr < nrows) v = *(const float4*)&in[(size_t)gr * KDIM + g * 4];
            if constexpr (IN_AFF) {
                float4 a = *(const float4*)&ac[g * 4];
                float4 c = *(const float4*)&ac[KDIM + g * 4];
                v.x = v.x * a.x + c.x; v.y = v.y * a.y + c.y;
                v.z = v.z * a.z + c.z; v.w = v.w * a.w + c.w;
            }
            if constexpr (IN_RELU) {
                v.x = fmaxf(v.x, 0.f); v.y = fmaxf(v.y, 0.f);
                v.z = fmaxf(v.z, 0.f); v.w = fmaxf(v.w, 0.f);
            }
            *(float4*)&xs[r][4 * (g ^ (r & 7))] = v;
        }
        __syncthreads();
        float acc[4][4];
        #pragma unroll
        for (int m = 0; m < 4; m++) {
            acc[m][0] = bj.x; acc[m][1] = bj.y; acc[m][2] = bj.z; acc[m][3] = bj.w;
        }
        #pragma unroll 4
        for (int g = 0; g < KG; g++) {
            const int xi = 4 * (g ^ rg);
            float4 xv0 = *(const float4*)&xs[rg     ][xi];
            float4 xv1 = *(const float4*)&xs[rg +  8][xi];
            float4 xv2 = *(const float4*)&xs[rg + 16][xi];
            float4 xv3 = *(const float4*)&xs[rg + 24][xi];
            #pragma unroll
            for (int i = 0; i < 4; i++) {
                float4 wv = *(const float4*)&ws[g * 4 + i][cg * 4];
                float x0 = (i==0)?xv0.x:(i==1)?xv0.y:(i==2)?xv0.z:xv0.w;
                float x1 = (i==0)?xv1.x:(i==1)?xv1.y:(i==2)?xv1.z:xv1.w;
                float x2 = (i==0)?xv2.x:(i==1)?xv2.y:(i==2)?xv2.z:xv2.w;
                float x3 = (i==0)?xv3.x:(i==1)?xv3.y:(i==2)?xv3.z:xv3.w;
                acc[0][0] = fmaf(x0, wv.x, acc[0][0]); acc[0][1] = fmaf(x0, wv.y, acc[0][1]);
                acc[0][2] = fmaf(x0, wv.z, acc[0][2]); acc[0][3] = fmaf(x0, wv.w, acc[0][3]);
                acc[1][0] = fmaf(x1, wv.x, acc[1][0]); acc[1][1] = fmaf(x1, wv.y, acc[1][1]);
                acc[1][2] = fmaf(x1, wv.z, acc[1][2]); acc[1][3] = fmaf(x1, wv.w, acc[1][3]);
                acc[2][0] = fmaf(x2, wv.x, acc[2][0]); acc[2][1] = fmaf(x2, wv.y, acc[2][1]);
                acc[2][2] = fmaf(x2, wv.z, acc[2][2]); acc[2][3] = fmaf(x2, wv.w, acc[2][3]);
                acc[3][0] = fmaf(x3, wv.x, acc[3][0]); acc[3][1] = fmaf(x3, wv.y, acc[3][1]);
                acc[3][2] = fmaf(x3, wv.z, acc[3][2]); acc[3][3] = fmaf(x3, wv.w, acc[3][3]);
            }
        }
        #pragma unroll
        for (int m = 0; m < 4; m++) {
            const int gr = row0 + rg + 8 * m;
            if (gr < nrows) {
                float4 o = make_float4(acc[m][0], acc[m][1], acc[m][2], acc[m][3]);
                if constexpr (OUT_RELU) {
                    o.x = fmaxf(o.x, 0.f); o.y = fmaxf(o.y, 0.f);
                    o.z = fmaxf(o.z, 0.f); o.w = fmaxf(o.w, 0.f);
                }
                *(float4*)&out[(size_t)gr * 96 + cg * 4] = o;
                if constexpr (STATS) {
                    s0 += o.x; q0 += o.x * o.x; s1 += o.y; q1 += o.y * o.y;
                    s2 += o.z; q2 += o.z * o.z; s3 += o.w; q3 += o.w * o.w;
                }
            }
        }
    }
    if constexpr (STATS) {
        __syncthreads();
        float* rs = &xs[0][0];
        float* rq = rs + 8 * 96;
        rs[rg * 96 + cg * 4 + 0] = s0; rs[rg * 96 + cg * 4 + 1] = s1;
        rs[rg * 96 + cg * 4 + 2] = s2; rs[rg * 96 + cg * 4 + 3] = s3;
        rq[rg * 96 + cg * 4 + 0] = q0; rq[rg * 96 + cg * 4 + 1] = q1;
        rq[rg * 96 + cg * 4 + 2] = q2; rq[rg * 96 + cg * 4 + 3] = q3;
        __syncthreads();
        if (tid < 96) {
            float a = 0.f, b = 0.f;
            #pragma unroll
            for (int r = 0; r < 8; r++) { a += rs[r * 96 + tid]; b += rq[r * 96 + tid]; }
            partials[(size_t)blockIdx.x * 192 + tid]      = a;
            partials[(size_t)blockIdx.x * 192 + 96 + tid] = b;
        }
    }
}

// ---------------- head ----------------
__global__ void head_kernel(const float* __restrict__ g1, const float* __restrict__ ac,
                            const float* __restrict__ Wc, const float* __restrict__ bc,
                            float* __restrict__ out, int ngraphs) {
    int gi = blockIdx.x * blockDim.x + threadIdx.x;
    if (gi >= ngraphs) return;
    float v[NCLS];
    #pragma unroll
    for (int c = 0; c < NCLS; c++) v[c] = bc[c];
    for (int k = 0; k < HDIM; k++) {
        float x = g1[(size_t)gi * HDIM + k] * ac[k] + ac[HDIM + k];
        #pragma unroll
        for (int c = 0; c < NCLS; c++) v[c] = fmaf(x, Wc[k * NCLS + c], v[c]);
    }
    float mx = v[0];
    #pragma unroll
    for (int c = 1; c < NCLS; c++) mx = fmaxf(mx, v[c]);
    float sum = 0.f;
    #pragma unroll
    for (int c = 0; c < NCLS; c++) sum += expf(v[c] - mx);
    float lse = mx + logf(sum);
    #pragma unroll
    for (int c = 0; c < NCLS; c++) out[(size_t)gi * NCLS + c] = v[c] - lse;
}

extern "C" void kernel_launch(void* const* d_in, const int* in_sizes, int n_in,
                              void* d_out, int out_size, void* d_ws, size_t ws_size,
                              hipStream_t stream) {
    const float* x         = (const float*)d_in[0];
    const int*   ei        = (const int*)  d_in[1];
    const int*   batch     = (const int*)  d_in[2];
    const float* bn_feat_w = (const float*)d_in[3];
    const float* bn_feat_b = (const float*)d_in[4];
    const float* Wf        = (const float*)d_in[5];
    const float* bfv       = (const float*)d_in[6];
    const float* bn_fc_w   = (const float*)d_in[7];
    const float* bn_fc_b   = (const float*)d_in[8];
    const float* Wl        = (const float*)d_in[9];
    const float* bl        = (const float*)d_in[10];
    const float* bn_hid_w  = (const float*)d_in[11];
    const float* bn_hid_b  = (const float*)d_in[12];
    const float* Wc        = (const float*)d_in[13];
    const float* bc        = (const float*)d_in[14];
    float* out = (float*)d_out;

    char* p = (char*)d_ws;
    auto alloc = [&](size_t bytes) { char* q = p; p += (bytes + 255) & ~(size_t)255; return q; };

    // slot-partial buffers (fully rewritten each call -> no zeroing anywhere)
    float* pstatX = (float*)alloc((size_t)256 * 2 * F_IN * 4);
    float* pstatT = (float*)alloc((size_t)1024 * 192 * 4);
    float* pstatG = (float*)alloc((size_t)N_GRAPHS * 192 * 4);
    float* pstatG1= (float*)alloc((size_t)16 * 192 * 4);

    u16*   hb     = (u16*)  alloc((size_t)N_NODES * HDIM * 2);
    float* tf     = (float*)alloc((size_t)N_NODES * HDIM * 4);
    float* g      = (float*)alloc((size_t)N_GRAPHS * HDIM * 4);
    float* g1     = (float*)alloc((size_t)N_GRAPHS * HDIM * 4);
    float* acX    = (float*)alloc(2 * F_IN * 4);
    float* acT    = (float*)alloc(2 * HDIM * 4);
    float* acG    = (float*)alloc(2 * HDIM * 4);
    float* acHid  = (float*)alloc(2 * HDIM * 4);
    u16*   wtF    = (u16*)  alloc(96 * F_IN * 2);
    float* bFmod  = (float*)alloc(96 * 4);
    u16*   wtH    = (u16*)  alloc((size_t)6 * 96 * HDIM * 2);
    float* bmH    = (float*)alloc((size_t)6 * 96 * 4);
    int* row_ptr  = (int*)alloc((size_t)(N_NODES + 1) * 4);
    int* csr      = (int*)alloc((size_t)N_EDGES * 4);
    int* cnt      = (int*)alloc((size_t)NBUCK2 * NEB * 4);
    int* ofs      = (int*)alloc((size_t)NBUCK2 * NEB * 4);
    int* stmp2    = (int*)alloc((size_t)NBUCK2 * NEB * 4);
    int* spart2   = (int*)alloc(64 * 4);
    u32* ebuf     = (u32*)alloc((size_t)N_EDGES * 4);

    const int* srcp = ei;
    const int* dstp = ei + N_EDGES;

    const int nch64  = (N_NODES + 63) / 64;
    const int gridF  = (nch64 < 768) ? nch64 : 768;
    const int grid96 = (nch64 < 1024) ? nch64 : 1024;   // 782
    const int gridG  = (N_GRAPHS + 31) / 32;            // 16
    const int ncb    = NBUCK2 * NEB;                    // 50048
    const int nscan2 = (ncb + 1023) / 1024;             // 49

    // BN(x) stats (slots) -> finalize -> fold into Wf -> h = relu(x @ Wf' + bf')
    colstats4_kernel<F_IN><<<256, 256, 0, stream>>>(x, pstatX, N_NODES);
    reduce_finalize_kernel<F_IN><<<1, F_IN * 8, 0, stream>>>(pstatX, 256, bn_feat_w, bn_feat_b, acX, 1.0f / N_NODES);
    wprep_all_kernel<<<WPF_BLOCKS + 6 * WPH_BLOCKS, 256, 0, stream>>>(
        Wf, bfv, acX,
        (const float*)d_in[15], (const float*)d_in[16],
        (const float*)d_in[19], (const float*)d_in[20],
        (const float*)d_in[21], (const float*)d_in[22],
        (const float*)d_in[25], (const float*)d_in[26],
        (const float*)d_in[27], (const float*)d_in[28],
        (const float*)d_in[31], (const float*)d_in[32],
        wtF, bFmod, wtH, bmH);
    mmx_kernel<F_IN, true, false, true, false, true><<<gridF, 256, 0, stream>>>(x, wtF, bFmod, nullptr, hb, nullptr, N_NODES);

    // CSR build (no global per-node histogram; row_ptr from bucket-local scan)
    count_kernel<<<NEB, 256, 0, stream>>>(dstp, cnt);
    scan1_kernel<<<nscan2, 1024, 0, stream>>>(cnt, stmp2, spart2, ncb);
    scan3_kernel<<<nscan2, 1024, 0, stream>>>(stmp2, spart2, ofs, ncb, nscan2);
    distribute_kernel<<<NEB, 256, 0, stream>>>(srcp, dstp, ofs, ebuf);
    bucket_fill2_kernel<<<NBUCK2, 256, 0, stream>>>(ebuf, ofs, row_ptr, csr);

    for (int l = 0; l < 3; l++) {
        const float* bw = (const float*)d_in[17 + 6 * l];
        const float* bb = (const float*)d_in[18 + 6 * l];
        u16*   wt1 = wtH + (size_t)(2 * l)     * 96 * HDIM;
        u16*   wt2 = wtH + (size_t)(2 * l + 1) * 96 * HDIM;
        float* b1m = bmH + (size_t)(2 * l)     * 96;
        float* b2m = bmH + (size_t)(2 * l + 1) * 96;
        // tf = (h + sum_nbr h) @ W1 + b1  (fused agg + mm1; f64 agg accum), stats slots
        aggmm_kernel<<<grid96, 256, 0, stream>>>(hb, row_ptr, csr, wt1, b1m, tf, pstatT, N_NODES);
        reduce_finalize_kernel<HDIM><<<1, HDIM * 8, 0, stream>>>(pstatT, grid96, bw, bb, acT, 1.0f / N_NODES);
        // h = relu( relu(BN(t_f32)) @ W2 + b2 ) -> bf16 hb
        mmx_kernel<HDIM, true, true, true, false, true><<<grid96, 256, 0, stream>>>(tf, wt2, b2m, acT, hb, nullptr, N_NODES);
    }

    // deterministic per-graph pool + fused stats partials
    pool_stats_kernel<<<N_GRAPHS, 96, 0, stream>>>(hb, batch, g, pstatG);
    reduce_finalize_kernel<HDIM><<<1, HDIM * 8, 0, stream>>>(pstatG, N_GRAPHS, bn_fc_w, bn_fc_b, acG, 1.0f / N_GRAPHS);
    mm_kernel<HDIM, true, false, true, true><<<gridG, 192, 0, stream>>>(g, Wl, bl, acG, g1, pstatG1, N_GRAPHS);
    reduce_finalize_kernel<HDIM><<<1, HDIM * 8, 0, stream>>>(pstatG1, gridG, bn_hid_w, bn_hid_b, acHid, 1.0f / N_GRAPHS);

    head_kernel<<<2, 256, 0, stream>>>(g1, acHid, Wc, bc, out, N_GRAPHS);
}

// Round 15
// 348.451 us; speedup vs baseline: 1.4647x; 1.0304x over previous
//
#include <hip/hip_runtime.h>

#define N_NODES 50000
#define N_EDGES 800000
#define N_GRAPHS 512
#define F_IN 128
#define HDIM 96
#define NCLS 10
#define BN_EPS 1e-5f

// partitioned CSR fill geometry
#define NPB 128
#define NBUCK2 ((N_NODES + NPB - 1) / NPB) // 391 buckets
#define NEB 128
#define EPB ((N_EDGES + NEB - 1) / NEB)    // 6250 edges per block

typedef unsigned int u32;
typedef unsigned short u16;
typedef __attribute__((ext_vector_type(8))) short bf16x8;
typedef __attribute__((ext_vector_type(4))) float f32x4;

__device__ __forceinline__ u16 f2bf(float f) {
    u32 u = __float_as_uint(f);
    u32 r = (u + 0x7fffu + ((u >> 16) & 1u)) >> 16;   // RNE
    return (u16)r;
}
__device__ __forceinline__ float bflo(u32 w) { return __uint_as_float(w << 16); }
__device__ __forceinline__ float bfhi(u32 w) { return __uint_as_float(w & 0xffff0000u); }
__device__ __forceinline__ float bf2f(u16 v) { return __uint_as_float((u32)v << 16); }

// ---------------- fused front kernel: colstats4(x) + edge-bucket count + all weight preps ----
// All three are input-independent of each other; one launch packs the GPU once.
#define CS_BLOCKS 256
#define WF_BLOCKS 48                 // ceil(128*96/256)
#define WPH_BLOCKS 36                // 96*96/256
#define FRONT_BLOCKS (CS_BLOCKS + NEB + WF_BLOCKS + 6 * WPH_BLOCKS)
__global__ __launch_bounds__(256) void front_kernel(
        const float* __restrict__ x, float* __restrict__ pstatX,
        const int* __restrict__ dst, int* __restrict__ cnt,
        const float* __restrict__ Wf, u16* __restrict__ wtF,
        const float* __restrict__ W0a, const float* __restrict__ b0a,
        const float* __restrict__ W0b, const float* __restrict__ b0b,
        const float* __restrict__ W1a, const float* __restrict__ b1a,
        const float* __restrict__ W1b, const float* __restrict__ b1b,
        const float* __restrict__ W2a, const float* __restrict__ b2a,
        const float* __restrict__ W2b, const float* __restrict__ b2b,
        u16* __restrict__ wtH, float* __restrict__ bmH) {
    const int tid = threadIdx.x;
    int blk = blockIdx.x;
    if (blk < CS_BLOCKS) {
        // column stats of x[N][128] -> slot partials
        constexpr int CG = F_IN / 4;      // 32
        constexpr int RPB = 256 / CG;     // 8
        const int cg = tid % CG;
        const int rg = tid / CG;
        float4 s = make_float4(0.f, 0.f, 0.f, 0.f);
        float4 q = make_float4(0.f, 0.f, 0.f, 0.f);
        for (int r = blk * RPB + rg; r < N_NODES; r += CS_BLOCKS * RPB) {
            float4 v = *(const float4*)&x[(size_t)r * F_IN + cg * 4];
            s.x += v.x; s.y += v.y; s.z += v.z; s.w += v.w;
            q.x += v.x * v.x; q.y += v.y * v.y; q.z += v.z * v.z; q.w += v.w * v.w;
        }
        __shared__ float ss[8][F_IN], sq[8][F_IN];
        *(float4*)&ss[rg][cg * 4] = s;
        *(float4*)&sq[rg][cg * 4] = q;
        __syncthreads();
        if (tid < F_IN) {
            float a = 0.f, b = 0.f;
            #pragma unroll
            for (int r = 0; r < 8; r++) { a += ss[r][tid]; b += sq[r][tid]; }
            pstatX[(size_t)blk * 2 * F_IN + tid]        = a;
            pstatX[(size_t)blk * 2 * F_IN + F_IN + tid] = b;
        }
        return;
    }
    blk -= CS_BLOCKS;
    if (blk < NEB) {
        __shared__ int lc[NBUCK2];
        for (int i = tid; i < NBUCK2; i += 256) lc[i] = 0;
        __syncthreads();
        const int lo = blk * EPB;
        const int hi = min(lo + EPB, N_EDGES);
        for (int e = lo + tid; e < hi; e += 256)
            atomicAdd(&lc[dst[e] / NPB], 1);
        __syncthreads();
        for (int i = tid; i < NBUCK2; i += 256)
            cnt[i * NEB + blk] = lc[i];
        return;
    }
    blk -= NEB;
    if (blk < WF_BLOCKS) {
        int i = blk * 256 + tid;
        if (i < F_IN * 96) {
            int k = i / 96, n = i % 96;
            wtF[n * F_IN + k] = f2bf(Wf[i]);
        }
        return;
    }
    blk -= WF_BLOCKS;
    const int s  = blk / WPH_BLOCKS;
    const int b2 = blk % WPH_BLOCKS;
    const float* W; const float* bias;
    switch (s) {
        case 0: W = W0a; bias = b0a; break;
        case 1: W = W0b; bias = b0b; break;
        case 2: W = W1a; bias = b1a; break;
        case 3: W = W1b; bias = b1b; break;
        case 4: W = W2a; bias = b2a; break;
        default: W = W2b; bias = b2b; break;
    }
    u16*   wtb  = wtH + (size_t)s * 96 * HDIM;
    float* bmod = bmH + (size_t)s * 96;
    int i = b2 * 256 + tid;
    if (i < HDIM * 96) {
        int k = i / 96, n = i % 96;
        wtb[n * HDIM + k] = f2bf(W[i]);
    }
    if (b2 == 0 && tid < 96) bmod[tid] = bias[tid];
}

// group-parallel fixed-order slot reduction + BN finalize (deterministic)
template<int NCOLS>
__global__ __launch_bounds__(NCOLS * 8) void reduce_finalize_kernel(
        const float* __restrict__ partials, int nslots,
        const float* __restrict__ w,
        const float* __restrict__ b,
        float* __restrict__ ac, float inv_n) {
    const int k   = threadIdx.x % NCOLS;
    const int grp = threadIdx.x / NCOLS;   // 0..7
    const int stride = 2 * NCOLS;
    float s = 0.f, q = 0.f;
    for (int i = grp; i < nslots; i += 8) {
        s += partials[(size_t)i * stride + k];
        q += partials[(size_t)i * stride + NCOLS + k];
    }
    __shared__ float ss[8][NCOLS], sq[8][NCOLS];
    ss[grp][k] = s; sq[grp][k] = q;
    __syncthreads();
    if (grp == 0) {
        float S = ((ss[0][k] + ss[1][k]) + (ss[2][k] + ss[3][k]))
                + ((ss[4][k] + ss[5][k]) + (ss[6][k] + ss[7][k]));
        float Q = ((sq[0][k] + sq[1][k]) + (sq[2][k] + sq[3][k]))
                + ((sq[4][k] + sq[5][k]) + (sq[6][k] + sq[7][k]));
        float mu  = S * inv_n;
        float var = Q * inv_n - mu * mu;
        float a   = w[k] * rsqrtf(var + BN_EPS);
        ac[k]         = a;
        ac[NCOLS + k] = b[k] - mu * a;
    }
}

// ---------------- CSR build ----------------
__global__ __launch_bounds__(1024) void scan1_kernel(const int* __restrict__ in,
                                                     int* __restrict__ tmp,
                                                     int* __restrict__ partial, int n) {
    __shared__ int sh[1024];
    const int i = blockIdx.x * 1024 + threadIdx.x;
    const int d = (i < n) ? in[i] : 0;
    sh[threadIdx.x] = d;
    __syncthreads();
    for (int off = 1; off < 1024; off <<= 1) {
        int v = 0;
        if (threadIdx.x >= off) v = sh[threadIdx.x - off];
        __syncthreads();
        sh[threadIdx.x] += v;
        __syncthreads();
    }
    if (i < n) tmp[i] = sh[threadIdx.x] - d;
    if (threadIdx.x == 1023) partial[blockIdx.x] = sh[1023];
}

__global__ __launch_bounds__(1024) void scan3_kernel(const int* __restrict__ tmp,
                                                     const int* __restrict__ partial,
                                                     int* __restrict__ out,
                                                     int n, int nparts) {
    __shared__ int offs;
    if (threadIdx.x < 64) {
        int v = (threadIdx.x < blockIdx.x && (int)threadIdx.x < nparts) ? partial[threadIdx.x] : 0;
        for (int o = 32; o > 0; o >>= 1) v += __shfl_down(v, o, 64);
        if (threadIdx.x == 0) offs = v;
    }
    __syncthreads();
    const int i = blockIdx.x * 1024 + threadIdx.x;
    if (i < n) out[i] = tmp[i] + offs;
}

__global__ __launch_bounds__(256) void distribute_kernel(const int* __restrict__ src,
                                                         const int* __restrict__ dst,
                                                         const int* __restrict__ ofs,
                                                         u32* __restrict__ ebuf) {
    __shared__ int lofs[NBUCK2];
    for (int i = threadIdx.x; i < NBUCK2; i += 256) lofs[i] = ofs[i * NEB + blockIdx.x];
    __syncthreads();
    const int lo = blockIdx.x * EPB;
    const int hi = min(lo + EPB, N_EDGES);
    for (int e = lo + threadIdx.x; e < hi; e += 256) {
        int d = dst[e];
        int q = atomicAdd(&lofs[d / NPB], 1);
        ebuf[q] = ((u32)src[e] << 7) | (u32)(d & (NPB - 1));
    }
}

// bucket fill v2: row_ptr from LDS-local histogram + scan, then csr scatter
__global__ __launch_bounds__(256) void bucket_fill2_kernel(const u32* __restrict__ ebuf,
                                                           const int* __restrict__ ofs,
                                                           int* __restrict__ row_ptr,
                                                           int* __restrict__ csr) {
    __shared__ int lcnt[NPB], lpos[NPB];
    const int p    = blockIdx.x;
    const int base = p * NPB;
    const int nn   = min(NPB, N_NODES - base);
    const int tid  = threadIdx.x;
    const int e0 = ofs[p * NEB];
    const int e1 = (p + 1 < NBUCK2) ? ofs[(p + 1) * NEB] : N_EDGES;
    for (int i = tid; i < NPB; i += 256) lcnt[i] = 0;
    __syncthreads();
    for (int e = e0 + tid; e < e1; e += 256)
        atomicAdd(&lcnt[ebuf[e] & (NPB - 1)], 1);
    __syncthreads();
    if (tid < NPB) lpos[tid] = lcnt[tid];
    __syncthreads();
    for (int off = 1; off < NPB; off <<= 1) {
        int v = 0;
        if (tid < NPB && tid >= off) v = lpos[tid - off];
        __syncthreads();
        if (tid < NPB) lpos[tid] += v;
        __syncthreads();
    }
    if (tid < NPB) {
        int excl = lpos[tid] - lcnt[tid];
        lpos[tid] = e0 + excl;
        if (tid < nn) row_ptr[base + tid] = e0 + excl;
    }
    if (p == NBUCK2 - 1 && tid == 0) row_ptr[N_NODES] = N_EDGES;
    __syncthreads();
    for (int e = e0 + tid; e < e1; e += 256) {
        u32 v = ebuf[e];
        int pos = atomicAdd(&lpos[v & (NPB - 1)], 1);
        csr[pos] = (int)(v >> 7);
    }
}

// ---------------- fused GIN agg + mm1:  tf = (h + sum_nbr h) @ W1 + b1, stats(tf) ----------------
__global__ __launch_bounds__(256) void aggmm_kernel(const u16* __restrict__ hb,
                                                    const int* __restrict__ row_ptr,
                                                    const int* __restrict__ csr,
                                                    const u16* __restrict__ wt,   // [96][96] bf16
                                                    const float* __restrict__ bias,
                                                    float* __restrict__ tf,
                                                    float* __restrict__ partials,
                                                    int nrows) {
    constexpr int KP = HDIM + 8;      // 104
    constexpr int KB = HDIM / 32;     // 3
    __shared__ u16 wlds[96 * KP];
    __shared__ u16 alds[64 * KP];
    __shared__ float sred[2][4][96];
    const int tid = threadIdx.x;

    for (int i = tid; i < 96 * (HDIM / 8); i += 256) {
        int nn = i / (HDIM / 8), c8 = i % (HDIM / 8);
        *(uint4*)&wlds[nn * KP + c8 * 8] = *(const uint4*)&wt[nn * HDIM + c8 * 8];
    }

    const int w    = tid >> 6;
    const int lane = tid & 63;
    const int r16  = lane & 15;
    const int kg   = lane >> 4;
    const int m0   = w * 16;
    float bn[6];
    #pragma unroll
    for (int nt = 0; nt < 6; nt++) bn[nt] = bias[nt * 16 + r16];
    float scol[6] = {0,0,0,0,0,0}, qcol[6] = {0,0,0,0,0,0};

    const int nchunks = (nrows + 63) / 64;
    for (int chunk = blockIdx.x; chunk < nchunks; chunk += gridDim.x) {
        const int row0 = chunk * 64;
        __syncthreads();
        for (int t = tid; t < 64 * 12; t += 256) {
            const int r  = t / 12, sl = t % 12;
            const int node = row0 + r;
            uint4 ov = make_uint4(0u, 0u, 0u, 0u);
            if (node < nrows) {
                const int p0 = row_ptr[node], p1 = row_ptr[node + 1];
                uint4 sv = *(const uint4*)&hb[(size_t)node * 96 + sl * 8];
                double a0 = bflo(sv.x), a1 = bfhi(sv.x), a2 = bflo(sv.y), a3 = bfhi(sv.y);
                double a4 = bflo(sv.z), a5 = bfhi(sv.z), a6 = bflo(sv.w), a7 = bfhi(sv.w);
                int p = p0;
                for (; p + 4 <= p1; p += 4) {
                    int s0 = csr[p], s1 = csr[p + 1], s2 = csr[p + 2], s3 = csr[p + 3];
                    uint4 v0 = *(const uint4*)&hb[(size_t)s0 * 96 + sl * 8];
                    uint4 v1 = *(const uint4*)&hb[(size_t)s1 * 96 + sl * 8];
                    uint4 v2 = *(const uint4*)&hb[(size_t)s2 * 96 + sl * 8];
                    uint4 v3 = *(const uint4*)&hb[(size_t)s3 * 96 + sl * 8];
                    a0 += bflo(v0.x); a0 += bflo(v1.x); a0 += bflo(v2.x); a0 += bflo(v3.x);
                    a1 += bfhi(v0.x); a1 += bfhi(v1.x); a1 += bfhi(v2.x); a1 += bfhi(v3.x);
                    a2 += bflo(v0.y); a2 += bflo(v1.y); a2 += bflo(v2.y); a2 += bflo(v3.y);
                    a3 += bfhi(v0.y); a3 += bfhi(v1.y); a3 += bfhi(v2.y); a3 += bfhi(v3.y);
                    a4 += bflo(v0.z); a4 += bflo(v1.z); a4 += bflo(v2.z); a4 += bflo(v3.z);
                    a5 += bfhi(v0.z); a5 += bfhi(v1.z); a5 += bfhi(v2.z); a5 += bfhi(v3.z);
                    a6 += bflo(v0.w); a6 += bflo(v1.w); a6 += bflo(v2.w); a6 += bflo(v3.w);
                    a7 += bfhi(v0.w); a7 += bfhi(v1.w); a7 += bfhi(v2.w); a7 += bfhi(v3.w);
                }
                for (; p < p1; p++) {
                    int s = csr[p];
                    uint4 v = *(const uint4*)&hb[(size_t)s * 96 + sl * 8];
                    a0 += bflo(v.x); a1 += bfhi(v.x); a2 += bflo(v.y); a3 += bfhi(v.y);
                    a4 += bflo(v.z); a5 += bfhi(v.z); a6 += bflo(v.w); a7 += bfhi(v.w);
                }
                ov.x = (u32)f2bf((float)a0) | ((u32)f2bf((float)a1) << 16);
                ov.y = (u32)f2bf((float)a2) | ((u32)f2bf((float)a3) << 16);
                ov.z = (u32)f2bf((float)a4) | ((u32)f2bf((float)a5) << 16);
                ov.w = (u32)f2bf((float)a6) | ((u32)f2bf((float)a7) << 16);
            }
            *(uint4*)&alds[r * KP + sl * 8] = ov;
        }
        __syncthreads();

        bf16x8 af[KB];
        #pragma unroll
        for (int kb = 0; kb < KB; kb++)
            af[kb] = *(const bf16x8*)&alds[(m0 + r16) * KP + kb * 32 + kg * 8];

        f32x4 acc[6];
        #pragma unroll
        for (int nt = 0; nt < 6; nt++) acc[nt] = (f32x4){bn[nt], bn[nt], bn[nt], bn[nt]};
        #pragma unroll
        for (int kb = 0; kb < KB; kb++) {
            #pragma unroll
            for (int nt = 0; nt < 6; nt++) {
                bf16x8 bfr = *(const bf16x8*)&wlds[(nt * 16 + r16) * KP + kb * 32 + kg * 8];
                acc[nt] = __builtin_amdgcn_mfma_f32_16x16x32_bf16(af[kb], bfr, acc[nt], 0, 0, 0);
            }
        }

        const int gr0  = row0 + m0 + kg * 4;
        const bool full = (gr0 + 3 < nrows);
        #pragma unroll
        for (int nt = 0; nt < 6; nt++) {
            const int n = nt * 16 + r16;
            #pragma unroll
            for (int rr = 0; rr < 4; rr++) {
                const int gr = gr0 + rr;
                if (full || gr < nrows) {
                    float v = acc[nt][rr];
                    tf[(size_t)gr * 96 + n] = v;
                    scol[nt] += v; qcol[nt] += v * v;
                }
            }
        }
    }

    #pragma unroll
    for (int nt = 0; nt < 6; nt++) {
        scol[nt] += __shfl_xor(scol[nt], 16);
        scol[nt] += __shfl_xor(scol[nt], 32);
        qcol[nt] += __shfl_xor(qcol[nt], 16);
        qcol[nt] += __shfl_xor(qcol[nt], 32);
    }
    __syncthreads();
    if (kg == 0) {
        #pragma unroll
        for (int nt = 0; nt < 6; nt++) {
            sred[0][w][nt * 16 + r16] = scol[nt];
            sred[1][w][nt * 16 + r16] = qcol[nt];
        }
    }
    __syncthreads();
    if (tid < 96) {
        float a = (sred[0][0][tid] + sred[0][1][tid]) + (sred[0][2][tid] + sred[0][3][tid]);
        float b = (sred[1][0][tid] + sred[1][1][tid]) + (sred[1][2][tid] + sred[1][3][tid]);
        partials[(size_t)blockIdx.x * 192 + tid]      = a;
        partials[(size_t)blockIdx.x * 192 + 96 + tid] = b;
    }
}

// ---------------- MFMA matmul (mmF and mm2) ----------------
// IN_AFF: affine at f32 staging; IN_RELU_STAGE: relu after affine (before bf16 rounding).
template<int KDIM, bool IN_F32, bool IN_AFF, bool IN_RELU_STAGE, bool OUT_RELU, bool STATS, bool OUT_BF16>
__global__ __launch_bounds__(256) void mmx_kernel(const void* __restrict__ in_,
                                                  const u16* __restrict__ wt,
                                                  const float* __restrict__ bias,
                                                  const float* __restrict__ ac,
                                                  void* __restrict__ out_,
                                                  float* __restrict__ partials,
                                                  int nrows) {
    constexpr int KP = KDIM + 8;
    constexpr int KB = KDIM / 32;
    __shared__ u16 wlds[96 * KP];
    __shared__ u16 alds[64 * KP];
    __shared__ float sred[2][4][96];
    const int tid = threadIdx.x;

    for (int i = tid; i < 96 * (KDIM / 8); i += 256) {
        int nn = i / (KDIM / 8), c8 = i % (KDIM / 8);
        *(uint4*)&wlds[nn * KP + c8 * 8] = *(const uint4*)&wt[nn * KDIM + c8 * 8];
    }

    const int w    = tid >> 6;
    const int lane = tid & 63;
    const int r16  = lane & 15;
    const int kg   = lane >> 4;
    const int m0   = w * 16;
    float bn[6];
    #pragma unroll
    for (int nt = 0; nt < 6; nt++) bn[nt] = bias[nt * 16 + r16];
    float scol[6] = {0,0,0,0,0,0}, qcol[6] = {0,0,0,0,0,0};

    const int nchunks = (nrows + 63) / 64;
    for (int chunk = blockIdx.x; chunk < nchunks; chunk += gridDim.x) {
        const int row0 = chunk * 64;
        __syncthreads();
        if constexpr (IN_F32) {
            const float* inf = (const float*)in_;
            for (int i = tid; i < 64 * (KDIM / 4); i += 256) {
                int r = i / (KDIM / 4), c4 = i % (KDIM / 4);
                int gr = row0 + r;
                float4 v = (gr < nrows) ? *(const float4*)&inf[(size_t)gr * KDIM + c4 * 4]
                                        : make_float4(0.f, 0.f, 0.f, 0.f);
                if constexpr (IN_AFF) {
                    float4 a = *(const float4*)&ac[c4 * 4];
                    float4 c = *(const float4*)&ac[KDIM + c4 * 4];
                    v.x = v.x * a.x + c.x; v.y = v.y * a.y + c.y;
                    v.z = v.z * a.z + c.z; v.w = v.w * a.w + c.w;
                }
                if constexpr (IN_RELU_STAGE) {
                    v.x = fmaxf(v.x, 0.f); v.y = fmaxf(v.y, 0.f);
                    v.z = fmaxf(v.z, 0.f); v.w = fmaxf(v.w, 0.f);
                }
                ushort4 o; o.x = f2bf(v.x); o.y = f2bf(v.y); o.z = f2bf(v.z); o.w = f2bf(v.w);
                *(ushort4*)&alds[r * KP + c4 * 4] = o;
            }
        } else {
            const u16* inb = (const u16*)in_;
            for (int i = tid; i < 64 * (KDIM / 8); i += 256) {
                int r = i / (KDIM / 8), c8 = i % (KDIM / 8);
                int gr = row0 + r;
                uint4 v = (gr < nrows) ? *(const uint4*)&inb[(size_t)gr * KDIM + c8 * 8]
                                       : make_uint4(0u, 0u, 0u, 0u);
                *(uint4*)&alds[r * KP + c8 * 8] = v;
            }
        }
        __syncthreads();

        bf16x8 af[KB];
        #pragma unroll
        for (int kb = 0; kb < KB; kb++)
            af[kb] = *(const bf16x8*)&alds[(m0 + r16) * KP + kb * 32 + kg * 8];

        f32x4 acc[6];
        #pragma unroll
        for (int nt = 0; nt < 6; nt++) acc[nt] = (f32x4){bn[nt], bn[nt], bn[nt], bn[nt]};
        #pragma unroll
        for (int kb = 0; kb < KB; kb++) {
            #pragma unroll
            for (int nt = 0; nt < 6; nt++) {
                bf16x8 bfr = *(const bf16x8*)&wlds[(nt * 16 + r16) * KP + kb * 32 + kg * 8];
                acc[nt] = __builtin_amdgcn_mfma_f32_16x16x32_bf16(af[kb], bfr, acc[nt], 0, 0, 0);
            }
        }

        const int gr0  = row0 + m0 + kg * 4;
        const bool full = (gr0 + 3 < nrows);
        #pragma unroll
        for (int nt = 0; nt < 6; nt++) {
            float v[4] = {acc[nt][0], acc[nt][1], acc[nt][2], acc[nt][3]};
            if constexpr (OUT_RELU) {
                #pragma unroll
                for (int rr = 0; rr < 4; rr++) v[rr] = fmaxf(v[rr], 0.f);
            }
            const int n = nt * 16 + r16;
            #pragma unroll
            for (int rr = 0; rr < 4; rr++) {
                const int gr = gr0 + rr;
                if (full || gr < nrows) {
                    if constexpr (OUT_BF16) ((u16*)out_)[(size_t)gr * 96 + n] = f2bf(v[rr]);
                    else                    ((float*)out_)[(size_t)gr * 96 + n] = v[rr];
                    if constexpr (STATS) { scol[nt] += v[rr]; qcol[nt] += v[rr] * v[rr]; }
                }
            }
        }
    }

    if constexpr (STATS) {
        #pragma unroll
        for (int nt = 0; nt < 6; nt++) {
            scol[nt] += __shfl_xor(scol[nt], 16);
            scol[nt] += __shfl_xor(scol[nt], 32);
            qcol[nt] += __shfl_xor(qcol[nt], 16);
            qcol[nt] += __shfl_xor(qcol[nt], 32);
        }
        __syncthreads();
        if (kg == 0) {
            #pragma unroll
            for (int nt = 0; nt < 6; nt++) {
                sred[0][w][nt * 16 + r16] = scol[nt];
                sred[1][w][nt * 16 + r16] = qcol[nt];
            }
        }
        __syncthreads();
        if (tid < 96) {
            float a = (sred[0][0][tid] + sred[0][1][tid]) + (sred[0][2][tid] + sred[0][3][tid]);
            float b = (sred[1][0][tid] + sred[1][1][tid]) + (sred[1][2][tid] + sred[1][3][tid]);
            partials[(size_t)blockIdx.x * 192 + tid]      = a;
            partials[(size_t)blockIdx.x * 192 + 96 + tid] = b;
        }
    }
}

// ---------------- deterministic per-graph pool + fused stats partials ----------------
__device__ __forceinline__ int lower_bound_dev(const int* __restrict__ a, int n, int v) {
    int lo = 0, hi = n;
    while (lo < hi) { int m = (lo + hi) >> 1; if (a[m] < v) lo = m + 1; else hi = m; }
    return lo;
}
__global__ __launch_bounds__(96) void pool_stats_kernel(const u16* __restrict__ hb,
                                                        const int* __restrict__ batch,
                                                        float* __restrict__ g,
                                                        float* __restrict__ partials) {
    const int gi = blockIdx.x;
    __shared__ int sh_lo, sh_hi;
    if (threadIdx.x == 0) sh_lo = lower_bound_dev(batch, N_NODES, gi);
    if (threadIdx.x == 1) sh_hi = lower_bound_dev(batch, N_NODES, gi + 1);
    __syncthreads();
    const int lo = sh_lo, hi = sh_hi;
    const int j = threadIdx.x;
    float s0 = 0.f, s1 = 0.f, s2 = 0.f, s3 = 0.f;
    int r = lo;
    for (; r + 4 <= hi; r += 4) {
        s0 += bf2f(hb[(size_t)r       * 96 + j]);
        s1 += bf2f(hb[(size_t)(r + 1) * 96 + j]);
        s2 += bf2f(hb[(size_t)(r + 2) * 96 + j]);
        s3 += bf2f(hb[(size_t)(r + 3) * 96 + j]);
    }
    for (; r < hi; r++) s0 += bf2f(hb[(size_t)r * 96 + j]);
    float val = (s0 + s1) + (s2 + s3);
    g[(size_t)gi * 96 + j] = val;
    partials[(size_t)gi * 192 + j]      = val;
    partials[(size_t)gi * 192 + 96 + j] = val * val;
}

// ---------------- f32 small matmul (G-sized tail; STATS -> slots) ----------------
template<int KDIM, bool IN_AFF, bool IN_RELU, bool OUT_RELU, bool STATS>
__global__ __launch_bounds__(192) void mm_kernel(const float* __restrict__ in,
                                                 const float* __restrict__ W,
                                                 const float* __restrict__ bias,
                                                 const float* __restrict__ ac,
                                                 float* __restrict__ out,
                                                 float* __restrict__ partials, int nrows) {
    constexpr int KG = KDIM / 4;
    __shared__ float ws[KDIM][96];
    __shared__ float xs[32][KDIM];
    const int tid = threadIdx.x;
    const int cg  = tid % 24;
    const int rg  = tid / 24;
    for (int i = tid; i < KDIM * 24; i += 192) {
        int k = i / 24, c4 = i % 24;
        *(float4*)&ws[k][c4 * 4] = *(const float4*)&W[(size_t)k * 96 + c4 * 4];
    }
    const float4 bj = *(const float4*)&bias[cg * 4];
    float s0=0,s1=0,s2=0,s3=0, q0=0,q1=0,q2=0,q3=0;
    const int nchunks = (nrows + 31) / 32;
    for (int chunk = blockIdx.x; chunk < nchunks; chunk += gridDim.x) {
        const int row0 = chunk * 32;
        __syncthreads();
        for (int i = tid; i < 32 * KG; i += 192) {
            int r = i / KG, g = i % KG;
            int gr = row0 + r;
            float4 v = make_float4(0.f, 0.f, 0.f, 0.f);
            if (gr < nrows) v = *(const float4*)&in[(size_t)gr * KDIM + g * 4];
            if constexpr (IN_AFF) {
                float4 a = *(const float4*)&ac[g * 4];
                float4 c = *(const float4*)&ac[KDIM + g * 4];
                v.x = v.x * a.x + c.x; v.y = v.y * a.y + c.y;
                v.z = v.z * a.z + c.z; v.w = v.w * a.w + c.w;
            }
            if constexpr (IN_RELU) {
                v.x = fmaxf(v.x, 0.f); v.y = fmaxf(v.y, 0.f);
                v.z = fmaxf(v.z, 0.f); v.w = fmaxf(v.w, 0.f);
            }
            *(float4*)&xs[r][4 * (g ^ (r & 7))] = v;
        }
        __syncthreads();
        float acc[4][4];
        #pragma unroll
        for (int m = 0; m < 4; m++) {
            acc[m][0] = bj.x; acc[m][1] = bj.y; acc[m][2] = bj.z; acc[m][3] = bj.w;
        }
        #pragma unroll 4
        for (int g = 0; g < KG; g++) {
            const int xi = 4 * (g ^ rg);
            float4 xv0 = *(const float4*)&xs[rg     ][xi];
            float4 xv1 = *(const float4*)&xs[rg +  8][xi];
            float4 xv2 = *(const float4*)&xs[rg + 16][xi];
            float4 xv3 = *(const float4*)&xs[rg + 24][xi];
            #pragma unroll
            for (int i = 0; i < 4; i++) {
                float4 wv = *(const float4*)&ws[g * 4 + i][cg * 4];
                float x0 = (i==0)?xv0.x:(i==1)?xv0.y:(i==2)?xv0.z:xv0.w;
                float x1 = (i==0)?xv1.x:(i==1)?xv1.y:(i==2)?xv1.z:xv1.w;
                float x2 = (i==0)?xv2.x:(i==1)?xv2.y:(i==2)?xv2.z:xv2.w;
                float x3 = (i==0)?xv3.x:(i==1)?xv3.y:(i==2)?xv3.z:xv3.w;
                acc[0][0] = fmaf(x0, wv.x, acc[0][0]); acc[0][1] = fmaf(x0, wv.y, acc[0][1]);
                acc[0][2] = fmaf(x0, wv.z, acc[0][2]); acc[0][3] = fmaf(x0, wv.w, acc[0][3]);
                acc[1][0] = fmaf(x1, wv.x, acc[1][0]); acc[1][1] = fmaf(x1, wv.y, acc[1][1]);
                acc[1][2] = fmaf(x1, wv.z, acc[1][2]); acc[1][3] = fmaf(x1, wv.w, acc[1][3]);
                acc[2][0] = fmaf(x2, wv.x, acc[2][0]); acc[2][1] = fmaf(x2, wv.y, acc[2][1]);
                acc[2][2] = fmaf(x2, wv.z, acc[2][2]); acc[2][3] = fmaf(x2, wv.w, acc[2][3]);
                acc[3][0] = fmaf(x3, wv.x, acc[3][0]); acc[3][1] = fmaf(x3, wv.y, acc[3][1]);
                acc[3][2] = fmaf(x3, wv.z, acc[3][2]); acc[3][3] = fmaf(x3, wv.w, acc[3][3]);
            }
        }
        #pragma unroll
        for (int m = 0; m < 4; m++) {
            const int gr = row0 + rg + 8 * m;
            if (gr < nrows) {
                float4 o = make_float4(acc[m][0], acc[m][1], acc[m][2], acc[m][3]);
                if constexpr (OUT_RELU) {
                    o.x = fmaxf(o.x, 0.f); o.y = fmaxf(o.y, 0.f);
                    o.z = fmaxf(o.z, 0.f); o.w = fmaxf(o.w, 0.f);
                }
                *(float4*)&out[(size_t)gr * 96 + cg * 4] = o;
                if constexpr (STATS) {
                    s0 += o.x; q0 += o.x * o.x; s1 += o.y; q1 += o.y * o.y;
                    s2 += o.z; q2 += o.z * o.z; s3 += o.w; q3 += o.w * o.w;
                }
            }
        }
    }
    if constexpr (STATS) {
        __syncthreads();
        float* rs = &xs[0][0];
        float* rq = rs + 8 * 96;
        rs[rg * 96 + cg * 4 + 0] = s0; rs[rg * 96 + cg * 4 + 1] = s1;
        rs[rg * 96 + cg * 4 + 2] = s2; rs[rg * 96 + cg * 4 + 3] = s3;
        rq[rg * 96 + cg * 4 + 0] = q0; rq[rg * 96 + cg * 4 + 1] = q1;
        rq[rg * 96 + cg * 4 + 2] = q2; rq[rg * 96 + cg * 4 + 3] = q3;
        __syncthreads();
        if (tid < 96) {
            float a = 0.f, b = 0.f;
            #pragma unroll
            for (int r = 0; r < 8; r++) { a += rs[r * 96 + tid]; b += rq[r * 96 + tid]; }
            partials[(size_t)blockIdx.x * 192 + tid]      = a;
            partials[(size_t)blockIdx.x * 192 + 96 + tid] = b;
        }
    }
}

// ---------------- head ----------------
__global__ void head_kernel(const float* __restrict__ g1, const float* __restrict__ ac,
                            const float* __restrict__ Wc, const float* __restrict__ bc,
                            float* __restrict__ out, int ngraphs) {
    int gi = blockIdx.x * blockDim.x + threadIdx.x;
    if (gi >= ngraphs) return;
    float v[NCLS];
    #pragma unroll
    for (int c = 0; c < NCLS; c++) v[c] = bc[c];
    for (int k = 0; k < HDIM; k++) {
        float x = g1[(size_t)gi * HDIM + k] * ac[k] + ac[HDIM + k];
        #pragma unroll
        for (int c = 0; c < NCLS; c++) v[c] = fmaf(x, Wc[k * NCLS + c], v[c]);
    }
    float mx = v[0];
    #pragma unroll
    for (int c = 1; c < NCLS; c++) mx = fmaxf(mx, v[c]);
    float sum = 0.f;
    #pragma unroll
    for (int c = 0; c < NCLS; c++) sum += expf(v[c] - mx);
    float lse = mx + logf(sum);
    #pragma unroll
    for (int c = 0; c < NCLS; c++) out[(size_t)gi * NCLS + c] = v[c] - lse;
}

extern "C" void kernel_launch(void* const* d_in, const int* in_sizes, int n_in,
                              void* d_out, int out_size, void* d_ws, size_t ws_size,
                              hipStream_t stream) {
    const float* x         = (const float*)d_in[0];
    const int*   ei        = (const int*)  d_in[1];
    const int*   batch     = (const int*)  d_in[2];
    const float* bn_feat_w = (const float*)d_in[3];
    const float* bn_feat_b = (const float*)d_in[4];
    const float* Wf        = (const float*)d_in[5];
    const float* bfv       = (const float*)d_in[6];
    const float* bn_fc_w   = (const float*)d_in[7];
    const float* bn_fc_b   = (const float*)d_in[8];
    const float* Wl        = (const float*)d_in[9];
    const float* bl        = (const float*)d_in[10];
    const float* bn_hid_w  = (const float*)d_in[11];
    const float* bn_hid_b  = (const float*)d_in[12];
    const float* Wc        = (const float*)d_in[13];
    const float* bc        = (const float*)d_in[14];
    float* out = (float*)d_out;

    char* p = (char*)d_ws;
    auto alloc = [&](size_t bytes) { char* q = p; p += (bytes + 255) & ~(size_t)255; return q; };

    // slot-partial buffers (fully rewritten each call -> no zeroing anywhere)
    float* pstatX = (float*)alloc((size_t)256 * 2 * F_IN * 4);
    float* pstatT = (float*)alloc((size_t)1024 * 192 * 4);
    float* pstatG = (float*)alloc((size_t)N_GRAPHS * 192 * 4);
    float* pstatG1= (float*)alloc((size_t)16 * 192 * 4);

    u16*   hb     = (u16*)  alloc((size_t)N_NODES * HDIM * 2);
    float* tf     = (float*)alloc((size_t)N_NODES * HDIM * 4);
    float* g      = (float*)alloc((size_t)N_GRAPHS * HDIM * 4);
    float* g1     = (float*)alloc((size_t)N_GRAPHS * HDIM * 4);
    float* acX    = (float*)alloc(2 * F_IN * 4);
    float* acT    = (float*)alloc(2 * HDIM * 4);
    float* acG    = (float*)alloc(2 * HDIM * 4);
    float* acHid  = (float*)alloc(2 * HDIM * 4);
    u16*   wtF    = (u16*)  alloc(96 * F_IN * 2);
    u16*   wtH    = (u16*)  alloc((size_t)6 * 96 * HDIM * 2);
    float* bmH    = (float*)alloc((size_t)6 * 96 * 4);
    int* row_ptr  = (int*)alloc((size_t)(N_NODES + 1) * 4);
    int* csr      = (int*)alloc((size_t)N_EDGES * 4);
    int* cnt      = (int*)alloc((size_t)NBUCK2 * NEB * 4);
    int* ofs      = (int*)alloc((size_t)NBUCK2 * NEB * 4);
    int* stmp2    = (int*)alloc((size_t)NBUCK2 * NEB * 4);
    int* spart2   = (int*)alloc(64 * 4);
    u32* ebuf     = (u32*)alloc((size_t)N_EDGES * 4);

    const int* srcp = ei;
    const int* dstp = ei + N_EDGES;

    const int nch64  = (N_NODES + 63) / 64;
    const int gridF  = (nch64 < 768) ? nch64 : 768;
    const int grid96 = (nch64 < 1024) ? nch64 : 1024;   // 782
    const int gridG  = (N_GRAPHS + 31) / 32;            // 16
    const int ncb    = NBUCK2 * NEB;                    // 50048
    const int nscan2 = (ncb + 1023) / 1024;             // 49

    // fused front: colstats4(x) + edge-bucket count + all 7 weight transposes
    front_kernel<<<FRONT_BLOCKS, 256, 0, stream>>>(
        x, pstatX, dstp, cnt, Wf, wtF,
        (const float*)d_in[15], (const float*)d_in[16],
        (const float*)d_in[19], (const float*)d_in[20],
        (const float*)d_in[21], (const float*)d_in[22],
        (const float*)d_in[25], (const float*)d_in[26],
        (const float*)d_in[27], (const float*)d_in[28],
        (const float*)d_in[31], (const float*)d_in[32],
        wtH, bmH);
    reduce_finalize_kernel<F_IN><<<1, F_IN * 8, 0, stream>>>(pstatX, 256, bn_feat_w, bn_feat_b, acX, 1.0f / N_NODES);
    // h = relu( BN(x) @ Wf + bf ): affine applied at f32 staging, bf16 out
    mmx_kernel<F_IN, true, true, false, true, false, true><<<gridF, 256, 0, stream>>>(x, wtF, bfv, acX, hb, nullptr, N_NODES);

    // CSR build
    scan1_kernel<<<nscan2, 1024, 0, stream>>>(cnt, stmp2, spart2, ncb);
    scan3_kernel<<<nscan2, 1024, 0, stream>>>(stmp2, spart2, ofs, ncb, nscan2);
    distribute_kernel<<<NEB, 256, 0, stream>>>(srcp, dstp, ofs, ebuf);
    bucket_fill2_kernel<<<NBUCK2, 256, 0, stream>>>(ebuf, ofs, row_ptr, csr);

    for (int l = 0; l < 3; l++) {
        const float* bw = (const float*)d_in[17 + 6 * l];
        const float* bb = (const float*)d_in[18 + 6 * l];
        u16*   wt1 = wtH + (size_t)(2 * l)     * 96 * HDIM;
        u16*   wt2 = wtH + (size_t)(2 * l + 1) * 96 * HDIM;
        float* b1m = bmH + (size_t)(2 * l)     * 96;
        float* b2m = bmH + (size_t)(2 * l + 1) * 96;
        // tf = (h + sum_nbr h) @ W1 + b1  (fused agg + mm1; f64 agg accum), stats slots
        aggmm_kernel<<<grid96, 256, 0, stream>>>(hb, row_ptr, csr, wt1, b1m, tf, pstatT, N_NODES);
        reduce_finalize_kernel<HDIM><<<1, HDIM * 8, 0, stream>>>(pstatT, grid96, bw, bb, acT, 1.0f / N_NODES);
        // h = relu( relu(BN(t_f32)) @ W2 + b2 ) -> bf16 hb
        mmx_kernel<HDIM, true, true, true, true, false, true><<<grid96, 256, 0, stream>>>(tf, wt2, b2m, acT, hb, nullptr, N_NODES);
    }

    // deterministic per-graph pool + fused stats partials
    pool_stats_kernel<<<N_GRAPHS, 96, 0, stream>>>(hb, batch, g, pstatG);
    reduce_finalize_kernel<HDIM><<<1, HDIM * 8, 0, stream>>>(pstatG, N_GRAPHS, bn_fc_w, bn_fc_b, acG, 1.0f / N_GRAPHS);
    mm_kernel<HDIM, true, false, true, true><<<gridG, 192, 0, stream>>>(g, Wl, bl, acG, g1, pstatG1, N_GRAPHS);
    reduce_finalize_kernel<HDIM><<<1, HDIM * 8, 0, stream>>>(pstatG1, gridG, bn_hid_w, bn_hid_b, acHid, 1.0f / N_GRAPHS);

    head_kernel<<<2, 256, 0, stream>>>(g1, acHid, Wc, bc, out, N_GRAPHS);
}